// Round 10
// baseline (3392.963 us; speedup 1.0000x reference)
//
#include <hip/hip_runtime.h>
#include <cstdint>

// CharRNN 2-layer LSTM, B=32,T=256,H=1024,V=256. Persistent kernel, round 10:
//   256 wgs x 512 threads (8 waves). wgs 0..127 = L0 chain; wgs 128..255 = L1 chain.
//   L0: all 8 waves split K (4 iters each), two-stage LDS reduce.
//   L1: waves 0-3 = critical h1@Whh1 (r7's exact 8-iter 2-deep gemm, Whh1-hi in LDS);
//       waves 4-7 = CONCURRENT zpre_{t+1} = h0@Wih1 (hi+lo streamed from L2),
//       pre-reduced into a double-buffered 4KB compact LDS buffer.
//   Flags: 32B-stride (r7), relaxed agent atomics. h slots write-once (257/layer);
//   h0 slots 1..128 alias WA0 (staged via sc-loads). Stores sc0sc1 write-through.
//   math: mfma_f32_16x16x32_bf16 split-bf16 (hi*hi + hi*lo + lo*hi) ~ f32 accuracy.

typedef float    f32x4 __attribute__((ext_vector_type(4)));
typedef short    s16x8 __attribute__((ext_vector_type(8)));
typedef unsigned u32x4 __attribute__((ext_vector_type(4)));

#define DEV __device__ __forceinline__

DEV unsigned short f2bf(float x){
  unsigned u = __builtin_bit_cast(unsigned, x);
  unsigned r = (u + 0x7fffu + ((u >> 16) & 1u)) >> 16;   // round-nearest-even
  return (unsigned short)r;
}
DEV float bf2f(unsigned short b){ return __builtin_bit_cast(float, ((unsigned)b) << 16); }

DEV s16x8 ld16(const void* p){ return *(const s16x8*)p; }

DEV f32x4 MF(s16x8 a, s16x8 b, f32x4 c){
  return __builtin_amdgcn_mfma_f32_16x16x32_bf16(a, b, c, 0, 0, 0);
}

// coherent (bypass L1/L2) 16B load — only for WA0/WAi0 (aliased regions)
#define LDC(dst, ptr)  asm volatile("global_load_dwordx4 %0, %1, off sc0 sc1" : "=v"(dst) : "v"(ptr))
// plain cached 16B load (participates in our vmcnt accounting)
#define LDP(dst, ptr)  asm volatile("global_load_dwordx4 %0, %1, off"         : "=v"(dst) : "v"(ptr))
#define WAITVM(n) do { asm volatile("s_waitcnt vmcnt(" #n ")" ::: "memory"); \
                       __builtin_amdgcn_sched_barrier(0); } while (0)
#define CFENCE()  asm volatile("" ::: "memory")
#define TRIPLE(Cmn, Ahm, Alm, Bhn, Bln) do { \
    Cmn = MF(Ahm, Bhn, Cmn); Cmn = MF(Ahm, Bln, Cmn); Cmn = MF(Alm, Bhn, Cmn); } while (0)

DEV void st16c(void* p, u32x4 v){   // coherent 16B store (write-through)
  asm volatile("global_store_dwordx4 %0, %1, off sc0 sc1" :: "v"(p), "v"(v) : "memory");
}
DEV void set_flag(int* p, int v){
  __hip_atomic_store(p, v, __ATOMIC_RELAXED, __HIP_MEMORY_SCOPE_AGENT);
}
// per-wave collective poll: all 128 flags (stride 8 ints) >= target
template<int SLP>
DEV void pollT(const int* f, int lane, int target){
  const int* p0 = f + lane * 8;
  const int* p1 = f + (64 + lane) * 8;
  for (;;) {
    int a = __hip_atomic_load(p0, __ATOMIC_RELAXED, __HIP_MEMORY_SCOPE_AGENT);
    int b = __hip_atomic_load(p1, __ATOMIC_RELAXED, __HIP_MEMORY_SCOPE_AGENT);
    if (__all((a >= target) && (b >= target))) break;
    __builtin_amdgcn_s_sleep(SLP);
  }
  CFENCE();
}
// h0 slot address: 0 -> s0 buf; 1..128 -> aliased over WA0; 129..256 -> hi buf
DEV char* h0slot(char* wa0, char* s0, char* hi, int s){
  return (s == 0) ? s0 : ((s <= 128) ? wa0 + ((size_t)(s - 1) << 17)
                                     : hi  + ((size_t)(s - 129) << 17));
}

// r7's critical half-gemm: A-hi from LDS (slots mi*32+ks), A-lo streamed from ALb, 8 iters
DEV void halfgemm8(const char* smemMat, const char* ALb, const char* Bb,
                   int wgl, int ksb, int lane, f32x4 (&C)[2][2]) {
  s16x8 P[3][4], AL[3][2];
  #pragma unroll
  for (int d = 0; d < 2; ++d) {
    #pragma unroll
    for (int q = 0; q < 4; ++q) LDP(P[d][q], Bb + ((q * 32 + ksb + d) << 10) + lane * 16);
    LDP(AL[d][0], ALb + ((((wgl * 2 + 0) * 2 + 1) * 32 + ksb + d) << 10) + lane * 16);
    LDP(AL[d][1], ALb + ((((wgl * 2 + 1) * 2 + 1) * 32 + ksb + d) << 10) + lane * 16);
  }
  #pragma unroll
  for (int i = 0; i < 8; ++i) {
    const int ks = ksb + i;
    if (i < 6) {
      #pragma unroll
      for (int q = 0; q < 4; ++q) LDP(P[(i + 2) % 3][q], Bb + ((q * 32 + ks + 2) << 10) + lane * 16);
      LDP(AL[(i + 2) % 3][0], ALb + ((((wgl * 2 + 0) * 2 + 1) * 32 + ks + 2) << 10) + lane * 16);
      LDP(AL[(i + 2) % 3][1], ALb + ((((wgl * 2 + 1) * 2 + 1) * 32 + ks + 2) << 10) + lane * 16);
    }
    s16x8 Ah0 = ld16(smemMat + ((0 * 32 + ks) << 10) + lane * 16);
    s16x8 Ah1 = ld16(smemMat + ((1 * 32 + ks) << 10) + lane * 16);
    if (i < 6) { WAITVM(12); } else if (i == 6) { WAITVM(6); } else { WAITVM(0); }
    TRIPLE(C[0][0], Ah0, AL[i % 3][0], P[i % 3][0], P[i % 3][2]);
    TRIPLE(C[0][1], Ah0, AL[i % 3][0], P[i % 3][1], P[i % 3][3]);
    TRIPLE(C[1][0], Ah1, AL[i % 3][1], P[i % 3][0], P[i % 3][2]);
    TRIPLE(C[1][1], Ah1, AL[i % 3][1], P[i % 3][1], P[i % 3][3]);
  }
}

// all-global half-gemm (zpre): A hi+lo streamed from Ab (Wih1), 8 iters, 8 loads/iter
DEV void gemm8g(const char* Ab, const char* Bb,
                int wgl, int ksb, int lane, f32x4 (&C)[2][2]) {
  s16x8 P[3][4], AH[3][2], AL[3][2];
  #pragma unroll
  for (int d = 0; d < 2; ++d) {
    #pragma unroll
    for (int q = 0; q < 4; ++q) LDP(P[d][q], Bb + ((q * 32 + ksb + d) << 10) + lane * 16);
    LDP(AH[d][0], Ab + ((((wgl * 2 + 0) * 2 + 0) * 32 + ksb + d) << 10) + lane * 16);
    LDP(AH[d][1], Ab + ((((wgl * 2 + 1) * 2 + 0) * 32 + ksb + d) << 10) + lane * 16);
    LDP(AL[d][0], Ab + ((((wgl * 2 + 0) * 2 + 1) * 32 + ksb + d) << 10) + lane * 16);
    LDP(AL[d][1], Ab + ((((wgl * 2 + 1) * 2 + 1) * 32 + ksb + d) << 10) + lane * 16);
  }
  #pragma unroll
  for (int i = 0; i < 8; ++i) {
    const int ks = ksb + i;
    if (i < 6) {
      #pragma unroll
      for (int q = 0; q < 4; ++q) LDP(P[(i + 2) % 3][q], Bb + ((q * 32 + ks + 2) << 10) + lane * 16);
      LDP(AH[(i + 2) % 3][0], Ab + ((((wgl * 2 + 0) * 2 + 0) * 32 + ks + 2) << 10) + lane * 16);
      LDP(AH[(i + 2) % 3][1], Ab + ((((wgl * 2 + 1) * 2 + 0) * 32 + ks + 2) << 10) + lane * 16);
      LDP(AL[(i + 2) % 3][0], Ab + ((((wgl * 2 + 0) * 2 + 1) * 32 + ks + 2) << 10) + lane * 16);
      LDP(AL[(i + 2) % 3][1], Ab + ((((wgl * 2 + 1) * 2 + 1) * 32 + ks + 2) << 10) + lane * 16);
    }
    if (i < 6) { WAITVM(16); } else if (i == 6) { WAITVM(8); } else { WAITVM(0); }
    TRIPLE(C[0][0], AH[i % 3][0], AL[i % 3][0], P[i % 3][0], P[i % 3][2]);
    TRIPLE(C[0][1], AH[i % 3][0], AL[i % 3][0], P[i % 3][1], P[i % 3][3]);
    TRIPLE(C[1][0], AH[i % 3][1], AL[i % 3][1], P[i % 3][0], P[i % 3][2]);
    TRIPLE(C[1][1], AH[i % 3][1], AL[i % 3][1], P[i % 3][1], P[i % 3][3]);
  }
}

// ---------------- prep: W[k][g*H+u] -> A-frag hi/lo bf16 [jb256][part2][ks32][64*16B] ----
__global__ void prep_wfrag(const float* __restrict__ W0, const float* __restrict__ W1,
                           const float* __restrict__ W2, const float* __restrict__ W3,
                           char* D0, char* D1, char* D2, char* D3) {
  int gid = blockIdx.x * 256 + threadIdx.x;       // 4*256*32*64 = 2M
  int lane = gid & 63, ks = (gid >> 6) & 31, jb = (gid >> 11) & 255, mat = gid >> 19;
  const float* S = (mat == 0) ? W0 : (mat == 1) ? W1 : (mat == 2) ? W2 : W3;
  char* D = (mat == 0) ? D0 : (mat == 1) ? D1 : (mat == 2) ? D2 : D3;
  int jp = jb * 16 + (lane & 15), u = jp >> 2, g = jp & 3;
  int kb = ks * 32 + (lane >> 4) * 8;
  s16x8 vh, vl;
  #pragma unroll
  for (int i = 0; i < 8; ++i) {
    float x = S[(kb + i) * 4096 + g * 1024 + u];
    unsigned short h = f2bf(x);
    vh[i] = (short)h;
    vl[i] = (short)f2bf(x - bf2f(h));
  }
  *(s16x8*)(D + (((jb * 2 + 0) * 32 + ks) << 10) + lane * 16) = vh;
  *(s16x8*)(D + (((jb * 2 + 1) * 32 + ks) << 10) + lane * 16) = vl;
}

// ---------------- prep: emb [v][k] and W_out [k][v] -> B-frag hi/lo [vb16][part2][ks32] ----
__global__ void prep_bfrag(const float* __restrict__ emb, const float* __restrict__ Wout,
                           char* Demb, char* Dwout) {
  int gid = blockIdx.x * 256 + threadIdx.x;       // 2*16*32*64 = 64K
  int lane = gid & 63, ks = (gid >> 6) & 31, vb = (gid >> 11) & 15, which = gid >> 15;
  int v = vb * 16 + (lane & 15), kb = ks * 32 + (lane >> 4) * 8;
  s16x8 vh, vl;
  #pragma unroll
  for (int i = 0; i < 8; ++i) {
    float x = which ? Wout[(kb + i) * 256 + v] : emb[v * 1024 + kb + i];
    unsigned short h = f2bf(x);
    vh[i] = (short)h;
    vl[i] = (short)f2bf(x - bf2f(h));
  }
  char* D = which ? Dwout : Demb;
  *(s16x8*)(D + (((vb * 2 + 0) * 32 + ks) << 10) + lane * 16) = vh;
  *(s16x8*)(D + (((vb * 2 + 1) * 32 + ks) << 10) + lane * 16) = vl;
}

// ---------------- prep: h0_in/h1_in [b][k] f32 -> h-frag slot0 [part2][nt2][ks32] ----
__global__ void prep_hinit(const float* __restrict__ h0, const float* __restrict__ h1,
                           char* h0s0, char* h1f) {
  int gid = blockIdx.x * 256 + threadIdx.x;       // 2*2*32*64 = 8192
  int lane = gid & 63, ks = (gid >> 6) & 31, nt = (gid >> 11) & 1, which = gid >> 12;
  const float* S = which ? h1 : h0;
  char* D = which ? h1f : h0s0;                   // slot 0 of each
  int b = nt * 16 + (lane & 15), kb = ks * 32 + (lane >> 4) * 8;
  s16x8 vh, vl;
  #pragma unroll
  for (int i = 0; i < 8; ++i) {
    float x = S[b * 1024 + kb + i];
    unsigned short h = f2bf(x);
    vh[i] = (short)h;
    vl[i] = (short)f2bf(x - bf2f(h));
  }
  *(s16x8*)(D + (((0 * 2 + nt) * 32 + ks) << 10) + lane * 16) = vh;
  *(s16x8*)(D + (((1 * 2 + nt) * 32 + ks) << 10) + lane * 16) = vl;
}

// ---------------- prep: flags = -1 (staging gate), gate-interleave b1 ----
__global__ void prep_misc(const float* __restrict__ b1, float* b1i, int* f0a, int* f1a) {
  int i = blockIdx.x * 256 + threadIdx.x;         // 4608
  if (i < 4096) b1i[i] = b1[(i & 3) * 1024 + (i >> 2)];
  if (i < 1024) { f0a[i] = -1; f1a[i] = -1; }
}

// ---------------- the persistent LSTM kernel ----------------
__global__ __launch_bounds__(512, 1) void lstm_persist(
    const int* __restrict__ tgt,
    const float* __restrict__ c0_in, const float* __restrict__ c1_in,
    const float* __restrict__ b0, const float* __restrict__ b_out,
    char* __restrict__ WA0, const char* __restrict__ WA1, const char* __restrict__ WA2,
    const char* __restrict__ WAi0, const char* __restrict__ WoutB, const char* __restrict__ embB,
    float* __restrict__ E0, const float* __restrict__ b1i,
    char* __restrict__ h0s0, char* __restrict__ h0hi, char* __restrict__ h1frag,
    int* __restrict__ f0, int* __restrict__ f1,
    float* __restrict__ out)
{
  extern __shared__ char smem[];
  // L0: [0,128K) Whh0 hi+lo A-frags; [128K,144K) PARTA (two-stage); [147456,148480) RP
  // L1: [0,64K) Whh1-hi A-frags; [64K,80K) ZTMP; [80K,88K) ZC (2 bufs x 4 slots);
  //     [128K,144K) PARTc; [147456,148480) RP
  constexpr int PARTA = 131072;
  constexpr int ZTMP  = 65536;
  constexpr int ZC    = 81920;
  constexpr int RP    = 147456;
  const int tid = threadIdx.x, lane = tid & 63, wv = tid >> 6;   // wv in [0,8)
  const int wg = blockIdx.x;
  const bool isL0 = (wg < 128);
  const int wgl = isL0 ? wg : (wg - 128);
  const int l15 = lane & 15, l4 = lane >> 4;
  const int mi_e = (wv >> 1) & 1, nt_e = wv & 1;  // epilogue role for wv<4

  // one-time cross-replay safety: invalidate stale L1/L2 lines
  __builtin_amdgcn_fence(__ATOMIC_ACQUIRE, "agent");

  // ---- stage A-frags into LDS ----
  if (isL0) {
    // Whh0 hi+lo (128KB) via sc-loads (WA0 becomes h0 slots!)
    u32x4 tmp[8];
    for (int blk = 0; blk < 2; ++blk) {
      #pragma unroll
      for (int q = 0; q < 8; ++q) {
        int idx = tid + (blk * 8 + q) * 512;
        int l16 = idx & 63, ks = (idx >> 6) & 31, mi = (idx >> 11) & 1, part = idx >> 12;
        LDC(tmp[q], WA0 + ((((wgl * 2 + mi) * 2 + part) * 32 + ks) << 10) + l16 * 16);
      }
      WAITVM(0);
      #pragma unroll
      for (int q = 0; q < 8; ++q) {
        int idx = tid + (blk * 8 + q) * 512;
        int l16 = idx & 63, ks = (idx >> 6) & 31, mi = (idx >> 11) & 1, part = idx >> 12;
        *(u32x4*)(smem + (((part * 2 + mi) * 32 + ks) << 10) + l16 * 16) = tmp[q];
      }
    }
  } else {
    // Whh1 hi only (64KB), slots mi*32+ks; plain loads (never overwritten)
    for (int idx = tid; idx < 4096; idx += 512) {
      int l16 = idx & 63, ks = (idx >> 6) & 31, mi = idx >> 11;
      u32x4 v = *(const u32x4*)(WA2 + ((((wgl * 2 + mi) * 2 + 0) * 32 + ks) << 10) + l16 * 16);
      *(u32x4*)(smem + ((mi * 32 + ks) << 10) + l16 * 16) = v;
    }
  }

  // ---- E0 = emb @ Wih0 + b0, own 32 gate-cols only (L0 wgs). WAi0 via sc-loads. ----
  if (isL0) {
    f32x4 C[2][2];
    #pragma unroll
    for (int a = 0; a < 2; ++a)
      #pragma unroll
      for (int b = 0; b < 2; ++b) C[a][b] = 0.0f;
    for (int ks = 0; ks < 32; ++ks) {
      s16x8 Ah0, Ah1, Al0, Al1;
      LDC(Ah0, WAi0 + ((((wgl * 2 + 0) * 2 + 0) * 32 + ks) << 10) + lane * 16);
      LDC(Ah1, WAi0 + ((((wgl * 2 + 1) * 2 + 0) * 32 + ks) << 10) + lane * 16);
      LDC(Al0, WAi0 + ((((wgl * 2 + 0) * 2 + 1) * 32 + ks) << 10) + lane * 16);
      LDC(Al1, WAi0 + ((((wgl * 2 + 1) * 2 + 1) * 32 + ks) << 10) + lane * 16);
      WAITVM(0);
      #pragma unroll
      for (int v4 = 0; v4 < 2; ++v4) {
        int vb = wv * 2 + v4;
        s16x8 Bh = ld16(embB + (((vb * 2 + 0) * 32 + ks) << 10) + lane * 16);
        s16x8 Bl = ld16(embB + (((vb * 2 + 1) * 32 + ks) << 10) + lane * 16);
        TRIPLE(C[0][v4], Ah0, Al0, Bh, Bl);
        TRIPLE(C[1][v4], Ah1, Al1, Bh, Bl);
      }
    }
    #pragma unroll
    for (int mi = 0; mi < 2; ++mi) {
      int jb4 = wgl * 32 + mi * 16 + l4 * 4;
      int u = jb4 >> 2;
      f32x4 bb;
      #pragma unroll
      for (int r = 0; r < 4; ++r) bb[r] = b0[r * 1024 + u];
      #pragma unroll
      for (int v4 = 0; v4 < 2; ++v4) {
        int v = (wv * 2 + v4) * 16 + l15;
        *(f32x4*)(E0 + v * 4096 + jb4) = C[mi][v4] + bb;
      }
    }
  }

  // ---- c state + L1 bias: one quadrant per epilogue wave (wv<4) ----
  float cst = 0.f;
  f32x4 b1z = {0.f, 0.f, 0.f, 0.f};
  if (wv < 4) {
    const float* cs = isL0 ? c0_in : c1_in;
    cst = cs[(nt_e * 16 + l15) * 1024 + wgl * 8 + mi_e * 4 + l4];
    if (!isL0) b1z = *(const f32x4*)(b1i + wgl * 32 + mi_e * 16 + (l4 << 2));
  }

  __syncthreads();                                 // staging + E0 complete for this wg
  if (tid == 0) set_flag((isL0 ? f0 : f1) + wgl * 8, 0);   // "staged" release

  // ---- sequential recurrence ----
  if (isL0) {
    for (int t = 0; t < 256; ++t) {
      const int s = t + 1;
      f32x4 C[2][2];
      #pragma unroll
      for (int a = 0; a < 2; ++a)
        #pragma unroll
        for (int b = 0; b < 2; ++b) C[a][b] = 0.0f;

      f32x4 e0v = {0.f, 0.f, 0.f, 0.f};
      if (wv < 4) {
        int tv = tgt[(nt_e * 16 + l15) * 256 + t];
        e0v = *(const f32x4*)(E0 + (size_t)tv * 4096 + wgl * 32 + mi_e * 16 + (l4 << 2));
      }
      pollT<1>(f0, lane, t);                       // all 8 waves
      const char* Bb = h0slot(WA0, h0s0, h0hi, t);
      const int ksb = wv * 4;                      // 4 iters per wave
      s16x8 P[3][4];
      #pragma unroll
      for (int d = 0; d < 2; ++d)
        #pragma unroll
        for (int q = 0; q < 4; ++q) LDP(P[d][q], Bb + ((q * 32 + ksb + d) << 10) + lane * 16);
      #pragma unroll
      for (int i = 0; i < 4; ++i) {
        const int ks = ksb + i;
        if (i < 2) {
          #pragma unroll
          for (int q = 0; q < 4; ++q) LDP(P[(i + 2) % 3][q], Bb + ((q * 32 + ks + 2) << 10) + lane * 16);
        }
        s16x8 Ah0 = ld16(smem + ((0 * 32 + ks) << 10) + lane * 16);
        s16x8 Ah1 = ld16(smem + ((1 * 32 + ks) << 10) + lane * 16);
        s16x8 Al0 = ld16(smem + ((2 * 32 + ks) << 10) + lane * 16);
        s16x8 Al1 = ld16(smem + ((3 * 32 + ks) << 10) + lane * 16);
        if (i < 2) { WAITVM(8); } else if (i == 2) { WAITVM(4); } else { WAITVM(0); }
        TRIPLE(C[0][0], Ah0, Al0, P[i % 3][0], P[i % 3][2]);
        TRIPLE(C[0][1], Ah0, Al0, P[i % 3][1], P[i % 3][3]);
        TRIPLE(C[1][0], Ah1, Al1, P[i % 3][0], P[i % 3][2]);
        TRIPLE(C[1][1], Ah1, Al1, P[i % 3][1], P[i % 3][3]);
      }

      // two-stage reduce: waves 4-7 write; waves 0-3 add their own; epilogue sums 4 slots
      if (wv >= 4) {
        #pragma unroll
        for (int mi = 0; mi < 2; ++mi)
          #pragma unroll
          for (int nt = 0; nt < 2; ++nt)
            *(f32x4*)(smem + PARTA + (((wv - 4) * 4 + mi * 2 + nt) << 10) + lane * 16) = C[mi][nt];
      }
      __syncthreads();                             // A1
      if (wv < 4) {
        #pragma unroll
        for (int mi = 0; mi < 2; ++mi)
          #pragma unroll
          for (int nt = 0; nt < 2; ++nt) {
            f32x4* p = (f32x4*)(smem + PARTA + ((wv * 4 + mi * 2 + nt) << 10) + lane * 16);
            *p = *p + C[mi][nt];
          }
      }
      __syncthreads();                             // A2
      if (wv < 4) {
        f32x4 z = {0.f, 0.f, 0.f, 0.f};
        #pragma unroll
        for (int w = 0; w < 4; ++w)
          z += *(const f32x4*)(smem + PARTA + ((w * 4 + wv) << 10) + lane * 16);
        z += e0v;
        float ig = 1.f / (1.f + __expf(-z[0]));
        float fg = 1.f / (1.f + __expf(-z[1]));
        float og = 1.f / (1.f + __expf(-z[3]));
        float cn = fg * cst + ig * tanhf(z[2]);
        float hn = og * tanhf(cn);
        cst = cn;
        unsigned short hb = f2bf(hn);
        unsigned short lb = f2bf(hn - bf2f(hb));
        *(short*)(smem + RP + ((0 + nt_e) * 16 + l15) * 16 + (mi_e * 4 + l4) * 2) = (short)hb;
        *(short*)(smem + RP + ((2 + nt_e) * 16 + l15) * 16 + (mi_e * 4 + l4) * 2) = (short)lb;
        if (t == 255) {
          int u = wgl * 8 + mi_e * 4 + l4, b = nt_e * 16 + l15;
          out[2097152 + b * 1024 + u] = hn;
          out[2097152 + 32768 + b * 1024 + u] = cn;
        }
      }
      __syncthreads();                             // B

      if (wv == 0) {
        char* hd = h0slot(WA0, h0s0, h0hi, s);
        u32x4 v = *(const u32x4*)(smem + RP + lane * 16);
        char* dst = hd + (((lane >> 4) * 32 + (wgl >> 2)) << 10) + ((wgl & 3) * 16 + l15) * 16;
        st16c(dst, v);
        asm volatile("s_waitcnt vmcnt(0)" ::: "memory");
        if (lane == 0) set_flag(f0 + wgl * 8, s);
      }
    }
  } else {
    // ---- L1 prologue: zc[0] = zpre for t=0 (h0 slot 1 @ Wih1), waves 4-7 ----
    if (wv >= 4) {
      pollT<2>(f0, lane, 1);
      f32x4 C2[2][2];
      #pragma unroll
      for (int a = 0; a < 2; ++a)
        #pragma unroll
        for (int b = 0; b < 2; ++b) C2[a][b] = 0.0f;
      gemm8g(WA1, h0slot(WA0, h0s0, h0hi, 1), wgl, (wv - 4) * 8, lane, C2);
      #pragma unroll
      for (int mi = 0; mi < 2; ++mi)
        #pragma unroll
        for (int nt = 0; nt < 2; ++nt)
          *(f32x4*)(smem + ZTMP + (((wv - 4) * 4 + mi * 2 + nt) << 10) + lane * 16) = C2[mi][nt];
    }
    __syncthreads();
    if (wv >= 4) {
      const int q = wv - 4;
      f32x4 zq = {0.f, 0.f, 0.f, 0.f};
      #pragma unroll
      for (int w = 0; w < 4; ++w)
        zq += *(const f32x4*)(smem + ZTMP + ((w * 4 + q) << 10) + lane * 16);
      *(f32x4*)(smem + ZC + ((0 * 4 + q) << 10) + lane * 16) = zq;
    }
    __syncthreads();

    for (int t = 0; t < 256; ++t) {
      const int s = t + 1;
      const int cur = t & 1, nxt = cur ^ 1;
      f32x4 C[2][2];
      #pragma unroll
      for (int a = 0; a < 2; ++a)
        #pragma unroll
        for (int b = 0; b < 2; ++b) C[a][b] = 0.0f;

      if (wv < 4) {
        // CRITICAL: h1_{t-1} @ Whh1, 8 iters (r7's exact microstructure)
        pollT<1>(f1, lane, t);
        halfgemm8(smem, WA2, h1frag + (size_t)t * 131072, wgl, wv * 8, lane, C);
        #pragma unroll
        for (int mi = 0; mi < 2; ++mi)
          #pragma unroll
          for (int nt = 0; nt < 2; ++nt)
            *(f32x4*)(smem + PARTA + ((wv * 4 + mi * 2 + nt) << 10) + lane * 16) = C[mi][nt];
      } else if (t < 255) {
        // CONCURRENT: zpre_{t+1} = h0 slot t+2 @ Wih1 (hi+lo streamed)
        pollT<2>(f0, lane, t + 2);
        gemm8g(WA1, h0slot(WA0, h0s0, h0hi, t + 2), wgl, (wv - 4) * 8, lane, C);
        #pragma unroll
        for (int mi = 0; mi < 2; ++mi)
          #pragma unroll
          for (int nt = 0; nt < 2; ++nt)
            *(f32x4*)(smem + ZTMP + (((wv - 4) * 4 + mi * 2 + nt) << 10) + lane * 16) = C[mi][nt];
      }
      __syncthreads();                             // A

      if (wv < 4) {
        f32x4 z = {0.f, 0.f, 0.f, 0.f};
        #pragma unroll
        for (int w = 0; w < 4; ++w)
          z += *(const f32x4*)(smem + PARTA + ((w * 4 + wv) << 10) + lane * 16);
        z += *(const f32x4*)(smem + ZC + ((cur * 4 + wv) << 10) + lane * 16);
        z += b1z;
        float ig = 1.f / (1.f + __expf(-z[0]));
        float fg = 1.f / (1.f + __expf(-z[1]));
        float og = 1.f / (1.f + __expf(-z[3]));
        float cn = fg * cst + ig * tanhf(z[2]);
        float hn = og * tanhf(cn);
        cst = cn;
        unsigned short hb = f2bf(hn);
        unsigned short lb = f2bf(hn - bf2f(hb));
        *(short*)(smem + RP + ((0 + nt_e) * 16 + l15) * 16 + (mi_e * 4 + l4) * 2) = (short)hb;
        *(short*)(smem + RP + ((2 + nt_e) * 16 + l15) * 16 + (mi_e * 4 + l4) * 2) = (short)lb;
        if (t == 255) {
          int u = wgl * 8 + mi_e * 4 + l4, b = nt_e * 16 + l15;
          out[2097152 + 65536 + b * 1024 + u] = hn;
          out[2097152 + 65536 + 32768 + b * 1024 + u] = cn;
        }
      } else if (t < 255) {
        const int q = wv - 4;
        f32x4 zq = {0.f, 0.f, 0.f, 0.f};
        #pragma unroll
        for (int w = 0; w < 4; ++w)
          zq += *(const f32x4*)(smem + ZTMP + ((w * 4 + q) << 10) + lane * 16);
        *(f32x4*)(smem + ZC + ((nxt * 4 + q) << 10) + lane * 16) = zq;
      }
      __syncthreads();                             // B

      if (wv == 0) {
        char* hd = h1frag + (size_t)s * 131072;
        u32x4 v = *(const u32x4*)(smem + RP + lane * 16);
        char* dst = hd + (((lane >> 4) * 32 + (wgl >> 2)) << 10) + ((wgl & 3) * 16 + l15) * 16;
        st16c(dst, v);
        asm volatile("s_waitcnt vmcnt(0)" ::: "memory");
        if (lane == 0) set_flag(f1 + wgl * 8, s);
      }
    }
  }

  // ---- projection: logits[b][t][v] = h1_t @ W_out + b_out ; one t per CU ----
  // L0 wgs (finish first) take EARLY t (flags long set); L1 wgs take late t.
  {
    const int tp = isL0 ? wgl : (128 + wgl);
    pollT<32>(f1, lane, tp + 1);
    const char* A = h1frag + (size_t)(tp + 1) * 131072;
    f32x4 C[2][2];
    #pragma unroll
    for (int a = 0; a < 2; ++a)
      #pragma unroll
      for (int b = 0; b < 2; ++b) C[a][b] = 0.0f;
    s16x8 QA[4], QB[4];
    #pragma unroll
    for (int q = 0; q < 4; ++q) LDP(QA[q], A + ((q * 32 + 0) << 10) + lane * 16);
    for (int kk = 0; kk < 16; ++kk) {
      const int ks = kk * 2;
      #pragma unroll
      for (int q = 0; q < 4; ++q) LDP(QB[q], A + ((q * 32 + ks + 1) << 10) + lane * 16);
      asm volatile("s_waitcnt vmcnt(4)" ::: "memory");
      __builtin_amdgcn_sched_barrier(0);
      #pragma unroll
      for (int v4 = 0; v4 < 2; ++v4) {
        int vb = wv * 2 + v4;
        s16x8 Bh = ld16(WoutB + (((vb * 2 + 0) * 32 + ks) << 10) + lane * 16);
        s16x8 Bl = ld16(WoutB + (((vb * 2 + 1) * 32 + ks) << 10) + lane * 16);
        C[0][v4] = MF(QA[0], Bh, C[0][v4]); C[0][v4] = MF(QA[0], Bl, C[0][v4]); C[0][v4] = MF(QA[2], Bh, C[0][v4]);
        C[1][v4] = MF(QA[1], Bh, C[1][v4]); C[1][v4] = MF(QA[1], Bl, C[1][v4]); C[1][v4] = MF(QA[3], Bh, C[1][v4]);
      }
      if (kk < 15) {
        #pragma unroll
        for (int q = 0; q < 4; ++q) LDP(QA[q], A + ((q * 32 + ks + 2) << 10) + lane * 16);
        asm volatile("s_waitcnt vmcnt(4)" ::: "memory");
      } else {
        asm volatile("s_waitcnt vmcnt(0)" ::: "memory");
      }
      __builtin_amdgcn_sched_barrier(0);
      #pragma unroll
      for (int v4 = 0; v4 < 2; ++v4) {
        int vb = wv * 2 + v4;
        s16x8 Bh = ld16(WoutB + (((vb * 2 + 0) * 32 + ks + 1) << 10) + lane * 16);
        s16x8 Bl = ld16(WoutB + (((vb * 2 + 1) * 32 + ks + 1) << 10) + lane * 16);
        C[0][v4] = MF(QB[0], Bh, C[0][v4]); C[0][v4] = MF(QB[0], Bl, C[0][v4]); C[0][v4] = MF(QB[2], Bh, C[0][v4]);
        C[1][v4] = MF(QB[1], Bh, C[1][v4]); C[1][v4] = MF(QB[1], Bl, C[1][v4]); C[1][v4] = MF(QB[3], Bh, C[1][v4]);
      }
    }
    #pragma unroll
    for (int nt = 0; nt < 2; ++nt)
      #pragma unroll
      for (int v4 = 0; v4 < 2; ++v4) {
        int v = (wv * 2 + v4) * 16 + l15;
        float bo = b_out[v];
        #pragma unroll
        for (int r = 0; r < 4; ++r) {
          int b = nt * 16 + l4 * 4 + r;
          out[((size_t)b * 256 + tp) * 256 + v] = C[nt][v4][r] + bo;
        }
      }
  }
}

extern "C" void kernel_launch(void* const* d_in, const int* in_sizes, int n_in,
                              void* d_out, int out_size, void* d_ws, size_t ws_size,
                              hipStream_t stream) {
  const int*   targets = (const int*)d_in[1];
  const float* h0_in   = (const float*)d_in[2];
  const float* c0_in   = (const float*)d_in[3];
  const float* h1_in   = (const float*)d_in[4];
  const float* c1_in   = (const float*)d_in[5];
  const float* emb     = (const float*)d_in[6];
  const float* W_ih0   = (const float*)d_in[7];
  const float* W_hh0   = (const float*)d_in[8];
  const float* b0      = (const float*)d_in[9];
  const float* W_ih1   = (const float*)d_in[10];
  const float* W_hh1   = (const float*)d_in[11];
  const float* b1      = (const float*)d_in[12];
  const float* W_out   = (const float*)d_in[13];
  const float* b_out   = (const float*)d_in[14];
  float* out = (float*)d_out;

  char* ws = (char*)d_ws;
  char*  WA0    = ws;                         // Whh0 A-frags hi/lo 16MB; becomes h0 slots 1..128
  char*  WA1    = ws + 16777216;              // Wih1 hi/lo (streamed by L1 waves 4-7)
  char*  WA2    = ws + 33554432;              // Whh1 (hi staged to LDS, lo streamed)
  char*  WoutB  = ws + 50331648;              // W_out B-frags, 1MB
  char*  embB   = ws + 51380224;              // emb B-frags, 1MB
  float* E0     = (float*)(ws + 52428800);    // 4MB f32
  float* b1i    = (float*)(ws + 56623104);    // 16KB
  int*   f0     = (int*)(ws + 56639488);      // flag array, 4KB (128 x stride 32B)
  int*   f1     = (int*)(ws + 56643584);      // flag array, 4KB
  char*  h0s0   = ws + 56647680;              // h0 slot 0, 128KB
  char*  h0hi   = ws + 56778752;              // h0 slots 129..256, 16MB
  char*  h1frag = ws + 73555968;              // 257 slots x 128KB (~33.7MB) -> end ~102.3MB
  char*  WAi0   = h1frag + 16777216;          // Wih0 A-frags alias h1 slots 128..255
                                              // (read via sc-loads at E0; slot 128 written step 127)

  prep_misc <<<18,   256, 0, stream>>>(b1, b1i, f0, f1);
  prep_wfrag<<<8192, 256, 0, stream>>>(W_hh0, W_ih1, W_hh1, W_ih0, WA0, WA1, WA2, WAi0);
  prep_bfrag<<<256,  256, 0, stream>>>(emb, W_out, embB, WoutB);
  prep_hinit<<<32,   256, 0, stream>>>(h0_in, h1_in, h0s0, h1frag);

  hipFuncSetAttribute(reinterpret_cast<const void*>(lstm_persist),
                      hipFuncAttributeMaxDynamicSharedMemorySize, 148480);
  lstm_persist<<<256, 512, 148480, stream>>>(
      targets, c0_in, c1_in, b0, b_out,
      WA0, WA1, WA2, WAi0, WoutB, embB,
      E0, b1i, h0s0, h0hi, h1frag, f0, f1, out);
}

// Round 11
// 2412.187 us; speedup vs baseline: 1.4066x; 1.4066x over previous
//
#include <hip/hip_runtime.h>
#include <cstdint>

// CharRNN 2-layer LSTM, B=32,T=256,H=1024,V=256. Persistent kernel, round 11:
//   Base = round 7 (best, 1723us). Change: L1's step collapses from {2 polls + 4
//   barriers, 2 serial gemms} to {1 combined poll + 2 barriers, ONE fused dual-GEMM}:
//   8 iters x (12 MFMA crit h1@Whh1 + 12 MFMA zpre h0@Wih1), 14 ordered loads/iter,
//   2-deep prefetch, waitvm 28/14/0. Whh1-hi in LDS; Wih1 hi+lo streamed (L2-hot).
//   zpre partials -> ZTMP; epilogue applies ZC[cur] and reduces ZC[nxt] (lane-local).
//   L0 chain, flags (32B stride), stores, projection: r7 verbatim.
//   math: mfma_f32_16x16x32_bf16 split-bf16 (hi*hi + hi*lo + lo*hi) ~ f32 accuracy.

typedef float    f32x4 __attribute__((ext_vector_type(4)));
typedef short    s16x8 __attribute__((ext_vector_type(8)));
typedef unsigned u32x4 __attribute__((ext_vector_type(4)));

#define DEV __device__ __forceinline__

DEV unsigned short f2bf(float x){
  unsigned u = __builtin_bit_cast(unsigned, x);
  unsigned r = (u + 0x7fffu + ((u >> 16) & 1u)) >> 16;   // round-nearest-even
  return (unsigned short)r;
}
DEV float bf2f(unsigned short b){ return __builtin_bit_cast(float, ((unsigned)b) << 16); }

DEV s16x8 ld16(const void* p){ return *(const s16x8*)p; }

DEV f32x4 MF(s16x8 a, s16x8 b, f32x4 c){
  return __builtin_amdgcn_mfma_f32_16x16x32_bf16(a, b, c, 0, 0, 0);
}

// coherent (bypass L1/L2) 16B load — only for WA0/WAi0 (aliased regions)
#define LDC(dst, ptr)  asm volatile("global_load_dwordx4 %0, %1, off sc0 sc1" : "=v"(dst) : "v"(ptr))
// plain cached 16B load (participates in our vmcnt accounting)
#define LDP(dst, ptr)  asm volatile("global_load_dwordx4 %0, %1, off"         : "=v"(dst) : "v"(ptr))
#define WAITVM(n) do { asm volatile("s_waitcnt vmcnt(" #n ")" ::: "memory"); \
                       __builtin_amdgcn_sched_barrier(0); } while (0)
#define CFENCE()  asm volatile("" ::: "memory")
#define TRIPLE(Cmn, Ahm, Alm, Bhn, Bln) do { \
    Cmn = MF(Ahm, Bhn, Cmn); Cmn = MF(Ahm, Bln, Cmn); Cmn = MF(Alm, Bhn, Cmn); } while (0)

// literal vmcnt wait (vmcnt=N; expcnt/lgkmcnt unmasked)
template<int N> DEV void waitvm(){
  __builtin_amdgcn_s_waitcnt((N & 15) | (7 << 4) | (15 << 8) | ((N >> 4) << 14));
  __builtin_amdgcn_sched_barrier(0);
}

DEV void st16c(void* p, u32x4 v){   // coherent 16B store (write-through)
  asm volatile("global_store_dwordx4 %0, %1, off sc0 sc1" :: "v"(p), "v"(v) : "memory");
}
DEV void set_flag(int* p, int v){
  __hip_atomic_store(p, v, __ATOMIC_RELAXED, __HIP_MEMORY_SCOPE_AGENT);
}
// per-wave collective poll: all 128 flags (stride 8 ints) >= target
template<int SLP>
DEV void pollT(const int* f, int lane, int target){
  const int* p0 = f + lane * 8;
  const int* p1 = f + (64 + lane) * 8;
  for (;;) {
    int a = __hip_atomic_load(p0, __ATOMIC_RELAXED, __HIP_MEMORY_SCOPE_AGENT);
    int b = __hip_atomic_load(p1, __ATOMIC_RELAXED, __HIP_MEMORY_SCOPE_AGENT);
    if (__all((a >= target) && (b >= target))) break;
    __builtin_amdgcn_s_sleep(SLP);
  }
  CFENCE();
}
// combined poll: all f1 >= t1 AND all f0 >= t0
DEV void poll2c(const int* fa, int ta, const int* fb, int tb, int lane){
  const int* a0 = fa + lane * 8;
  const int* a1 = fa + (64 + lane) * 8;
  const int* b0 = fb + lane * 8;
  const int* b1 = fb + (64 + lane) * 8;
  for (;;) {
    int x0 = __hip_atomic_load(a0, __ATOMIC_RELAXED, __HIP_MEMORY_SCOPE_AGENT);
    int x1 = __hip_atomic_load(a1, __ATOMIC_RELAXED, __HIP_MEMORY_SCOPE_AGENT);
    int y0 = __hip_atomic_load(b0, __ATOMIC_RELAXED, __HIP_MEMORY_SCOPE_AGENT);
    int y1 = __hip_atomic_load(b1, __ATOMIC_RELAXED, __HIP_MEMORY_SCOPE_AGENT);
    if (__all((x0 >= ta) && (x1 >= ta) && (y0 >= tb) && (y1 >= tb))) break;
    __builtin_amdgcn_s_sleep(1);
  }
  CFENCE();
}
// h0 slot address: 0 -> s0 buf; 1..128 -> aliased over WA0; 129..256 -> hi buf
DEV char* h0slot(char* wa0, char* s0, char* hi, int s){
  return (s == 0) ? s0 : ((s <= 128) ? wa0 + ((size_t)(s - 1) << 17)
                                     : hi  + ((size_t)(s - 129) << 17));
}

// all-global half-gemm (prologue zpre): A hi+lo streamed from Ab (Wih1), 8 iters
DEV void gemm8g(const char* Ab, const char* Bb,
                int wgl, int ksb, int lane, f32x4 (&C)[2][2]) {
  s16x8 P[3][4], AH[3][2], AL[3][2];
  #pragma unroll
  for (int d = 0; d < 2; ++d) {
    #pragma unroll
    for (int q = 0; q < 4; ++q) LDP(P[d][q], Bb + ((q * 32 + ksb + d) << 10) + lane * 16);
    LDP(AH[d][0], Ab + ((((wgl * 2 + 0) * 2 + 0) * 32 + ksb + d) << 10) + lane * 16);
    LDP(AH[d][1], Ab + ((((wgl * 2 + 1) * 2 + 0) * 32 + ksb + d) << 10) + lane * 16);
    LDP(AL[d][0], Ab + ((((wgl * 2 + 0) * 2 + 1) * 32 + ksb + d) << 10) + lane * 16);
    LDP(AL[d][1], Ab + ((((wgl * 2 + 1) * 2 + 1) * 32 + ksb + d) << 10) + lane * 16);
  }
  #pragma unroll
  for (int i = 0; i < 8; ++i) {
    const int ks = ksb + i;
    if (i < 6) {
      #pragma unroll
      for (int q = 0; q < 4; ++q) LDP(P[(i + 2) % 3][q], Bb + ((q * 32 + ks + 2) << 10) + lane * 16);
      LDP(AH[(i + 2) % 3][0], Ab + ((((wgl * 2 + 0) * 2 + 0) * 32 + ks + 2) << 10) + lane * 16);
      LDP(AH[(i + 2) % 3][1], Ab + ((((wgl * 2 + 1) * 2 + 0) * 32 + ks + 2) << 10) + lane * 16);
      LDP(AL[(i + 2) % 3][0], Ab + ((((wgl * 2 + 0) * 2 + 1) * 32 + ks + 2) << 10) + lane * 16);
      LDP(AL[(i + 2) % 3][1], Ab + ((((wgl * 2 + 1) * 2 + 1) * 32 + ks + 2) << 10) + lane * 16);
    }
    if (i < 6) { WAITVM(16); } else if (i == 6) { WAITVM(8); } else { WAITVM(0); }
    TRIPLE(C[0][0], AH[i % 3][0], AL[i % 3][0], P[i % 3][0], P[i % 3][2]);
    TRIPLE(C[0][1], AH[i % 3][0], AL[i % 3][0], P[i % 3][1], P[i % 3][3]);
    TRIPLE(C[1][0], AH[i % 3][1], AL[i % 3][1], P[i % 3][0], P[i % 3][2]);
    TRIPLE(C[1][1], AH[i % 3][1], AL[i % 3][1], P[i % 3][1], P[i % 3][3]);
  }
}

// ---------------- prep: W[k][g*H+u] -> A-frag hi/lo bf16 [jb256][part2][ks32][64*16B] ----
__global__ void prep_wfrag(const float* __restrict__ W0, const float* __restrict__ W1,
                           const float* __restrict__ W2, const float* __restrict__ W3,
                           char* D0, char* D1, char* D2, char* D3) {
  int gid = blockIdx.x * 256 + threadIdx.x;       // 4*256*32*64 = 2M
  int lane = gid & 63, ks = (gid >> 6) & 31, jb = (gid >> 11) & 255, mat = gid >> 19;
  const float* S = (mat == 0) ? W0 : (mat == 1) ? W1 : (mat == 2) ? W2 : W3;
  char* D = (mat == 0) ? D0 : (mat == 1) ? D1 : (mat == 2) ? D2 : D3;
  int jp = jb * 16 + (lane & 15), u = jp >> 2, g = jp & 3;
  int kb = ks * 32 + (lane >> 4) * 8;
  s16x8 vh, vl;
  #pragma unroll
  for (int i = 0; i < 8; ++i) {
    float x = S[(kb + i) * 4096 + g * 1024 + u];
    unsigned short h = f2bf(x);
    vh[i] = (short)h;
    vl[i] = (short)f2bf(x - bf2f(h));
  }
  *(s16x8*)(D + (((jb * 2 + 0) * 32 + ks) << 10) + lane * 16) = vh;
  *(s16x8*)(D + (((jb * 2 + 1) * 32 + ks) << 10) + lane * 16) = vl;
}

// ---------------- prep: emb [v][k] and W_out [k][v] -> B-frag hi/lo [vb16][part2][ks32] ----
__global__ void prep_bfrag(const float* __restrict__ emb, const float* __restrict__ Wout,
                           char* Demb, char* Dwout) {
  int gid = blockIdx.x * 256 + threadIdx.x;       // 2*16*32*64 = 64K
  int lane = gid & 63, ks = (gid >> 6) & 31, vb = (gid >> 11) & 15, which = gid >> 15;
  int v = vb * 16 + (lane & 15), kb = ks * 32 + (lane >> 4) * 8;
  s16x8 vh, vl;
  #pragma unroll
  for (int i = 0; i < 8; ++i) {
    float x = which ? Wout[(kb + i) * 256 + v] : emb[v * 1024 + kb + i];
    unsigned short h = f2bf(x);
    vh[i] = (short)h;
    vl[i] = (short)f2bf(x - bf2f(h));
  }
  char* D = which ? Dwout : Demb;
  *(s16x8*)(D + (((vb * 2 + 0) * 32 + ks) << 10) + lane * 16) = vh;
  *(s16x8*)(D + (((vb * 2 + 1) * 32 + ks) << 10) + lane * 16) = vl;
}

// ---------------- prep: h0_in/h1_in [b][k] f32 -> h-frag slot0 [part2][nt2][ks32] ----
__global__ void prep_hinit(const float* __restrict__ h0, const float* __restrict__ h1,
                           char* h0s0, char* h1f) {
  int gid = blockIdx.x * 256 + threadIdx.x;       // 2*2*32*64 = 8192
  int lane = gid & 63, ks = (gid >> 6) & 31, nt = (gid >> 11) & 1, which = gid >> 12;
  const float* S = which ? h1 : h0;
  char* D = which ? h1f : h0s0;                   // slot 0 of each
  int b = nt * 16 + (lane & 15), kb = ks * 32 + (lane >> 4) * 8;
  s16x8 vh, vl;
  #pragma unroll
  for (int i = 0; i < 8; ++i) {
    float x = S[b * 1024 + kb + i];
    unsigned short h = f2bf(x);
    vh[i] = (short)h;
    vl[i] = (short)f2bf(x - bf2f(h));
  }
  *(s16x8*)(D + (((0 * 2 + nt) * 32 + ks) << 10) + lane * 16) = vh;
  *(s16x8*)(D + (((1 * 2 + nt) * 32 + ks) << 10) + lane * 16) = vl;
}

// ---------------- prep: flags = -1 (staging gate), gate-interleave b1 ----
__global__ void prep_misc(const float* __restrict__ b1, float* b1i, int* f0a, int* f1a) {
  int i = blockIdx.x * 256 + threadIdx.x;         // 4608
  if (i < 4096) b1i[i] = b1[(i & 3) * 1024 + (i >> 2)];
  if (i < 1024) { f0a[i] = -1; f1a[i] = -1; }
}

// ---------------- the persistent LSTM kernel ----------------
__global__ __launch_bounds__(256, 1) void lstm_persist(
    const int* __restrict__ tgt,
    const float* __restrict__ c0_in, const float* __restrict__ c1_in,
    const float* __restrict__ b0, const float* __restrict__ b_out,
    char* __restrict__ WA0, const char* __restrict__ WA1, const char* __restrict__ WA2,
    const char* __restrict__ WAi0, const char* __restrict__ WoutB, const char* __restrict__ embB,
    float* __restrict__ E0, const float* __restrict__ b1i,
    char* __restrict__ h0s0, char* __restrict__ h0hi, char* __restrict__ h1frag,
    int* __restrict__ f0, int* __restrict__ f1,
    float* __restrict__ out)
{
  extern __shared__ char smem[];
  // L0: [0,128K) Whh0 hi+lo A-frags; [128K,144K) PART; [144K,145K) RP  (r7 layout)
  // L1: [0,64K) Whh1-hi A-frags; [64K,80K) PART1; [80K,96K) ZTMP; [96K,104K) ZC; [104K,105K) RP1
  constexpr int PART  = 131072;
  constexpr int RP0   = 131072 + 16384;
  constexpr int PART1 = 65536;
  constexpr int ZTMP  = 81920;
  constexpr int ZC    = 98304;
  constexpr int RP1   = 106496;
  const int tid = threadIdx.x, lane = tid & 63, wv = tid >> 6;
  const int wg = blockIdx.x;
  const bool isL0 = (wg < 128);
  const int wgl = isL0 ? wg : (wg - 128);
  const int l15 = lane & 15, l4 = lane >> 4;
  const int mi_e = wv >> 1, nt_e = wv & 1;        // epilogue role (mi, nt)

  // one-time cross-replay safety: invalidate stale L1/L2 lines
  __builtin_amdgcn_fence(__ATOMIC_ACQUIRE, "agent");

  // ---- stage A-frags into LDS ----
  if (isL0) {
    // Whh0 hi+lo (128KB) via sc-loads (WA0 becomes h0 slots!)
    u32x4 tmp[8];
    for (int blk = 0; blk < 4; ++blk) {
      #pragma unroll
      for (int q = 0; q < 8; ++q) {
        int idx = tid + (blk * 8 + q) * 256;
        int l16 = idx & 63, ks = (idx >> 6) & 31, mi = (idx >> 11) & 1, part = idx >> 12;
        LDC(tmp[q], WA0 + ((((wgl * 2 + mi) * 2 + part) * 32 + ks) << 10) + l16 * 16);
      }
      WAITVM(0);
      #pragma unroll
      for (int q = 0; q < 8; ++q) {
        int idx = tid + (blk * 8 + q) * 256;
        int l16 = idx & 63, ks = (idx >> 6) & 31, mi = (idx >> 11) & 1, part = idx >> 12;
        *(u32x4*)(smem + (((part * 2 + mi) * 32 + ks) << 10) + l16 * 16) = tmp[q];
      }
    }
  } else {
    // Whh1-hi only (64KB), slots mi*32+ks; plain loads (never overwritten)
    for (int idx = tid; idx < 4096; idx += 256) {
      int l16 = idx & 63, ks = (idx >> 6) & 31, mi = idx >> 11;
      u32x4 v = *(const u32x4*)(WA2 + ((((wgl * 2 + mi) * 2 + 0) * 32 + ks) << 10) + l16 * 16);
      *(u32x4*)(smem + ((mi * 32 + ks) << 10) + l16 * 16) = v;
    }
  }

  // ---- E0 = emb @ Wih0 + b0, own 32 gate-cols only (L0 wgs). WAi0 via sc-loads. ----
  if (isL0) {
    f32x4 C[2][4];
    #pragma unroll
    for (int a = 0; a < 2; ++a)
      #pragma unroll
      for (int b = 0; b < 4; ++b) C[a][b] = 0.0f;
    for (int ks = 0; ks < 32; ++ks) {
      s16x8 Ah0, Ah1, Al0, Al1;
      LDC(Ah0, WAi0 + ((((wgl * 2 + 0) * 2 + 0) * 32 + ks) << 10) + lane * 16);
      LDC(Ah1, WAi0 + ((((wgl * 2 + 1) * 2 + 0) * 32 + ks) << 10) + lane * 16);
      LDC(Al0, WAi0 + ((((wgl * 2 + 0) * 2 + 1) * 32 + ks) << 10) + lane * 16);
      LDC(Al1, WAi0 + ((((wgl * 2 + 1) * 2 + 1) * 32 + ks) << 10) + lane * 16);
      WAITVM(0);
      #pragma unroll
      for (int v4 = 0; v4 < 4; ++v4) {
        int vb = wv * 4 + v4;
        s16x8 Bh = ld16(embB + (((vb * 2 + 0) * 32 + ks) << 10) + lane * 16);
        s16x8 Bl = ld16(embB + (((vb * 2 + 1) * 32 + ks) << 10) + lane * 16);
        TRIPLE(C[0][v4], Ah0, Al0, Bh, Bl);
        TRIPLE(C[1][v4], Ah1, Al1, Bh, Bl);
      }
    }
    #pragma unroll
    for (int mi = 0; mi < 2; ++mi) {
      int jb4 = wgl * 32 + mi * 16 + l4 * 4;
      int u = jb4 >> 2;
      f32x4 bb;
      #pragma unroll
      for (int r = 0; r < 4; ++r) bb[r] = b0[r * 1024 + u];
      #pragma unroll
      for (int v4 = 0; v4 < 4; ++v4) {
        int v = (wv * 4 + v4) * 16 + l15;
        *(f32x4*)(E0 + v * 4096 + jb4) = C[mi][v4] + bb;
      }
    }
  }

  // ---- c state + L1 bias: one quadrant per wave ----
  float cst;
  {
    const float* cs = isL0 ? c0_in : c1_in;
    cst = cs[(nt_e * 16 + l15) * 1024 + wgl * 8 + mi_e * 4 + l4];
  }
  f32x4 b1z = {0.f, 0.f, 0.f, 0.f};
  if (!isL0) b1z = *(const f32x4*)(b1i + wgl * 32 + mi_e * 16 + (l4 << 2));

  __syncthreads();                                 // staging + E0 complete for this wg
  if (tid == 0) set_flag((isL0 ? f0 : f1) + wgl * 8, 0);   // "staged" release

  // ---- sequential recurrence ----
  if (isL0) {
    for (int t = 0; t < 256; ++t) {
      const int s = t + 1;
      f32x4 C[2][2];
      #pragma unroll
      for (int a = 0; a < 2; ++a)
        #pragma unroll
        for (int b = 0; b < 2; ++b) C[a][b] = 0.0f;

      // prefetch epilogue operands (E0 static during loop; issued before poll)
      int tv = tgt[(nt_e * 16 + l15) * 256 + t];
      f32x4 e0v = *(const f32x4*)(E0 + (size_t)tv * 4096 + wgl * 32 + mi_e * 16 + (l4 << 2));
      pollT<1>(f0, lane, t);
      const char* Bb = h0slot(WA0, h0s0, h0hi, t);
      const int ksb = wv * 8;
      s16x8 P[3][4];
      #pragma unroll
      for (int d = 0; d < 2; ++d)
        #pragma unroll
        for (int q = 0; q < 4; ++q) LDP(P[d][q], Bb + ((q * 32 + ksb + d) << 10) + lane * 16);
      #pragma unroll
      for (int i = 0; i < 8; ++i) {
        const int ks = ksb + i;
        if (i < 6) {
          #pragma unroll
          for (int q = 0; q < 4; ++q) LDP(P[(i + 2) % 3][q], Bb + ((q * 32 + ks + 2) << 10) + lane * 16);
        }
        s16x8 Ah0 = ld16(smem + ((0 * 32 + ks) << 10) + lane * 16);
        s16x8 Ah1 = ld16(smem + ((1 * 32 + ks) << 10) + lane * 16);
        s16x8 Al0 = ld16(smem + ((2 * 32 + ks) << 10) + lane * 16);
        s16x8 Al1 = ld16(smem + ((3 * 32 + ks) << 10) + lane * 16);
        if (i < 6) { WAITVM(8); } else if (i == 6) { WAITVM(4); } else { WAITVM(0); }
        TRIPLE(C[0][0], Ah0, Al0, P[i % 3][0], P[i % 3][2]);
        TRIPLE(C[0][1], Ah0, Al0, P[i % 3][1], P[i % 3][3]);
        TRIPLE(C[1][0], Ah1, Al1, P[i % 3][0], P[i % 3][2]);
        TRIPLE(C[1][1], Ah1, Al1, P[i % 3][1], P[i % 3][3]);
      }

      #pragma unroll
      for (int mi = 0; mi < 2; ++mi)
        #pragma unroll
        for (int nt = 0; nt < 2; ++nt)
          *(f32x4*)(smem + PART + ((wv * 4 + mi * 2 + nt) << 10) + lane * 16) = C[mi][nt];
      __syncthreads();                             // syncA

      {
        f32x4 z = *(const f32x4*)(smem + PART + ((0 * 4 + wv) << 10) + lane * 16);
        #pragma unroll
        for (int w = 1; w < 4; ++w)
          z += *(const f32x4*)(smem + PART + ((w * 4 + wv) << 10) + lane * 16);
        z += e0v;
        float ig = 1.f / (1.f + __expf(-z[0]));
        float fg = 1.f / (1.f + __expf(-z[1]));
        float og = 1.f / (1.f + __expf(-z[3]));
        float cn = fg * cst + ig * tanhf(z[2]);
        float hn = og * tanhf(cn);
        cst = cn;
        unsigned short hb = f2bf(hn);
        unsigned short lb = f2bf(hn - bf2f(hb));
        *(short*)(smem + RP0 + ((0 + nt_e) * 16 + l15) * 16 + (mi_e * 4 + l4) * 2) = (short)hb;
        *(short*)(smem + RP0 + ((2 + nt_e) * 16 + l15) * 16 + (mi_e * 4 + l4) * 2) = (short)lb;
        if (t == 255) {
          int u = wgl * 8 + mi_e * 4 + l4, b = nt_e * 16 + l15;
          out[2097152 + b * 1024 + u] = hn;
          out[2097152 + 32768 + b * 1024 + u] = cn;
        }
      }
      __syncthreads();                             // syncB

      if (wv == 0) {
        char* hd = h0slot(WA0, h0s0, h0hi, s);
        u32x4 v = *(const u32x4*)(smem + RP0 + lane * 16);
        char* dst = hd + (((lane >> 4) * 32 + (wgl >> 2)) << 10) + ((wgl & 3) * 16 + l15) * 16;
        st16c(dst, v);
        asm volatile("s_waitcnt vmcnt(0)" ::: "memory");
        if (lane == 0) set_flag(f0 + wgl * 8, s);
      }
    }
  } else {
    // ---- L1 prologue: ZC[0] = zpre for t=0 (h0 slot 1 @ Wih1) ----
    {
      pollT<2>(f0, lane, 1);
      f32x4 C2[2][2];
      #pragma unroll
      for (int a = 0; a < 2; ++a)
        #pragma unroll
        for (int b = 0; b < 2; ++b) C2[a][b] = 0.0f;
      gemm8g(WA1, h0slot(WA0, h0s0, h0hi, 1), wgl, wv * 8, lane, C2);
      #pragma unroll
      for (int mi = 0; mi < 2; ++mi)
        #pragma unroll
        for (int nt = 0; nt < 2; ++nt)
          *(f32x4*)(smem + ZTMP + ((wv * 4 + mi * 2 + nt) << 10) + lane * 16) = C2[mi][nt];
      __syncthreads();
      f32x4 zq = {0.f, 0.f, 0.f, 0.f};
      #pragma unroll
      for (int w = 0; w < 4; ++w)
        zq += *(const f32x4*)(smem + ZTMP + ((w * 4 + wv) << 10) + lane * 16);
      *(f32x4*)(smem + ZC + ((0 * 4 + wv) << 10) + lane * 16) = zq;
      __syncthreads();
    }

    for (int t = 0; t < 256; ++t) {
      const int s = t + 1;
      const int cur = t & 1, nxt = cur ^ 1;
      const int tz = (t < 255) ? (t + 2) : 256;
      f32x4 C[2][2], C2[2][2];
      #pragma unroll
      for (int a = 0; a < 2; ++a)
        #pragma unroll
        for (int b = 0; b < 2; ++b) { C[a][b] = 0.0f; C2[a][b] = 0.0f; }

      // ---- ONE combined poll: h1_{t-1} ready AND h0_{t+1} ready ----
      poll2c(f1, t, f0, tz, lane);

      // ---- fused dual-GEMM: crit (h1@Whh1) + zpre (h0@Wih1), 8 iters ----
      const char* B1 = h1frag + (size_t)t * 131072;
      const char* B2 = h0slot(WA0, h0s0, h0hi, tz);
      const int ksb = wv * 8;
      s16x8 P1[3][4], AL1[3][2], AH2[3][2], AL2[3][2], P2[3][4];
#define ISS(d, dst) { const int kk = ksb + (d); \
      LDP(P1[dst][0], B1 + ((0 * 32 + kk) << 10) + lane * 16); \
      LDP(P1[dst][1], B1 + ((1 * 32 + kk) << 10) + lane * 16); \
      LDP(P1[dst][2], B1 + ((2 * 32 + kk) << 10) + lane * 16); \
      LDP(P1[dst][3], B1 + ((3 * 32 + kk) << 10) + lane * 16); \
      LDP(AL1[dst][0], WA2 + ((((wgl * 2 + 0) * 2 + 1) * 32 + kk) << 10) + lane * 16); \
      LDP(AL1[dst][1], WA2 + ((((wgl * 2 + 1) * 2 + 1) * 32 + kk) << 10) + lane * 16); \
      LDP(AH2[dst][0], WA1 + ((((wgl * 2 + 0) * 2 + 0) * 32 + kk) << 10) + lane * 16); \
      LDP(AH2[dst][1], WA1 + ((((wgl * 2 + 1) * 2 + 0) * 32 + kk) << 10) + lane * 16); \
      LDP(AL2[dst][0], WA1 + ((((wgl * 2 + 0) * 2 + 1) * 32 + kk) << 10) + lane * 16); \
      LDP(AL2[dst][1], WA1 + ((((wgl * 2 + 1) * 2 + 1) * 32 + kk) << 10) + lane * 16); \
      LDP(P2[dst][0], B2 + ((0 * 32 + kk) << 10) + lane * 16); \
      LDP(P2[dst][1], B2 + ((1 * 32 + kk) << 10) + lane * 16); \
      LDP(P2[dst][2], B2 + ((2 * 32 + kk) << 10) + lane * 16); \
      LDP(P2[dst][3], B2 + ((3 * 32 + kk) << 10) + lane * 16); }
      ISS(0, 0)
      ISS(1, 1)
      #pragma unroll
      for (int i = 0; i < 8; ++i) {
        const int ks = ksb + i;
        if (i < 6) ISS(i + 2, (i + 2) % 3)
        s16x8 Ah0c = ld16(smem + ((0 * 32 + ks) << 10) + lane * 16);
        s16x8 Ah1c = ld16(smem + ((1 * 32 + ks) << 10) + lane * 16);
        if (i < 6) { waitvm<28>(); } else if (i == 6) { waitvm<14>(); } else { waitvm<0>(); }
        TRIPLE(C[0][0], Ah0c, AL1[i % 3][0], P1[i % 3][0], P1[i % 3][2]);
        TRIPLE(C[0][1], Ah0c, AL1[i % 3][0], P1[i % 3][1], P1[i % 3][3]);
        TRIPLE(C[1][0], Ah1c, AL1[i % 3][1], P1[i % 3][0], P1[i % 3][2]);
        TRIPLE(C[1][1], Ah1c, AL1[i % 3][1], P1[i % 3][1], P1[i % 3][3]);
        TRIPLE(C2[0][0], AH2[i % 3][0], AL2[i % 3][0], P2[i % 3][0], P2[i % 3][2]);
        TRIPLE(C2[0][1], AH2[i % 3][0], AL2[i % 3][0], P2[i % 3][1], P2[i % 3][3]);
        TRIPLE(C2[1][0], AH2[i % 3][1], AL2[i % 3][1], P2[i % 3][0], P2[i % 3][2]);
        TRIPLE(C2[1][1], AH2[i % 3][1], AL2[i % 3][1], P2[i % 3][1], P2[i % 3][3]);
      }
#undef ISS

      #pragma unroll
      for (int mi = 0; mi < 2; ++mi)
        #pragma unroll
        for (int nt = 0; nt < 2; ++nt) {
          *(f32x4*)(smem + PART1 + ((wv * 4 + mi * 2 + nt) << 10) + lane * 16) = C[mi][nt];
          *(f32x4*)(smem + ZTMP  + ((wv * 4 + mi * 2 + nt) << 10) + lane * 16) = C2[mi][nt];
        }
      __syncthreads();                             // syncA

      {
        f32x4 z = {0.f, 0.f, 0.f, 0.f};
        #pragma unroll
        for (int w = 0; w < 4; ++w)
          z += *(const f32x4*)(smem + PART1 + ((w * 4 + wv) << 10) + lane * 16);
        z += *(const f32x4*)(smem + ZC + ((cur * 4 + wv) << 10) + lane * 16);
        z += b1z;
        float ig = 1.f / (1.f + __expf(-z[0]));
        float fg = 1.f / (1.f + __expf(-z[1]));
        float og = 1.f / (1.f + __expf(-z[3]));
        float cn = fg * cst + ig * tanhf(z[2]);
        float hn = og * tanhf(cn);
        cst = cn;
        unsigned short hb = f2bf(hn);
        unsigned short lb = f2bf(hn - bf2f(hb));
        *(short*)(smem + RP1 + ((0 + nt_e) * 16 + l15) * 16 + (mi_e * 4 + l4) * 2) = (short)hb;
        *(short*)(smem + RP1 + ((2 + nt_e) * 16 + l15) * 16 + (mi_e * 4 + l4) * 2) = (short)lb;
        if (t == 255) {
          int u = wgl * 8 + mi_e * 4 + l4, b = nt_e * 16 + l15;
          out[2097152 + 65536 + b * 1024 + u] = hn;
          out[2097152 + 65536 + 32768 + b * 1024 + u] = cn;
        }
        // reduce next-step zpre (lane-local target; no extra barrier needed)
        f32x4 zq = {0.f, 0.f, 0.f, 0.f};
        #pragma unroll
        for (int w = 0; w < 4; ++w)
          zq += *(const f32x4*)(smem + ZTMP + ((w * 4 + wv) << 10) + lane * 16);
        *(f32x4*)(smem + ZC + ((nxt * 4 + wv) << 10) + lane * 16) = zq;
      }
      __syncthreads();                             // syncB

      if (wv == 0) {
        char* hd = h1frag + (size_t)s * 131072;
        u32x4 v = *(const u32x4*)(smem + RP1 + lane * 16);
        char* dst = hd + (((lane >> 4) * 32 + (wgl >> 2)) << 10) + ((wgl & 3) * 16 + l15) * 16;
        st16c(dst, v);
        asm volatile("s_waitcnt vmcnt(0)" ::: "memory");
        if (lane == 0) set_flag(f1 + wgl * 8, s);
      }
    }
  }

  // ---- projection: logits[b][t][v] = h1_t @ W_out + b_out ; one t per CU ----
  // L0 wgs (finish first) take EARLY t (flags long set); L1 wgs take late t.
  {
    const int tp = isL0 ? wgl : (128 + wgl);
    pollT<32>(f1, lane, tp + 1);
    const char* A = h1frag + (size_t)(tp + 1) * 131072;
    f32x4 C[2][4];
    #pragma unroll
    for (int a = 0; a < 2; ++a)
      #pragma unroll
      for (int b = 0; b < 4; ++b) C[a][b] = 0.0f;
    s16x8 QA[4], QB[4];
    #pragma unroll
    for (int q = 0; q < 4; ++q) LDP(QA[q], A + ((q * 32 + 0) << 10) + lane * 16);
    for (int kk = 0; kk < 16; ++kk) {
      const int ks = kk * 2;
      #pragma unroll
      for (int q = 0; q < 4; ++q) LDP(QB[q], A + ((q * 32 + ks + 1) << 10) + lane * 16);
      asm volatile("s_waitcnt vmcnt(4)" ::: "memory");
      __builtin_amdgcn_sched_barrier(0);
      #pragma unroll
      for (int v4 = 0; v4 < 4; ++v4) {
        int vb = wv * 4 + v4;
        s16x8 Bh = ld16(WoutB + (((vb * 2 + 0) * 32 + ks) << 10) + lane * 16);
        s16x8 Bl = ld16(WoutB + (((vb * 2 + 1) * 32 + ks) << 10) + lane * 16);
        C[0][v4] = MF(QA[0], Bh, C[0][v4]); C[0][v4] = MF(QA[0], Bl, C[0][v4]); C[0][v4] = MF(QA[2], Bh, C[0][v4]);
        C[1][v4] = MF(QA[1], Bh, C[1][v4]); C[1][v4] = MF(QA[1], Bl, C[1][v4]); C[1][v4] = MF(QA[3], Bh, C[1][v4]);
      }
      if (kk < 15) {
        #pragma unroll
        for (int q = 0; q < 4; ++q) LDP(QA[q], A + ((q * 32 + ks + 2) << 10) + lane * 16);
        asm volatile("s_waitcnt vmcnt(4)" ::: "memory");
      } else {
        asm volatile("s_waitcnt vmcnt(0)" ::: "memory");
      }
      __builtin_amdgcn_sched_barrier(0);
      #pragma unroll
      for (int v4 = 0; v4 < 4; ++v4) {
        int vb = wv * 4 + v4;
        s16x8 Bh = ld16(WoutB + (((vb * 2 + 0) * 32 + ks + 1) << 10) + lane * 16);
        s16x8 Bl = ld16(WoutB + (((vb * 2 + 1) * 32 + ks + 1) << 10) + lane * 16);
        C[0][v4] = MF(QB[0], Bh, C[0][v4]); C[0][v4] = MF(QB[0], Bl, C[0][v4]); C[0][v4] = MF(QB[2], Bh, C[0][v4]);
        C[1][v4] = MF(QB[1], Bh, C[1][v4]); C[1][v4] = MF(QB[1], Bl, C[1][v4]); C[1][v4] = MF(QB[3], Bh, C[1][v4]);
      }
    }
    #pragma unroll
    for (int nt = 0; nt < 2; ++nt)
      #pragma unroll
      for (int v4 = 0; v4 < 4; ++v4) {
        int v = (wv * 4 + v4) * 16 + l15;
        float bo = b_out[v];
        #pragma unroll
        for (int r = 0; r < 4; ++r) {
          int b = nt * 16 + l4 * 4 + r;
          out[((size_t)b * 256 + tp) * 256 + v] = C[nt][v4][r] + bo;
        }
      }
  }
}

extern "C" void kernel_launch(void* const* d_in, const int* in_sizes, int n_in,
                              void* d_out, int out_size, void* d_ws, size_t ws_size,
                              hipStream_t stream) {
  const int*   targets = (const int*)d_in[1];
  const float* h0_in   = (const float*)d_in[2];
  const float* c0_in   = (const float*)d_in[3];
  const float* h1_in   = (const float*)d_in[4];
  const float* c1_in   = (const float*)d_in[5];
  const float* emb     = (const float*)d_in[6];
  const float* W_ih0   = (const float*)d_in[7];
  const float* W_hh0   = (const float*)d_in[8];
  const float* b0      = (const float*)d_in[9];
  const float* W_ih1   = (const float*)d_in[10];
  const float* W_hh1   = (const float*)d_in[11];
  const float* b1      = (const float*)d_in[12];
  const float* W_out   = (const float*)d_in[13];
  const float* b_out   = (const float*)d_in[14];
  float* out = (float*)d_out;

  char* ws = (char*)d_ws;
  char*  WA0    = ws;                         // Whh0 A-frags hi/lo 16MB; becomes h0 slots 1..128
  char*  WA1    = ws + 16777216;              // Wih1 hi/lo (streamed every step, L2-hot)
  char*  WA2    = ws + 33554432;              // Whh1 (hi staged to LDS, lo streamed)
  char*  WoutB  = ws + 50331648;              // W_out B-frags, 1MB
  char*  embB   = ws + 51380224;              // emb B-frags, 1MB
  float* E0     = (float*)(ws + 52428800);    // 4MB f32
  float* b1i    = (float*)(ws + 56623104);    // 16KB
  int*   f0     = (int*)(ws + 56639488);      // flag array, 4KB (128 x stride 32B)
  int*   f1     = (int*)(ws + 56643584);      // flag array, 4KB
  char*  h0s0   = ws + 56647680;              // h0 slot 0, 128KB
  char*  h0hi   = ws + 56778752;              // h0 slots 129..256, 16MB
  char*  h1frag = ws + 73555968;              // 257 slots x 128KB (~33.7MB) -> end ~102.3MB
  char*  WAi0   = h1frag + 16777216;          // Wih0 A-frags alias h1 slots 128..255
                                              // (read via sc-loads at E0; slot 128 written step 127)

  prep_misc <<<18,   256, 0, stream>>>(b1, b1i, f0, f1);
  prep_wfrag<<<8192, 256, 0, stream>>>(W_hh0, W_ih1, W_hh1, W_ih0, WA0, WA1, WA2, WAi0);
  prep_bfrag<<<256,  256, 0, stream>>>(emb, W_out, embB, WoutB);
  prep_hinit<<<32,   256, 0, stream>>>(h0_in, h1_in, h0s0, h1frag);

  hipFuncSetAttribute(reinterpret_cast<const void*>(lstm_persist),
                      hipFuncAttributeMaxDynamicSharedMemorySize, 148480);
  lstm_persist<<<256, 256, 148480, stream>>>(
      targets, c0_in, c1_in, b0, b_out,
      WA0, WA1, WA2, WAi0, WoutB, embB,
      E0, b1i, h0s0, h0hi, h1frag, f0, f1, out);
}

// Round 12
// 2105.790 us; speedup vs baseline: 1.6113x; 1.1455x over previous
//
#include <hip/hip_runtime.h>
#include <cstdint>

// CharRNN 2-layer LSTM, B=32,T=256,H=1024,V=256. Persistent kernel, round 12:
//   Group A (wgs 0..127):  L0 chain, 8 units each — r7 verbatim.
//   Group B (wgs 128..191): z1a_t = h0_t @ Wih1, 64 gate-cols each (Wih1-hi in LDS,
//      lo streamed); stores 8KB f32 to 4-slot ring; flags f2. Off the critical chain.
//   Group C (wgs 192..255): L1 chain, 16 units each. ONE GEMM per step (h1@Whh1,
//      Whh1-hi in LDS, lo streamed, K/4 per wave, 8 iters, 2-deep prefetch) +
//      coherent 8KB z1a read (issued pre-GEMM). Wave0-only epilogue; ONE barrier/step;
//      PART reuse ordered by the flag chain (waves1-3's next write gated by wave0's flag).
//   math identical to r7: mfma split-bf16 (hi*hi+hi*lo+lo*hi); same summation orders.

typedef float    f32x4 __attribute__((ext_vector_type(4)));
typedef short    s16x8 __attribute__((ext_vector_type(8)));
typedef unsigned u32x4 __attribute__((ext_vector_type(4)));

#define DEV __device__ __forceinline__

DEV unsigned short f2bf(float x){
  unsigned u = __builtin_bit_cast(unsigned, x);
  unsigned r = (u + 0x7fffu + ((u >> 16) & 1u)) >> 16;   // round-nearest-even
  return (unsigned short)r;
}
DEV float bf2f(unsigned short b){ return __builtin_bit_cast(float, ((unsigned)b) << 16); }

DEV s16x8 ld16(const void* p){ return *(const s16x8*)p; }

DEV f32x4 MF(s16x8 a, s16x8 b, f32x4 c){
  return __builtin_amdgcn_mfma_f32_16x16x32_bf16(a, b, c, 0, 0, 0);
}

// coherent (bypass L1/L2) 16B load — for aliased/ring regions
#define LDC(dst, ptr)  asm volatile("global_load_dwordx4 %0, %1, off sc0 sc1" : "=v"(dst) : "v"(ptr))
// plain cached 16B load
#define LDP(dst, ptr)  asm volatile("global_load_dwordx4 %0, %1, off"         : "=v"(dst) : "v"(ptr))
#define WAITVM(n) do { asm volatile("s_waitcnt vmcnt(" #n ")" ::: "memory"); \
                       __builtin_amdgcn_sched_barrier(0); } while (0)
#define CFENCE()  asm volatile("" ::: "memory")
#define TRIPLE(Cmn, Ahm, Alm, Bhn, Bln) do { \
    Cmn = MF(Ahm, Bhn, Cmn); Cmn = MF(Ahm, Bln, Cmn); Cmn = MF(Alm, Bhn, Cmn); } while (0)

DEV void st16c(void* p, u32x4 v){   // coherent 16B store (write-through)
  asm volatile("global_store_dwordx4 %0, %1, off sc0 sc1" :: "v"(p), "v"(v) : "memory");
}
DEV void st16cf(void* p, f32x4 v){ st16c(p, __builtin_bit_cast(u32x4, v)); }
DEV void set_flag(int* p, int v){
  __hip_atomic_store(p, v, __ATOMIC_RELAXED, __HIP_MEMORY_SCOPE_AGENT);
}
// poll over 128-entry flag array (stride 8 ints)
template<int SLP>
DEV void pollT(const int* f, int lane, int target){
  const int* p0 = f + lane * 8;
  const int* p1 = f + (64 + lane) * 8;
  for (;;) {
    int a = __hip_atomic_load(p0, __ATOMIC_RELAXED, __HIP_MEMORY_SCOPE_AGENT);
    int b = __hip_atomic_load(p1, __ATOMIC_RELAXED, __HIP_MEMORY_SCOPE_AGENT);
    if (__all((a >= target) && (b >= target))) break;
    __builtin_amdgcn_s_sleep(SLP);
  }
  CFENCE();
}
// C's poll: all f1 >= t1 (64 real entries) AND all f2 >= t2
DEV void pollC(const int* f1p, int t1, const int* f2p, int t2, int lane){
  const int* a = f1p + lane * 8;
  const int* b = f2p + lane * 8;
  for (;;) {
    int x = __hip_atomic_load(a, __ATOMIC_RELAXED, __HIP_MEMORY_SCOPE_AGENT);
    int y = __hip_atomic_load(b, __ATOMIC_RELAXED, __HIP_MEMORY_SCOPE_AGENT);
    if (__all((x >= t1) && (y >= t2))) break;
    __builtin_amdgcn_s_sleep(1);
  }
  CFENCE();
}
// B's poll: f0 >= t0 (128) AND f2 >= t2 AND f1 >= t1
DEV void pollB(const int* f0p, int t0, const int* f2p, int t2,
               const int* f1p, int t1, int lane){
  const int* a0 = f0p + lane * 8;
  const int* a1 = f0p + (64 + lane) * 8;
  const int* b  = f2p + lane * 8;
  const int* c  = f1p + lane * 8;
  for (;;) {
    int x0 = __hip_atomic_load(a0, __ATOMIC_RELAXED, __HIP_MEMORY_SCOPE_AGENT);
    int x1 = __hip_atomic_load(a1, __ATOMIC_RELAXED, __HIP_MEMORY_SCOPE_AGENT);
    int y  = __hip_atomic_load(b,  __ATOMIC_RELAXED, __HIP_MEMORY_SCOPE_AGENT);
    int z  = __hip_atomic_load(c,  __ATOMIC_RELAXED, __HIP_MEMORY_SCOPE_AGENT);
    if (__all((x0 >= t0) && (x1 >= t0) && (y >= t2) && (z >= t1))) break;
    __builtin_amdgcn_s_sleep(2);
  }
  CFENCE();
}
// h0 slot address: 0 -> s0 buf; 1..128 -> aliased over WA0; 129..256 -> hi buf
DEV char* h0slot(char* wa0, char* s0, char* hi, int s){
  return (s == 0) ? s0 : ((s <= 128) ? wa0 + ((size_t)(s - 1) << 17)
                                     : hi  + ((size_t)(s - 129) << 17));
}

// 16-unit half-gemm: A-hi (4 blocks) from LDS, A-lo streamed (4/iter), B 4 q-rows/iter
DEV void gemm16u(const char* smemA, const char* ALb, int jb0, const char* Bb,
                 int ksb, int lane, f32x4 (&C)[4][2]) {
  s16x8 P[3][4], AL[3][4];
  #pragma unroll
  for (int d = 0; d < 2; ++d) {
    #pragma unroll
    for (int q = 0; q < 4; ++q) LDP(P[d][q], Bb + ((q * 32 + ksb + d) << 10) + lane * 16);
    #pragma unroll
    for (int m = 0; m < 4; ++m)
      LDP(AL[d][m], ALb + ((((jb0 + m) * 2 + 1) * 32 + ksb + d) << 10) + lane * 16);
  }
  #pragma unroll
  for (int i = 0; i < 8; ++i) {
    const int ks = ksb + i;
    if (i < 6) {
      #pragma unroll
      for (int q = 0; q < 4; ++q) LDP(P[(i + 2) % 3][q], Bb + ((q * 32 + ks + 2) << 10) + lane * 16);
      #pragma unroll
      for (int m = 0; m < 4; ++m)
        LDP(AL[(i + 2) % 3][m], ALb + ((((jb0 + m) * 2 + 1) * 32 + ks + 2) << 10) + lane * 16);
    }
    s16x8 Ah[4];
    #pragma unroll
    for (int m = 0; m < 4; ++m) Ah[m] = ld16(smemA + ((m * 32 + ks) << 10) + lane * 16);
    if (i < 6) { WAITVM(16); } else if (i == 6) { WAITVM(8); } else { WAITVM(0); }
    #pragma unroll
    for (int m = 0; m < 4; ++m) {
      TRIPLE(C[m][0], Ah[m], AL[i % 3][m], P[i % 3][0], P[i % 3][2]);
      TRIPLE(C[m][1], Ah[m], AL[i % 3][m], P[i % 3][1], P[i % 3][3]);
    }
  }
}

// ---------------- prep: W[k][g*H+u] -> A-frag hi/lo bf16 [jb256][part2][ks32][64*16B] ----
__global__ void prep_wfrag(const float* __restrict__ W0, const float* __restrict__ W1,
                           const float* __restrict__ W2, const float* __restrict__ W3,
                           char* D0, char* D1, char* D2, char* D3) {
  int gid = blockIdx.x * 256 + threadIdx.x;       // 4*256*32*64 = 2M
  int lane = gid & 63, ks = (gid >> 6) & 31, jb = (gid >> 11) & 255, mat = gid >> 19;
  const float* S = (mat == 0) ? W0 : (mat == 1) ? W1 : (mat == 2) ? W2 : W3;
  char* D = (mat == 0) ? D0 : (mat == 1) ? D1 : (mat == 2) ? D2 : D3;
  int jp = jb * 16 + (lane & 15), u = jp >> 2, g = jp & 3;
  int kb = ks * 32 + (lane >> 4) * 8;
  s16x8 vh, vl;
  #pragma unroll
  for (int i = 0; i < 8; ++i) {
    float x = S[(kb + i) * 4096 + g * 1024 + u];
    unsigned short h = f2bf(x);
    vh[i] = (short)h;
    vl[i] = (short)f2bf(x - bf2f(h));
  }
  *(s16x8*)(D + (((jb * 2 + 0) * 32 + ks) << 10) + lane * 16) = vh;
  *(s16x8*)(D + (((jb * 2 + 1) * 32 + ks) << 10) + lane * 16) = vl;
}

// ---------------- prep: emb [v][k] and W_out [k][v] -> B-frag hi/lo [vb16][part2][ks32] ----
__global__ void prep_bfrag(const float* __restrict__ emb, const float* __restrict__ Wout,
                           char* Demb, char* Dwout) {
  int gid = blockIdx.x * 256 + threadIdx.x;       // 2*16*32*64 = 64K
  int lane = gid & 63, ks = (gid >> 6) & 31, vb = (gid >> 11) & 15, which = gid >> 15;
  int v = vb * 16 + (lane & 15), kb = ks * 32 + (lane >> 4) * 8;
  s16x8 vh, vl;
  #pragma unroll
  for (int i = 0; i < 8; ++i) {
    float x = which ? Wout[(kb + i) * 256 + v] : emb[v * 1024 + kb + i];
    unsigned short h = f2bf(x);
    vh[i] = (short)h;
    vl[i] = (short)f2bf(x - bf2f(h));
  }
  char* D = which ? Dwout : Demb;
  *(s16x8*)(D + (((vb * 2 + 0) * 32 + ks) << 10) + lane * 16) = vh;
  *(s16x8*)(D + (((vb * 2 + 1) * 32 + ks) << 10) + lane * 16) = vl;
}

// ---------------- prep: h0_in/h1_in [b][k] f32 -> h-frag slot0 [part2][nt2][ks32] ----
__global__ void prep_hinit(const float* __restrict__ h0, const float* __restrict__ h1,
                           char* h0s0, char* h1f) {
  int gid = blockIdx.x * 256 + threadIdx.x;       // 2*2*32*64 = 8192
  int lane = gid & 63, ks = (gid >> 6) & 31, nt = (gid >> 11) & 1, which = gid >> 12;
  const float* S = which ? h1 : h0;
  char* D = which ? h1f : h0s0;                   // slot 0 of each
  int b = nt * 16 + (lane & 15), kb = ks * 32 + (lane >> 4) * 8;
  s16x8 vh, vl;
  #pragma unroll
  for (int i = 0; i < 8; ++i) {
    float x = S[b * 1024 + kb + i];
    unsigned short h = f2bf(x);
    vh[i] = (short)h;
    vl[i] = (short)f2bf(x - bf2f(h));
  }
  *(s16x8*)(D + (((0 * 2 + nt) * 32 + ks) << 10) + lane * 16) = vh;
  *(s16x8*)(D + (((1 * 2 + nt) * 32 + ks) << 10) + lane * 16) = vl;
}

// ---------------- prep: flags (sentinels for 64-entry arrays), b1 interleave ----
__global__ void prep_misc(const float* __restrict__ b1, float* b1i,
                          int* f0a, int* f1a, int* f2a) {
  int i = blockIdx.x * 256 + threadIdx.x;         // 4608
  if (i < 4096) b1i[i] = b1[(i & 3) * 1024 + (i >> 2)];
  if (i < 1024) {
    f0a[i] = -1;
    f1a[i] = (i >= 512) ? 0x7fffffff : -1;
    f2a[i] = (i >= 512) ? 0x7fffffff : -1;
  }
}

// ---------------- the persistent LSTM kernel ----------------
__global__ __launch_bounds__(256, 1) void lstm_persist(
    const int* __restrict__ tgt,
    const float* __restrict__ c0_in, const float* __restrict__ c1_in,
    const float* __restrict__ b0, const float* __restrict__ b_out,
    char* __restrict__ WA0, const char* __restrict__ WA1, const char* __restrict__ WA2,
    const char* __restrict__ WAi0, const char* __restrict__ WoutB, const char* __restrict__ embB,
    float* __restrict__ E0, const float* __restrict__ b1i,
    char* __restrict__ h0s0, char* __restrict__ h0hi, char* __restrict__ h1frag,
    char* __restrict__ z1ring,
    int* __restrict__ f0, int* __restrict__ f1, int* __restrict__ f2,
    float* __restrict__ out)
{
  extern __shared__ char smem[];
  // A: frag [0,128K); PARTA 128K..144K; RP0 at 147456 (1KB)
  // B/C: frag [0,128K); PARTB 128K..152K (24 slots); RP1 at 155648 (2KB)
  constexpr int PARTA = 131072;
  constexpr int RP0   = 147456;
  constexpr int PARTB = 131072;
  constexpr int RP1   = 155648;
  const int tid = threadIdx.x, lane = tid & 63, wv = tid >> 6;
  const int wg = blockIdx.x;
  const int l15 = lane & 15, l4 = lane >> 4;

  // one-time cross-replay safety: invalidate stale L1/L2 lines
  __builtin_amdgcn_fence(__ATOMIC_ACQUIRE, "agent");

  if (wg < 128) {
    // ==================== GROUP A: layer-0 chain (r7 verbatim) ====================
    const int wgl = wg;
    const int mi_e = wv >> 1, nt_e = wv & 1;
    {
      u32x4 tmp[8];
      for (int blk = 0; blk < 4; ++blk) {
        #pragma unroll
        for (int q = 0; q < 8; ++q) {
          int idx = tid + (blk * 8 + q) * 256;
          int l16 = idx & 63, ks = (idx >> 6) & 31, mi = (idx >> 11) & 1, part = idx >> 12;
          LDC(tmp[q], WA0 + ((((wgl * 2 + mi) * 2 + part) * 32 + ks) << 10) + l16 * 16);
        }
        WAITVM(0);
        #pragma unroll
        for (int q = 0; q < 8; ++q) {
          int idx = tid + (blk * 8 + q) * 256;
          int l16 = idx & 63, ks = (idx >> 6) & 31, mi = (idx >> 11) & 1, part = idx >> 12;
          *(u32x4*)(smem + (((part * 2 + mi) * 32 + ks) << 10) + l16 * 16) = tmp[q];
        }
      }
    }
    {   // E0 = emb @ Wih0 + b0 (own 32 gate-cols)
      f32x4 C[2][4];
      #pragma unroll
      for (int a = 0; a < 2; ++a)
        #pragma unroll
        for (int b = 0; b < 4; ++b) C[a][b] = 0.0f;
      for (int ks = 0; ks < 32; ++ks) {
        s16x8 Ah0, Ah1, Al0, Al1;
        LDC(Ah0, WAi0 + ((((wgl * 2 + 0) * 2 + 0) * 32 + ks) << 10) + lane * 16);
        LDC(Ah1, WAi0 + ((((wgl * 2 + 1) * 2 + 0) * 32 + ks) << 10) + lane * 16);
        LDC(Al0, WAi0 + ((((wgl * 2 + 0) * 2 + 1) * 32 + ks) << 10) + lane * 16);
        LDC(Al1, WAi0 + ((((wgl * 2 + 1) * 2 + 1) * 32 + ks) << 10) + lane * 16);
        WAITVM(0);
        #pragma unroll
        for (int v4 = 0; v4 < 4; ++v4) {
          int vb = wv * 4 + v4;
          s16x8 Bh = ld16(embB + (((vb * 2 + 0) * 32 + ks) << 10) + lane * 16);
          s16x8 Bl = ld16(embB + (((vb * 2 + 1) * 32 + ks) << 10) + lane * 16);
          TRIPLE(C[0][v4], Ah0, Al0, Bh, Bl);
          TRIPLE(C[1][v4], Ah1, Al1, Bh, Bl);
        }
      }
      #pragma unroll
      for (int mi = 0; mi < 2; ++mi) {
        int jb4 = wgl * 32 + mi * 16 + l4 * 4;
        int u = jb4 >> 2;
        f32x4 bb;
        #pragma unroll
        for (int r = 0; r < 4; ++r) bb[r] = b0[r * 1024 + u];
        #pragma unroll
        for (int v4 = 0; v4 < 4; ++v4) {
          int v = (wv * 4 + v4) * 16 + l15;
          *(f32x4*)(E0 + v * 4096 + jb4) = C[mi][v4] + bb;
        }
      }
    }
    float cst = c0_in[(nt_e * 16 + l15) * 1024 + wgl * 8 + mi_e * 4 + l4];
    __syncthreads();
    if (tid == 0) set_flag(f0 + wgl * 8, 0);

    for (int t = 0; t < 256; ++t) {
      const int s = t + 1;
      f32x4 C[2][2];
      #pragma unroll
      for (int a = 0; a < 2; ++a)
        #pragma unroll
        for (int b = 0; b < 2; ++b) C[a][b] = 0.0f;
      int tv = tgt[(nt_e * 16 + l15) * 256 + t];
      f32x4 e0v = *(const f32x4*)(E0 + (size_t)tv * 4096 + wgl * 32 + mi_e * 16 + (l4 << 2));
      pollT<1>(f0, lane, t);
      const char* Bb = h0slot(WA0, h0s0, h0hi, t);
      const int ksb = wv * 8;
      s16x8 P[3][4];
      #pragma unroll
      for (int d = 0; d < 2; ++d)
        #pragma unroll
        for (int q = 0; q < 4; ++q) LDP(P[d][q], Bb + ((q * 32 + ksb + d) << 10) + lane * 16);
      #pragma unroll
      for (int i = 0; i < 8; ++i) {
        const int ks = ksb + i;
        if (i < 6) {
          #pragma unroll
          for (int q = 0; q < 4; ++q) LDP(P[(i + 2) % 3][q], Bb + ((q * 32 + ks + 2) << 10) + lane * 16);
        }
        s16x8 Ah0 = ld16(smem + ((0 * 32 + ks) << 10) + lane * 16);
        s16x8 Ah1 = ld16(smem + ((1 * 32 + ks) << 10) + lane * 16);
        s16x8 Al0 = ld16(smem + ((2 * 32 + ks) << 10) + lane * 16);
        s16x8 Al1 = ld16(smem + ((3 * 32 + ks) << 10) + lane * 16);
        if (i < 6) { WAITVM(8); } else if (i == 6) { WAITVM(4); } else { WAITVM(0); }
        TRIPLE(C[0][0], Ah0, Al0, P[i % 3][0], P[i % 3][2]);
        TRIPLE(C[0][1], Ah0, Al0, P[i % 3][1], P[i % 3][3]);
        TRIPLE(C[1][0], Ah1, Al1, P[i % 3][0], P[i % 3][2]);
        TRIPLE(C[1][1], Ah1, Al1, P[i % 3][1], P[i % 3][3]);
      }
      #pragma unroll
      for (int mi = 0; mi < 2; ++mi)
        #pragma unroll
        for (int nt = 0; nt < 2; ++nt)
          *(f32x4*)(smem + PARTA + ((wv * 4 + mi * 2 + nt) << 10) + lane * 16) = C[mi][nt];
      __syncthreads();                             // syncA
      {
        f32x4 z = *(const f32x4*)(smem + PARTA + ((0 * 4 + wv) << 10) + lane * 16);
        #pragma unroll
        for (int w = 1; w < 4; ++w)
          z += *(const f32x4*)(smem + PARTA + ((w * 4 + wv) << 10) + lane * 16);
        z += e0v;
        float ig = 1.f / (1.f + __expf(-z[0]));
        float fg = 1.f / (1.f + __expf(-z[1]));
        float og = 1.f / (1.f + __expf(-z[3]));
        float cn = fg * cst + ig * tanhf(z[2]);
        float hn = og * tanhf(cn);
        cst = cn;
        unsigned short hb = f2bf(hn);
        unsigned short lb = f2bf(hn - bf2f(hb));
        *(short*)(smem + RP0 + ((0 + nt_e) * 16 + l15) * 16 + (mi_e * 4 + l4) * 2) = (short)hb;
        *(short*)(smem + RP0 + ((2 + nt_e) * 16 + l15) * 16 + (mi_e * 4 + l4) * 2) = (short)lb;
        if (t == 255) {
          int u = wgl * 8 + mi_e * 4 + l4, b = nt_e * 16 + l15;
          out[2097152 + b * 1024 + u] = hn;
          out[2097152 + 32768 + b * 1024 + u] = cn;
        }
      }
      __syncthreads();                             // syncB
      if (wv == 0) {
        char* hd = h0slot(WA0, h0s0, h0hi, s);
        u32x4 v = *(const u32x4*)(smem + RP0 + lane * 16);
        char* dst = hd + (((lane >> 4) * 32 + (wgl >> 2)) << 10) + ((wgl & 3) * 16 + l15) * 16;
        st16c(dst, v);
        asm volatile("s_waitcnt vmcnt(0)" ::: "memory");
        if (lane == 0) set_flag(f0 + wgl * 8, s);
      }
    }
  } else if (wg < 192) {
    // ==================== GROUP B: z1a producer ====================
    const int wgb = wg - 128;
    const int jb0 = wgb * 4;
    for (int idx = tid; idx < 8192; idx += 256) {  // Wih1-hi 128KB -> LDS
      int l16 = idx & 63, ks = (idx >> 6) & 31, m = idx >> 11;
      u32x4 v = *(const u32x4*)(WA1 + ((((jb0 + m) * 2 + 0) * 32 + ks) << 10) + l16 * 16);
      *(u32x4*)(smem + ((m * 32 + ks) << 10) + l16 * 16) = v;
    }
    __syncthreads();
    if (tid == 0) set_flag(f2 + wgb * 8, 0);

    for (int t = 0; t < 256; ++t) {
      const int rt = (t >= 4) ? (t - 3) : 0;
      pollB(f0, t + 1, f2, t, f1, rt, lane);
      f32x4 Cb[4][2];
      #pragma unroll
      for (int a = 0; a < 4; ++a)
        #pragma unroll
        for (int b = 0; b < 2; ++b) Cb[a][b] = 0.0f;
      gemm16u(smem, WA1, jb0, h0slot(WA0, h0s0, h0hi, t + 1), wv * 8, lane, Cb);
      if (wv) {
        #pragma unroll
        for (int m = 0; m < 4; ++m)
          #pragma unroll
          for (int n = 0; n < 2; ++n)
            *(f32x4*)(smem + PARTB + (((wv - 1) * 8 + m * 2 + n) << 10) + lane * 16) = Cb[m][n];
      }
      __syncthreads();
      if (wv == 0) {
        char* zs = z1ring + ((size_t)(t & 3) * 64 + wgb) * 8192;
        #pragma unroll
        for (int m = 0; m < 4; ++m)
          #pragma unroll
          for (int n = 0; n < 2; ++n) {
            f32x4 z = Cb[m][n];
            #pragma unroll
            for (int w = 1; w < 4; ++w)
              z += *(const f32x4*)(smem + PARTB + (((w - 1) * 8 + m * 2 + n) << 10) + lane * 16);
            st16cf(zs + ((m * 2 + n) * 64 + lane) * 16, z);
          }
        asm volatile("s_waitcnt vmcnt(0)" ::: "memory");
        if (lane == 0) set_flag(f2 + wgb * 8, t + 1);
      }
    }
  } else {
    // ==================== GROUP C: layer-1 chain ====================
    const int wgc = wg - 192;
    const int jb0 = wgc * 4;
    for (int idx = tid; idx < 8192; idx += 256) {  // Whh1-hi 128KB -> LDS
      int l16 = idx & 63, ks = (idx >> 6) & 31, m = idx >> 11;
      u32x4 v = *(const u32x4*)(WA2 + ((((jb0 + m) * 2 + 0) * 32 + ks) << 10) + l16 * 16);
      *(u32x4*)(smem + ((m * 32 + ks) << 10) + l16 * 16) = v;
    }
    f32x4 b1z4[4];
    float cst[4][2];
    if (wv == 0) {
      #pragma unroll
      for (int m = 0; m < 4; ++m) {
        b1z4[m] = *(const f32x4*)(b1i + wgc * 64 + m * 16 + (l4 << 2));
        #pragma unroll
        for (int n = 0; n < 2; ++n)
          cst[m][n] = c1_in[(n * 16 + l15) * 1024 + wgc * 16 + m * 4 + l4];
      }
    }
    __syncthreads();
    if (tid == 0) set_flag(f1 + wgc * 8, 0);

    for (int t = 0; t < 256; ++t) {
      const int s = t + 1;
      pollC(f1, t, f2, s, lane);
      f32x4 zA[4][2];
      if (wv == 0) {
        const char* zs = z1ring + ((size_t)(t & 3) * 64 + wgc) * 8192;
        #pragma unroll
        for (int m = 0; m < 4; ++m)
          #pragma unroll
          for (int n = 0; n < 2; ++n)
            LDC(zA[m][n], zs + ((m * 2 + n) * 64 + lane) * 16);
      }
      f32x4 Cc[4][2];
      #pragma unroll
      for (int a = 0; a < 4; ++a)
        #pragma unroll
        for (int b = 0; b < 2; ++b) Cc[a][b] = 0.0f;
      gemm16u(smem, WA2, jb0, h1frag + (size_t)t * 131072, wv * 8, lane, Cc);
      if (wv) {
        #pragma unroll
        for (int m = 0; m < 4; ++m)
          #pragma unroll
          for (int n = 0; n < 2; ++n)
            *(f32x4*)(smem + PARTB + (((wv - 1) * 8 + m * 2 + n) << 10) + lane * 16) = Cc[m][n];
      }
      __syncthreads();                             // the ONLY barrier per step
      if (wv == 0) {
        #pragma unroll
        for (int m = 0; m < 4; ++m)
          #pragma unroll
          for (int n = 0; n < 2; ++n) {
            f32x4 z = Cc[m][n];
            #pragma unroll
            for (int w = 1; w < 4; ++w)
              z += *(const f32x4*)(smem + PARTB + (((w - 1) * 8 + m * 2 + n) << 10) + lane * 16);
            z += zA[m][n] + b1z4[m];
            float ig = 1.f / (1.f + __expf(-z[0]));
            float fg = 1.f / (1.f + __expf(-z[1]));
            float og = 1.f / (1.f + __expf(-z[3]));
            float cn = fg * cst[m][n] + ig * tanhf(z[2]);
            float hn = og * tanhf(cn);
            cst[m][n] = cn;
            unsigned short hb = f2bf(hn);
            unsigned short lb = f2bf(hn - bf2f(hb));
            int i8 = (m * 4 + l4) & 7, subl = (m * 4 + l4) >> 3;
            *(short*)(smem + RP1 + (((0 * 2 + n) * 2 + subl) * 16 + l15) * 16 + i8 * 2) = (short)hb;
            *(short*)(smem + RP1 + (((1 * 2 + n) * 2 + subl) * 16 + l15) * 16 + i8 * 2) = (short)lb;
            if (t == 255) {
              int u = wgc * 16 + m * 4 + l4, b = n * 16 + l15;
              out[2097152 + 65536 + b * 1024 + u] = hn;
              out[2097152 + 98304 + b * 1024 + u] = cn;
            }
          }
        char* hd = h1frag + (size_t)s * 131072;
        asm volatile("s_waitcnt lgkmcnt(0)" ::: "memory");
        __builtin_amdgcn_sched_barrier(0);
        #pragma unroll
        for (int h = 0; h < 2; ++h) {
          int idx16 = lane * 2 + h;
          u32x4 v = *(const u32x4*)(smem + RP1 + idx16 * 16);
          int l15r = idx16 & 15, subl = (idx16 >> 4) & 1, ntq = (idx16 >> 5) & 1, part = idx16 >> 6;
          char* dst = hd + (((part * 2 + ntq) * 32 + (wgc >> 1)) << 10)
                         + (((wgc & 1) * 2 + subl) * 16 + l15r) * 16;
          st16c(dst, v);
        }
        asm volatile("s_waitcnt vmcnt(0)" ::: "memory");
        if (lane == 0) set_flag(f1 + wgc * 8, s);
      }
    }
  }

  // ---- projection: logits[b][t][v] = h1_t @ W_out + b_out ; one t per wg (tp = wg) ----
  {
    const int tp = wg;
    pollT<32>(f1, lane, tp + 1);
    const char* A = h1frag + (size_t)(tp + 1) * 131072;
    f32x4 C[2][4];
    #pragma unroll
    for (int a = 0; a < 2; ++a)
      #pragma unroll
      for (int b = 0; b < 4; ++b) C[a][b] = 0.0f;
    s16x8 QA[4], QB[4];
    #pragma unroll
    for (int q = 0; q < 4; ++q) LDP(QA[q], A + ((q * 32 + 0) << 10) + lane * 16);
    for (int kk = 0; kk < 16; ++kk) {
      const int ks = kk * 2;
      #pragma unroll
      for (int q = 0; q < 4; ++q) LDP(QB[q], A + ((q * 32 + ks + 1) << 10) + lane * 16);
      asm volatile("s_waitcnt vmcnt(4)" ::: "memory");
      __builtin_amdgcn_sched_barrier(0);
      #pragma unroll
      for (int v4 = 0; v4 < 4; ++v4) {
        int vb = wv * 4 + v4;
        s16x8 Bh = ld16(WoutB + (((vb * 2 + 0) * 32 + ks) << 10) + lane * 16);
        s16x8 Bl = ld16(WoutB + (((vb * 2 + 1) * 32 + ks) << 10) + lane * 16);
        C[0][v4] = MF(QA[0], Bh, C[0][v4]); C[0][v4] = MF(QA[0], Bl, C[0][v4]); C[0][v4] = MF(QA[2], Bh, C[0][v4]);
        C[1][v4] = MF(QA[1], Bh, C[1][v4]); C[1][v4] = MF(QA[1], Bl, C[1][v4]); C[1][v4] = MF(QA[3], Bh, C[1][v4]);
      }
      if (kk < 15) {
        #pragma unroll
        for (int q = 0; q < 4; ++q) LDP(QA[q], A + ((q * 32 + ks + 2) << 10) + lane * 16);
        asm volatile("s_waitcnt vmcnt(4)" ::: "memory");
      } else {
        asm volatile("s_waitcnt vmcnt(0)" ::: "memory");
      }
      __builtin_amdgcn_sched_barrier(0);
      #pragma unroll
      for (int v4 = 0; v4 < 4; ++v4) {
        int vb = wv * 4 + v4;
        s16x8 Bh = ld16(WoutB + (((vb * 2 + 0) * 32 + ks + 1) << 10) + lane * 16);
        s16x8 Bl = ld16(WoutB + (((vb * 2 + 1) * 32 + ks + 1) << 10) + lane * 16);
        C[0][v4] = MF(QB[0], Bh, C[0][v4]); C[0][v4] = MF(QB[0], Bl, C[0][v4]); C[0][v4] = MF(QB[2], Bh, C[0][v4]);
        C[1][v4] = MF(QB[1], Bh, C[1][v4]); C[1][v4] = MF(QB[1], Bl, C[1][v4]); C[1][v4] = MF(QB[3], Bh, C[1][v4]);
      }
    }
    #pragma unroll
    for (int nt = 0; nt < 2; ++nt)
      #pragma unroll
      for (int v4 = 0; v4 < 4; ++v4) {
        int v = (wv * 4 + v4) * 16 + l15;
        float bo = b_out[v];
        #pragma unroll
        for (int r = 0; r < 4; ++r) {
          int b = nt * 16 + l4 * 4 + r;
          out[((size_t)b * 256 + tp) * 256 + v] = C[nt][v4][r] + bo;
        }
      }
  }
}

extern "C" void kernel_launch(void* const* d_in, const int* in_sizes, int n_in,
                              void* d_out, int out_size, void* d_ws, size_t ws_size,
                              hipStream_t stream) {
  const int*   targets = (const int*)d_in[1];
  const float* h0_in   = (const float*)d_in[2];
  const float* c0_in   = (const float*)d_in[3];
  const float* h1_in   = (const float*)d_in[4];
  const float* c1_in   = (const float*)d_in[5];
  const float* emb     = (const float*)d_in[6];
  const float* W_ih0   = (const float*)d_in[7];
  const float* W_hh0   = (const float*)d_in[8];
  const float* b0      = (const float*)d_in[9];
  const float* W_ih1   = (const float*)d_in[10];
  const float* W_hh1   = (const float*)d_in[11];
  const float* b1      = (const float*)d_in[12];
  const float* W_out   = (const float*)d_in[13];
  const float* b_out   = (const float*)d_in[14];
  float* out = (float*)d_out;

  char* ws = (char*)d_ws;
  char*  WA0    = ws;                         // Whh0 A-frags hi/lo 16MB; becomes h0 slots 1..128
  char*  WA1    = ws + 16777216;              // Wih1 (hi staged by B, lo streamed)
  char*  WA2    = ws + 33554432;              // Whh1 (hi staged by C, lo streamed)
  char*  WoutB  = ws + 50331648;              // W_out B-frags, 1MB
  char*  embB   = ws + 51380224;              // emb B-frags, 1MB
  float* E0     = (float*)(ws + 52428800);    // 4MB f32
  float* b1i    = (float*)(ws + 56623104);    // 16KB
  int*   f0     = (int*)(ws + 56639488);      // 4KB (128 entries x 32B stride)
  int*   f1     = (int*)(ws + 56643584);      // 4KB (64 real + 64 sentinel)
  char*  h0s0   = ws + 56647680;              // h0 slot 0, 128KB
  char*  h0hi   = ws + 56778752;              // h0 slots 129..256, 16MB
  char*  h1frag = ws + 73555968;              // 257 slots x 128KB -> ends 107241472
  char*  z1ring = ws + 107241472;             // 4 slots x 64 wgs x 8KB = 2MB
  int*   f2     = (int*)(ws + 109338624);     // 4KB
  char*  WAi0   = h1frag + 16777216;          // Wih0 A-frags alias h1 slots 128..255

  prep_misc <<<18,   256, 0, stream>>>(b1, b1i, f0, f1, f2);
  prep_wfrag<<<8192, 256, 0, stream>>>(W_hh0, W_ih1, W_hh1, W_ih0, WA0, WA1, WA2, WAi0);
  prep_bfrag<<<256,  256, 0, stream>>>(emb, W_out, embB, WoutB);
  prep_hinit<<<32,   256, 0, stream>>>(h0_in, h1_in, h0s0, h1frag);

  hipFuncSetAttribute(reinterpret_cast<const void*>(lstm_persist),
                      hipFuncAttributeMaxDynamicSharedMemorySize, 157696);
  lstm_persist<<<256, 256, 157696, stream>>>(
      targets, c0_in, c1_in, b0, b_out,
      WA0, WA1, WA2, WAi0, WoutB, embB,
      E0, b1i, h0s0, h0hi, h1frag, z1ring, f0, f1, f2, out);
}

// Round 13
// 2007.642 us; speedup vs baseline: 1.6900x; 1.0489x over previous
//
#include <hip/hip_runtime.h>
#include <cstdint>

// CharRNN 2-layer LSTM, B=32,T=256,H=1024,V=256. Persistent kernel, round 13:
//   A (wgs 0..63):    L0 chain, 16 units each. Whh0-hi in LDS, lo streamed from WA0
//                     (h0 slots are now their OWN write-once region -> WA0 stays live).
//                     Wave0-only epilogue, 1 barrier/step, no recycle polls.
//   B (wgs 64..127):  z1a_t = h0_{t+1} @ Wih1 (64 cols each; Wih1-hi LDS, lo streamed).
//                     4-slot ring + f2 flags. Off the critical chain.
//   C (wgs 128..255): L1 chain, 8 units each. Whh1 hi+lo BOTH in LDS -> critical loop =
//                     poll + {4 loads + 12 MFMA}x8 + 1 barrier + wave0 epilogue/store/flag.
//   Aliasing (startup-dead regions only): h1 slots 1..128 over WA2 (C stages via LDC),
//   129..256 over WAi0 (A's E0 reads via LDC; ordered transitively f0->f2->f1).
//   math: mfma split-bf16 (hi*hi+hi*lo+lo*hi), summation groups identical to r7.

typedef float    f32x4 __attribute__((ext_vector_type(4)));
typedef short    s16x8 __attribute__((ext_vector_type(8)));
typedef unsigned u32x4 __attribute__((ext_vector_type(4)));

#define DEV __device__ __forceinline__

DEV unsigned short f2bf(float x){
  unsigned u = __builtin_bit_cast(unsigned, x);
  unsigned r = (u + 0x7fffu + ((u >> 16) & 1u)) >> 16;   // round-nearest-even
  return (unsigned short)r;
}
DEV float bf2f(unsigned short b){ return __builtin_bit_cast(float, ((unsigned)b) << 16); }

DEV s16x8 ld16(const void* p){ return *(const s16x8*)p; }

DEV f32x4 MF(s16x8 a, s16x8 b, f32x4 c){
  return __builtin_amdgcn_mfma_f32_16x16x32_bf16(a, b, c, 0, 0, 0);
}

// coherent (bypass L1/L2) 16B load — pre-write reads of aliased regions + ring reads
#define LDC(dst, ptr)  asm volatile("global_load_dwordx4 %0, %1, off sc0 sc1" : "=v"(dst) : "v"(ptr))
// plain cached 16B load
#define LDP(dst, ptr)  asm volatile("global_load_dwordx4 %0, %1, off"         : "=v"(dst) : "v"(ptr))
#define WAITVM(n) do { asm volatile("s_waitcnt vmcnt(" #n ")" ::: "memory"); \
                       __builtin_amdgcn_sched_barrier(0); } while (0)
#define CFENCE()  asm volatile("" ::: "memory")
#define TRIPLE(Cmn, Ahm, Alm, Bhn, Bln) do { \
    Cmn = MF(Ahm, Bhn, Cmn); Cmn = MF(Ahm, Bln, Cmn); Cmn = MF(Alm, Bhn, Cmn); } while (0)

DEV void st16c(void* p, u32x4 v){   // coherent 16B store (write-through)
  asm volatile("global_store_dwordx4 %0, %1, off sc0 sc1" :: "v"(p), "v"(v) : "memory");
}
DEV void st16cf(void* p, f32x4 v){ st16c(p, __builtin_bit_cast(u32x4, v)); }
DEV void set_flag(int* p, int v){
  __hip_atomic_store(p, v, __ATOMIC_RELAXED, __HIP_MEMORY_SCOPE_AGENT);
}
// 64-entry flag poll (stride 8 ints)
template<int SLP>
DEV void poll64(const int* f, int lane, int target){
  const int* p = f + lane * 8;
  for (;;) {
    int a = __hip_atomic_load(p, __ATOMIC_RELAXED, __HIP_MEMORY_SCOPE_AGENT);
    if (__all(a >= target)) break;
    __builtin_amdgcn_s_sleep(SLP);
  }
  CFENCE();
}
// 128-entry flag poll
template<int SLP>
DEV void pollT(const int* f, int lane, int target){
  const int* p0 = f + lane * 8;
  const int* p1 = f + (64 + lane) * 8;
  for (;;) {
    int a = __hip_atomic_load(p0, __ATOMIC_RELAXED, __HIP_MEMORY_SCOPE_AGENT);
    int b = __hip_atomic_load(p1, __ATOMIC_RELAXED, __HIP_MEMORY_SCOPE_AGENT);
    if (__all((a >= target) && (b >= target))) break;
    __builtin_amdgcn_s_sleep(SLP);
  }
  CFENCE();
}
// B: f0>=t0 (64) AND f2>=t2 (64) AND f1>=t1 (128)
DEV void pollB(const int* f0p, int t0, const int* f2p, int t2,
               const int* f1p, int t1, int lane){
  const int* a = f0p + lane * 8;
  const int* b = f2p + lane * 8;
  const int* c0 = f1p + lane * 8;
  const int* c1 = f1p + (64 + lane) * 8;
  for (;;) {
    int x = __hip_atomic_load(a,  __ATOMIC_RELAXED, __HIP_MEMORY_SCOPE_AGENT);
    int y = __hip_atomic_load(b,  __ATOMIC_RELAXED, __HIP_MEMORY_SCOPE_AGENT);
    int z0 = __hip_atomic_load(c0, __ATOMIC_RELAXED, __HIP_MEMORY_SCOPE_AGENT);
    int z1 = __hip_atomic_load(c1, __ATOMIC_RELAXED, __HIP_MEMORY_SCOPE_AGENT);
    if (__all((x >= t0) && (y >= t2) && (z0 >= t1) && (z1 >= t1))) break;
    __builtin_amdgcn_s_sleep(2);
  }
  CFENCE();
}
// C: f1>=t1 (128) AND f2>=t2 (64)
DEV void pollC(const int* f1p, int t1, const int* f2p, int t2, int lane){
  const int* a0 = f1p + lane * 8;
  const int* a1 = f1p + (64 + lane) * 8;
  const int* b  = f2p + lane * 8;
  for (;;) {
    int x0 = __hip_atomic_load(a0, __ATOMIC_RELAXED, __HIP_MEMORY_SCOPE_AGENT);
    int x1 = __hip_atomic_load(a1, __ATOMIC_RELAXED, __HIP_MEMORY_SCOPE_AGENT);
    int y  = __hip_atomic_load(b,  __ATOMIC_RELAXED, __HIP_MEMORY_SCOPE_AGENT);
    if (__all((x0 >= t1) && (x1 >= t1) && (y >= t2))) break;
    __builtin_amdgcn_s_sleep(1);
  }
  CFENCE();
}

// 16-unit half-gemm: A-hi (4 blocks) from LDS, A-lo streamed (4/iter), B 4 q-rows/iter
DEV void gemm16u(const char* smemA, const char* ALb, int jb0, const char* Bb,
                 int ksb, int lane, f32x4 (&C)[4][2]) {
  s16x8 P[3][4], AL[3][4];
  #pragma unroll
  for (int d = 0; d < 2; ++d) {
    #pragma unroll
    for (int q = 0; q < 4; ++q) LDP(P[d][q], Bb + ((q * 32 + ksb + d) << 10) + lane * 16);
    #pragma unroll
    for (int m = 0; m < 4; ++m)
      LDP(AL[d][m], ALb + ((((jb0 + m) * 2 + 1) * 32 + ksb + d) << 10) + lane * 16);
  }
  #pragma unroll
  for (int i = 0; i < 8; ++i) {
    const int ks = ksb + i;
    if (i < 6) {
      #pragma unroll
      for (int q = 0; q < 4; ++q) LDP(P[(i + 2) % 3][q], Bb + ((q * 32 + ks + 2) << 10) + lane * 16);
      #pragma unroll
      for (int m = 0; m < 4; ++m)
        LDP(AL[(i + 2) % 3][m], ALb + ((((jb0 + m) * 2 + 1) * 32 + ks + 2) << 10) + lane * 16);
    }
    s16x8 Ah[4];
    #pragma unroll
    for (int m = 0; m < 4; ++m) Ah[m] = ld16(smemA + ((m * 32 + ks) << 10) + lane * 16);
    if (i < 6) { WAITVM(16); } else if (i == 6) { WAITVM(8); } else { WAITVM(0); }
    #pragma unroll
    for (int m = 0; m < 4; ++m) {
      TRIPLE(C[m][0], Ah[m], AL[i % 3][m], P[i % 3][0], P[i % 3][2]);
      TRIPLE(C[m][1], Ah[m], AL[i % 3][m], P[i % 3][1], P[i % 3][3]);
    }
  }
}

// ---------------- prep: W[k][g*H+u] -> A-frag hi/lo bf16 [jb256][part2][ks32][64*16B] ----
__global__ void prep_wfrag(const float* __restrict__ W0, const float* __restrict__ W1,
                           const float* __restrict__ W2, const float* __restrict__ W3,
                           char* D0, char* D1, char* D2, char* D3) {
  int gid = blockIdx.x * 256 + threadIdx.x;       // 4*256*32*64 = 2M
  int lane = gid & 63, ks = (gid >> 6) & 31, jb = (gid >> 11) & 255, mat = gid >> 19;
  const float* S = (mat == 0) ? W0 : (mat == 1) ? W1 : (mat == 2) ? W2 : W3;
  char* D = (mat == 0) ? D0 : (mat == 1) ? D1 : (mat == 2) ? D2 : D3;
  int jp = jb * 16 + (lane & 15), u = jp >> 2, g = jp & 3;
  int kb = ks * 32 + (lane >> 4) * 8;
  s16x8 vh, vl;
  #pragma unroll
  for (int i = 0; i < 8; ++i) {
    float x = S[(kb + i) * 4096 + g * 1024 + u];
    unsigned short h = f2bf(x);
    vh[i] = (short)h;
    vl[i] = (short)f2bf(x - bf2f(h));
  }
  *(s16x8*)(D + (((jb * 2 + 0) * 32 + ks) << 10) + lane * 16) = vh;
  *(s16x8*)(D + (((jb * 2 + 1) * 32 + ks) << 10) + lane * 16) = vl;
}

// ---------------- prep: emb [v][k] and W_out [k][v] -> B-frag hi/lo [vb16][part2][ks32] ----
__global__ void prep_bfrag(const float* __restrict__ emb, const float* __restrict__ Wout,
                           char* Demb, char* Dwout) {
  int gid = blockIdx.x * 256 + threadIdx.x;       // 2*16*32*64 = 64K
  int lane = gid & 63, ks = (gid >> 6) & 31, vb = (gid >> 11) & 15, which = gid >> 15;
  int v = vb * 16 + (lane & 15), kb = ks * 32 + (lane >> 4) * 8;
  s16x8 vh, vl;
  #pragma unroll
  for (int i = 0; i < 8; ++i) {
    float x = which ? Wout[(kb + i) * 256 + v] : emb[v * 1024 + kb + i];
    unsigned short h = f2bf(x);
    vh[i] = (short)h;
    vl[i] = (short)f2bf(x - bf2f(h));
  }
  char* D = which ? Dwout : Demb;
  *(s16x8*)(D + (((vb * 2 + 0) * 32 + ks) << 10) + lane * 16) = vh;
  *(s16x8*)(D + (((vb * 2 + 1) * 32 + ks) << 10) + lane * 16) = vl;
}

// ---------------- prep: h0_in/h1_in [b][k] f32 -> h-frag slot0 [part2][nt2][ks32] ----
__global__ void prep_hinit(const float* __restrict__ h0, const float* __restrict__ h1,
                           char* h0s0, char* h1s0) {
  int gid = blockIdx.x * 256 + threadIdx.x;       // 2*2*32*64 = 8192
  int lane = gid & 63, ks = (gid >> 6) & 31, nt = (gid >> 11) & 1, which = gid >> 12;
  const float* S = which ? h1 : h0;
  char* D = which ? h1s0 : h0s0;
  int b = nt * 16 + (lane & 15), kb = ks * 32 + (lane >> 4) * 8;
  s16x8 vh, vl;
  #pragma unroll
  for (int i = 0; i < 8; ++i) {
    float x = S[b * 1024 + kb + i];
    unsigned short h = f2bf(x);
    vh[i] = (short)h;
    vl[i] = (short)f2bf(x - bf2f(h));
  }
  *(s16x8*)(D + (((0 * 2 + nt) * 32 + ks) << 10) + lane * 16) = vh;
  *(s16x8*)(D + (((1 * 2 + nt) * 32 + ks) << 10) + lane * 16) = vl;
}

// ---------------- prep: flags = -1, b1 interleave ----
__global__ void prep_misc(const float* __restrict__ b1, float* b1i,
                          int* f0a, int* f1a, int* f2a) {
  int i = blockIdx.x * 256 + threadIdx.x;         // 4608
  if (i < 4096) b1i[i] = b1[(i & 3) * 1024 + (i >> 2)];
  if (i < 1024) { f0a[i] = -1; f1a[i] = -1; f2a[i] = -1; }
}

// ---------------- the persistent LSTM kernel ----------------
__global__ __launch_bounds__(256, 1) void lstm_persist(
    const int* __restrict__ tgt,
    const float* __restrict__ c0_in, const float* __restrict__ c1_in,
    const float* __restrict__ b0, const float* __restrict__ b_out,
    const char* __restrict__ WA0, const char* __restrict__ WA1, char* __restrict__ WA2,
    char* __restrict__ WAi0, const char* __restrict__ WoutB, const char* __restrict__ embB,
    float* __restrict__ E0, const float* __restrict__ b1i,
    char* __restrict__ h0all, char* __restrict__ h1s0, char* __restrict__ z1ring,
    int* __restrict__ f0, int* __restrict__ f1, int* __restrict__ f2,
    float* __restrict__ out)
{
  extern __shared__ char smem[];
  // A/B: frag 128K; PART 131072..155648 (24K); RP 155648..157696 (2K, A only)
  // C:   frag 128K; PART 131072..143360 (12K); RP 143360..144384 (1K)
  constexpr int PARTAB = 131072;
  constexpr int RPA    = 155648;
  constexpr int PARTC  = 131072;
  constexpr int RPC    = 143360;
  const int tid = threadIdx.x, lane = tid & 63, wv = tid >> 6;
  const int wg = blockIdx.x;
  const int l15 = lane & 15, l4 = lane >> 4;

  // h1 slot addressing: 0 -> h1s0; 1..128 alias WA2; 129..256 alias WAi0
  auto h1slot = [&](int s) -> char* {
    return (s == 0) ? h1s0 : ((s <= 128) ? WA2 + ((size_t)(s - 1) << 17)
                                         : WAi0 + ((size_t)(s - 129) << 17));
  };
  auto h0slot = [&](int s) -> char* { return h0all + ((size_t)s << 17); };

  // cross-replay safety: invalidate stale L1/L2 lines
  __builtin_amdgcn_fence(__ATOMIC_ACQUIRE, "agent");

  if (wg < 64) {
    // ==================== GROUP A: layer-0 chain (16 units/wg) ====================
    const int wgl = wg;
    // stage Whh0-hi (plain: WA0 never overwritten)
    for (int idx = tid; idx < 8192; idx += 256) {
      int l16 = idx & 63, ks = (idx >> 6) & 31, m = idx >> 11;
      u32x4 v = *(const u32x4*)(WA0 + ((((wgl * 4 + m) * 2 + 0) * 32 + ks) << 10) + l16 * 16);
      *(u32x4*)(smem + ((m * 32 + ks) << 10) + l16 * 16) = v;
    }
    // E0 = emb @ Wih0 + b0 for own 64 gate-cols. WAi0 aliased later -> LDC reads.
    {
      f32x4 C[4][4];
      #pragma unroll
      for (int a = 0; a < 4; ++a)
        #pragma unroll
        for (int b = 0; b < 4; ++b) C[a][b] = 0.0f;
      for (int ks = 0; ks < 32; ++ks) {
        s16x8 Ah[4], Al[4];
        #pragma unroll
        for (int m = 0; m < 4; ++m) {
          LDC(Ah[m], WAi0 + ((((wgl * 4 + m) * 2 + 0) * 32 + ks) << 10) + lane * 16);
          LDC(Al[m], WAi0 + ((((wgl * 4 + m) * 2 + 1) * 32 + ks) << 10) + lane * 16);
        }
        WAITVM(0);
        #pragma unroll
        for (int v4 = 0; v4 < 4; ++v4) {
          int vb = wv * 4 + v4;
          s16x8 Bh = ld16(embB + (((vb * 2 + 0) * 32 + ks) << 10) + lane * 16);
          s16x8 Bl = ld16(embB + (((vb * 2 + 1) * 32 + ks) << 10) + lane * 16);
          #pragma unroll
          for (int m = 0; m < 4; ++m) TRIPLE(C[m][v4], Ah[m], Al[m], Bh, Bl);
        }
      }
      #pragma unroll
      for (int m = 0; m < 4; ++m) {
        int jb4 = wgl * 64 + m * 16 + l4 * 4;
        int u = jb4 >> 2;
        f32x4 bb;
        #pragma unroll
        for (int r = 0; r < 4; ++r) bb[r] = b0[r * 1024 + u];
        #pragma unroll
        for (int v4 = 0; v4 < 4; ++v4) {
          int v = (wv * 4 + v4) * 16 + l15;
          *(f32x4*)(E0 + v * 4096 + jb4) = C[m][v4] + bb;
        }
      }
    }
    float cst[4][2];
    if (wv == 0) {
      #pragma unroll
      for (int m = 0; m < 4; ++m)
        #pragma unroll
        for (int n = 0; n < 2; ++n)
          cst[m][n] = c0_in[(n * 16 + l15) * 1024 + wgl * 16 + m * 4 + l4];
    }
    __syncthreads();
    if (tid == 0) set_flag(f0 + wgl * 8, 0);

    for (int t = 0; t < 256; ++t) {
      const int s = t + 1;
      f32x4 e0v[4][2];
      if (wv == 0) {
        #pragma unroll
        for (int n = 0; n < 2; ++n) {
          int tv = tgt[(n * 16 + l15) * 256 + t];
          #pragma unroll
          for (int m = 0; m < 4; ++m)
            e0v[m][n] = *(const f32x4*)(E0 + (size_t)tv * 4096 + wgl * 64 + m * 16 + (l4 << 2));
        }
      }
      poll64<1>(f0, lane, t);
      f32x4 C[4][2];
      #pragma unroll
      for (int a = 0; a < 4; ++a)
        #pragma unroll
        for (int b = 0; b < 2; ++b) C[a][b] = 0.0f;
      gemm16u(smem, WA0, wgl * 4, h0slot(t), wv * 8, lane, C);
      if (wv) {
        #pragma unroll
        for (int m = 0; m < 4; ++m)
          #pragma unroll
          for (int n = 0; n < 2; ++n)
            *(f32x4*)(smem + PARTAB + (((wv - 1) * 8 + m * 2 + n) << 10) + lane * 16) = C[m][n];
      }
      __syncthreads();                             // the only barrier per step
      if (wv == 0) {
        #pragma unroll
        for (int m = 0; m < 4; ++m)
          #pragma unroll
          for (int n = 0; n < 2; ++n) {
            f32x4 z = C[m][n];
            #pragma unroll
            for (int w = 1; w < 4; ++w)
              z += *(const f32x4*)(smem + PARTAB + (((w - 1) * 8 + m * 2 + n) << 10) + lane * 16);
            z += e0v[m][n];
            float ig = 1.f / (1.f + __expf(-z[0]));
            float fg = 1.f / (1.f + __expf(-z[1]));
            float og = 1.f / (1.f + __expf(-z[3]));
            float cn = fg * cst[m][n] + ig * tanhf(z[2]);
            float hn = og * tanhf(cn);
            cst[m][n] = cn;
            unsigned short hb = f2bf(hn);
            unsigned short lb = f2bf(hn - bf2f(hb));
            int ul = m * 4 + l4, j8 = ul >> 3, i8 = ul & 7;
            *(short*)(smem + RPA + (((0 * 2 + n) * 2 + j8) * 16 + l15) * 16 + i8 * 2) = (short)hb;
            *(short*)(smem + RPA + (((1 * 2 + n) * 2 + j8) * 16 + l15) * 16 + i8 * 2) = (short)lb;
            if (t == 255) {
              int u = wgl * 16 + ul, b = n * 16 + l15;
              out[2097152 + b * 1024 + u] = hn;
              out[2097152 + 32768 + b * 1024 + u] = cn;
            }
          }
        char* hd = h0slot(s);
        asm volatile("s_waitcnt lgkmcnt(0)" ::: "memory");
        __builtin_amdgcn_sched_barrier(0);
        #pragma unroll
        for (int h = 0; h < 2; ++h) {
          int idx16 = lane * 2 + h;
          u32x4 v = *(const u32x4*)(smem + RPA + idx16 * 16);
          int l15r = idx16 & 15, subl = (idx16 >> 4) & 1, ntq = (idx16 >> 5) & 1, part = idx16 >> 6;
          char* dst = hd + (((part * 2 + ntq) * 32 + (wgl >> 1)) << 10)
                         + (((wgl & 1) * 2 + subl) * 16 + l15r) * 16;
          st16c(dst, v);
        }
        asm volatile("s_waitcnt vmcnt(0)" ::: "memory");
        if (lane == 0) set_flag(f0 + wgl * 8, s);
      }
    }
  } else if (wg < 128) {
    // ==================== GROUP B: z1a producer (64 cols/wg) ====================
    const int wgb = wg - 64;
    const int jb0 = wgb * 4;
    for (int idx = tid; idx < 8192; idx += 256) {  // Wih1-hi -> LDS (plain: WA1 live)
      int l16 = idx & 63, ks = (idx >> 6) & 31, m = idx >> 11;
      u32x4 v = *(const u32x4*)(WA1 + ((((jb0 + m) * 2 + 0) * 32 + ks) << 10) + l16 * 16);
      *(u32x4*)(smem + ((m * 32 + ks) << 10) + l16 * 16) = v;
    }
    __syncthreads();
    if (tid == 0) set_flag(f2 + wgb * 8, 0);

    for (int t = 0; t < 256; ++t) {
      pollB(f0, t + 1, f2, t, f1, t - 3, lane);
      f32x4 Cb[4][2];
      #pragma unroll
      for (int a = 0; a < 4; ++a)
        #pragma unroll
        for (int b = 0; b < 2; ++b) Cb[a][b] = 0.0f;
      gemm16u(smem, WA1, jb0, h0slot(t + 1), wv * 8, lane, Cb);
      if (wv) {
        #pragma unroll
        for (int m = 0; m < 4; ++m)
          #pragma unroll
          for (int n = 0; n < 2; ++n)
            *(f32x4*)(smem + PARTAB + (((wv - 1) * 8 + m * 2 + n) << 10) + lane * 16) = Cb[m][n];
      }
      __syncthreads();
      if (wv == 0) {
        char* zs = z1ring + ((size_t)(t & 3) * 64 + wgb) * 8192;
        #pragma unroll
        for (int m = 0; m < 4; ++m)
          #pragma unroll
          for (int n = 0; n < 2; ++n) {
            f32x4 z = Cb[m][n];
            #pragma unroll
            for (int w = 1; w < 4; ++w)
              z += *(const f32x4*)(smem + PARTAB + (((w - 1) * 8 + m * 2 + n) << 10) + lane * 16);
            st16cf(zs + ((m * 2 + n) * 64 + lane) * 16, z);
          }
        asm volatile("s_waitcnt vmcnt(0)" ::: "memory");
        if (lane == 0) set_flag(f2 + wgb * 8, t + 1);
      }
    }
  } else {
    // ==================== GROUP C: layer-1 chain (8 units/wg) ====================
    const int wgc = wg - 128;
    // stage Whh1 hi+lo via LDC (WA2 becomes h1 slots 1..128!)
    {
      u32x4 tmp[8];
      for (int blk = 0; blk < 4; ++blk) {
        #pragma unroll
        for (int q = 0; q < 8; ++q) {
          int idx = tid + (blk * 8 + q) * 256;
          int l16 = idx & 63, ks = (idx >> 6) & 31, mi = (idx >> 11) & 1, part = idx >> 12;
          LDC(tmp[q], WA2 + ((((wgc * 2 + mi) * 2 + part) * 32 + ks) << 10) + l16 * 16);
        }
        WAITVM(0);
        #pragma unroll
        for (int q = 0; q < 8; ++q) {
          int idx = tid + (blk * 8 + q) * 256;
          int l16 = idx & 63, ks = (idx >> 6) & 31, mi = (idx >> 11) & 1, part = idx >> 12;
          *(u32x4*)(smem + (((part * 2 + mi) * 32 + ks) << 10) + l16 * 16) = tmp[q];
        }
      }
    }
    f32x4 b1z[2];
    float cst[2][2];
    if (wv == 0) {
      #pragma unroll
      for (int mi = 0; mi < 2; ++mi) {
        b1z[mi] = *(const f32x4*)(b1i + wgc * 32 + mi * 16 + (l4 << 2));
        #pragma unroll
        for (int nt = 0; nt < 2; ++nt)
          cst[mi][nt] = c1_in[(nt * 16 + l15) * 1024 + wgc * 8 + mi * 4 + l4];
      }
    }
    __syncthreads();
    if (tid == 0) set_flag(f1 + wgc * 8, 0);

    for (int t = 0; t < 256; ++t) {
      const int s = t + 1;
      pollC(f1, t, f2, s, lane);
      f32x4 zA[2][2];
      if (wv == 0) {
        const char* zs = z1ring + ((size_t)(t & 3) * 64 + (wgc >> 1)) * 8192;
        #pragma unroll
        for (int mi = 0; mi < 2; ++mi) {
          int mb = (wgc & 1) * 2 + mi;
          #pragma unroll
          for (int nt = 0; nt < 2; ++nt)
            LDC(zA[mi][nt], zs + ((mb * 2 + nt) * 64 + lane) * 16);
        }
      }
      // critical GEMM: h1_{t} state @ Whh1, all frags in LDS, 4 loads/iter
      f32x4 C[2][2];
      #pragma unroll
      for (int a = 0; a < 2; ++a)
        #pragma unroll
        for (int b = 0; b < 2; ++b) C[a][b] = 0.0f;
      {
        const char* Bb = h1slot(t);
        const int ksb = wv * 8;
        s16x8 P[3][4];
        #pragma unroll
        for (int d = 0; d < 2; ++d)
          #pragma unroll
          for (int q = 0; q < 4; ++q) LDP(P[d][q], Bb + ((q * 32 + ksb + d) << 10) + lane * 16);
        #pragma unroll
        for (int i = 0; i < 8; ++i) {
          const int ks = ksb + i;
          if (i < 6) {
            #pragma unroll
            for (int q = 0; q < 4; ++q) LDP(P[(i + 2) % 3][q], Bb + ((q * 32 + ks + 2) << 10) + lane * 16);
          }
          s16x8 Ah0 = ld16(smem + ((0 * 32 + ks) << 10) + lane * 16);
          s16x8 Ah1 = ld16(smem + ((1 * 32 + ks) << 10) + lane * 16);
          s16x8 Al0 = ld16(smem + ((2 * 32 + ks) << 10) + lane * 16);
          s16x8 Al1 = ld16(smem + ((3 * 32 + ks) << 10) + lane * 16);
          if (i < 6) { WAITVM(8); } else if (i == 6) { WAITVM(4); } else { WAITVM(0); }
          TRIPLE(C[0][0], Ah0, Al0, P[i % 3][0], P[i % 3][2]);
          TRIPLE(C[0][1], Ah0, Al0, P[i % 3][1], P[i % 3][3]);
          TRIPLE(C[1][0], Ah1, Al1, P[i % 3][0], P[i % 3][2]);
          TRIPLE(C[1][1], Ah1, Al1, P[i % 3][1], P[i % 3][3]);
        }
      }
      if (wv) {
        #pragma unroll
        for (int mi = 0; mi < 2; ++mi)
          #pragma unroll
          for (int nt = 0; nt < 2; ++nt)
            *(f32x4*)(smem + PARTC + (((wv - 1) * 4 + mi * 2 + nt) << 10) + lane * 16) = C[mi][nt];
      }
      __syncthreads();                             // the only barrier per step
      if (wv == 0) {
        #pragma unroll
        for (int mi = 0; mi < 2; ++mi)
          #pragma unroll
          for (int nt = 0; nt < 2; ++nt) {
            f32x4 z = C[mi][nt];
            #pragma unroll
            for (int w = 1; w < 4; ++w)
              z += *(const f32x4*)(smem + PARTC + (((w - 1) * 4 + mi * 2 + nt) << 10) + lane * 16);
            z += zA[mi][nt] + b1z[mi];
            float ig = 1.f / (1.f + __expf(-z[0]));
            float fg = 1.f / (1.f + __expf(-z[1]));
            float og = 1.f / (1.f + __expf(-z[3]));
            float cn = fg * cst[mi][nt] + ig * tanhf(z[2]);
            float hn = og * tanhf(cn);
            cst[mi][nt] = cn;
            unsigned short hb = f2bf(hn);
            unsigned short lb = f2bf(hn - bf2f(hb));
            *(short*)(smem + RPC + ((0 + nt) * 16 + l15) * 16 + (mi * 4 + l4) * 2) = (short)hb;
            *(short*)(smem + RPC + ((2 + nt) * 16 + l15) * 16 + (mi * 4 + l4) * 2) = (short)lb;
            if (t == 255) {
              int u = wgc * 8 + mi * 4 + l4, b = nt * 16 + l15;
              out[2097152 + 65536 + b * 1024 + u] = hn;
              out[2097152 + 98304 + b * 1024 + u] = cn;
            }
          }
        char* hd = h1slot(s);
        asm volatile("s_waitcnt lgkmcnt(0)" ::: "memory");
        __builtin_amdgcn_sched_barrier(0);
        u32x4 v = *(const u32x4*)(smem + RPC + lane * 16);
        char* dst = hd + (((lane >> 4) * 32 + (wgc >> 2)) << 10) + ((wgc & 3) * 16 + l15) * 16;
        st16c(dst, v);
        asm volatile("s_waitcnt vmcnt(0)" ::: "memory");
        if (lane == 0) set_flag(f1 + wgc * 8, s);
      }
    }
  }

  // ---- projection: logits[b][t][v] = h1_t @ W_out + b_out ; tp = wg ----
  {
    const int tp = wg;
    pollT<32>(f1, lane, tp + 1);
    const char* A = h1slot(tp + 1);
    f32x4 C[2][4];
    #pragma unroll
    for (int a = 0; a < 2; ++a)
      #pragma unroll
      for (int b = 0; b < 4; ++b) C[a][b] = 0.0f;
    s16x8 QA[4], QB[4];
    #pragma unroll
    for (int q = 0; q < 4; ++q) LDP(QA[q], A + ((q * 32 + 0) << 10) + lane * 16);
    for (int kk = 0; kk < 16; ++kk) {
      const int ks = kk * 2;
      #pragma unroll
      for (int q = 0; q < 4; ++q) LDP(QB[q], A + ((q * 32 + ks + 1) << 10) + lane * 16);
      asm volatile("s_waitcnt vmcnt(4)" ::: "memory");
      __builtin_amdgcn_sched_barrier(0);
      #pragma unroll
      for (int v4 = 0; v4 < 4; ++v4) {
        int vb = wv * 4 + v4;
        s16x8 Bh = ld16(WoutB + (((vb * 2 + 0) * 32 + ks) << 10) + lane * 16);
        s16x8 Bl = ld16(WoutB + (((vb * 2 + 1) * 32 + ks) << 10) + lane * 16);
        C[0][v4] = MF(QA[0], Bh, C[0][v4]); C[0][v4] = MF(QA[0], Bl, C[0][v4]); C[0][v4] = MF(QA[2], Bh, C[0][v4]);
        C[1][v4] = MF(QA[1], Bh, C[1][v4]); C[1][v4] = MF(QA[1], Bl, C[1][v4]); C[1][v4] = MF(QA[3], Bh, C[1][v4]);
      }
      if (kk < 15) {
        #pragma unroll
        for (int q = 0; q < 4; ++q) LDP(QA[q], A + ((q * 32 + ks + 2) << 10) + lane * 16);
        asm volatile("s_waitcnt vmcnt(4)" ::: "memory");
      } else {
        asm volatile("s_waitcnt vmcnt(0)" ::: "memory");
      }
      __builtin_amdgcn_sched_barrier(0);
      #pragma unroll
      for (int v4 = 0; v4 < 4; ++v4) {
        int vb = wv * 4 + v4;
        s16x8 Bh = ld16(WoutB + (((vb * 2 + 0) * 32 + ks + 1) << 10) + lane * 16);
        s16x8 Bl = ld16(WoutB + (((vb * 2 + 1) * 32 + ks + 1) << 10) + lane * 16);
        C[0][v4] = MF(QB[0], Bh, C[0][v4]); C[0][v4] = MF(QB[0], Bl, C[0][v4]); C[0][v4] = MF(QB[2], Bh, C[0][v4]);
        C[1][v4] = MF(QB[1], Bh, C[1][v4]); C[1][v4] = MF(QB[1], Bl, C[1][v4]); C[1][v4] = MF(QB[3], Bh, C[1][v4]);
      }
    }
    #pragma unroll
    for (int nt = 0; nt < 2; ++nt)
      #pragma unroll
      for (int v4 = 0; v4 < 4; ++v4) {
        int v = (wv * 4 + v4) * 16 + l15;
        float bo = b_out[v];
        #pragma unroll
        for (int r = 0; r < 4; ++r) {
          int b = nt * 16 + l4 * 4 + r;
          out[((size_t)b * 256 + tp) * 256 + v] = C[nt][v4][r] + bo;
        }
      }
  }
}

extern "C" void kernel_launch(void* const* d_in, const int* in_sizes, int n_in,
                              void* d_out, int out_size, void* d_ws, size_t ws_size,
                              hipStream_t stream) {
  const int*   targets = (const int*)d_in[1];
  const float* h0_in   = (const float*)d_in[2];
  const float* c0_in   = (const float*)d_in[3];
  const float* h1_in   = (const float*)d_in[4];
  const float* c1_in   = (const float*)d_in[5];
  const float* emb     = (const float*)d_in[6];
  const float* W_ih0   = (const float*)d_in[7];
  const float* W_hh0   = (const float*)d_in[8];
  const float* b0      = (const float*)d_in[9];
  const float* W_ih1   = (const float*)d_in[10];
  const float* W_hh1   = (const float*)d_in[11];
  const float* b1      = (const float*)d_in[12];
  const float* W_out   = (const float*)d_in[13];
  const float* b_out   = (const float*)d_in[14];
  float* out = (float*)d_out;

  char* ws = (char*)d_ws;
  char*  WA0    = ws;                         // Whh0 hi/lo, 16MB (live: A streams lo)
  char*  WA1    = ws + 16777216;              // Wih1 hi/lo (live: B streams lo)
  char*  WA2    = ws + 33554432;              // Whh1 hi/lo; becomes h1 slots 1..128
  char*  WAi0   = ws + 50331648;              // Wih0 hi/lo; becomes h1 slots 129..256
  char*  WoutB  = ws + 67108864;              // 1MB
  char*  embB   = ws + 68157440;              // 1MB
  float* E0     = (float*)(ws + 69206016);    // 4MB
  float* b1i    = (float*)(ws + 73400320);    // 16KB
  int*   f0     = (int*)(ws + 73416704);      // 4KB
  int*   f1     = (int*)(ws + 73420800);      // 4KB
  int*   f2     = (int*)(ws + 73424896);      // 4KB
  char*  h0all  = ws + 73428992;              // 257 x 128KB = 33.69MB (write-once)
  char*  h1s0   = ws + 107114496;             // 128KB
  char*  z1ring = ws + 107245568;             // 4 x 64 x 8KB = 2MB -> ends 109342720

  prep_misc <<<18,   256, 0, stream>>>(b1, b1i, f0, f1, f2);
  prep_wfrag<<<8192, 256, 0, stream>>>(W_hh0, W_ih1, W_hh1, W_ih0, WA0, WA1, WA2, WAi0);
  prep_bfrag<<<256,  256, 0, stream>>>(emb, W_out, embB, WoutB);
  prep_hinit<<<32,   256, 0, stream>>>(h0_in, h1_in, h0all, h1s0);

  hipFuncSetAttribute(reinterpret_cast<const void*>(lstm_persist),
                      hipFuncAttributeMaxDynamicSharedMemorySize, 157696);
  lstm_persist<<<256, 256, 157696, stream>>>(
      targets, c0_in, c1_in, b0, b_out,
      WA0, WA1, WA2, WAi0, WoutB, embB,
      E0, b1i, h0all, h1s0, z1ring, f0, f1, f2, out);
}

// Round 14
// 1998.988 us; speedup vs baseline: 1.6973x; 1.0043x over previous
//
#include <hip/hip_runtime.h>
#include <cstdint>

// CharRNN 2-layer LSTM, B=32,T=256,H=1024,V=256. Persistent kernel, round 14:
//   Base = round 7 (best, 1723us). ONE change: L1's step drops from 4 barriers to 2.
//   zpre partials: each wave keeps its OWN quadrant in a register (zC2own) and dumps
//   the other 3 quadrants to a 12-slot ZTMP region (crit PART likewise 12 slots —
//   own quadrant stays in registers). Epilogue: ownCrit + 3*PART + ownZpre + 3*ZTMP + b1.
//   Ordering: ZTMP writes (post-syncB) -> reads (post-next-syncA); PART reuse gated by
//   the own-wg flag chain. L0 chain / projection / prep / flags / aliasing: r7 verbatim.
//   math: mfma_f32_16x16x32_bf16 split-bf16 (hi*hi + hi*lo + lo*hi) ~ f32 accuracy.

typedef float    f32x4 __attribute__((ext_vector_type(4)));
typedef short    s16x8 __attribute__((ext_vector_type(8)));
typedef unsigned u32x4 __attribute__((ext_vector_type(4)));

#define DEV __device__ __forceinline__

DEV unsigned short f2bf(float x){
  unsigned u = __builtin_bit_cast(unsigned, x);
  unsigned r = (u + 0x7fffu + ((u >> 16) & 1u)) >> 16;   // round-nearest-even
  return (unsigned short)r;
}
DEV float bf2f(unsigned short b){ return __builtin_bit_cast(float, ((unsigned)b) << 16); }

DEV s16x8 ld16(const void* p){ return *(const s16x8*)p; }

DEV f32x4 MF(s16x8 a, s16x8 b, f32x4 c){
  return __builtin_amdgcn_mfma_f32_16x16x32_bf16(a, b, c, 0, 0, 0);
}

// coherent (bypass L1/L2) 16B load — only for WA0/WAi0 (aliased regions)
#define LDC(dst, ptr)  asm volatile("global_load_dwordx4 %0, %1, off sc0 sc1" : "=v"(dst) : "v"(ptr))
// plain cached 16B load (participates in our vmcnt accounting)
#define LDP(dst, ptr)  asm volatile("global_load_dwordx4 %0, %1, off"         : "=v"(dst) : "v"(ptr))
#define WAITVM(n) do { asm volatile("s_waitcnt vmcnt(" #n ")" ::: "memory"); \
                       __builtin_amdgcn_sched_barrier(0); } while (0)
#define CFENCE()  asm volatile("" ::: "memory")
#define TRIPLE(Cmn, Ahm, Alm, Bhn, Bln) do { \
    Cmn = MF(Ahm, Bhn, Cmn); Cmn = MF(Ahm, Bln, Cmn); Cmn = MF(Alm, Bhn, Cmn); } while (0)

DEV void st16c(void* p, u32x4 v){   // coherent 16B store (write-through)
  asm volatile("global_store_dwordx4 %0, %1, off sc0 sc1" :: "v"(p), "v"(v) : "memory");
}
DEV void set_flag(int* p, int v){
  __hip_atomic_store(p, v, __ATOMIC_RELAXED, __HIP_MEMORY_SCOPE_AGENT);
}
// collective poll: all 128 flags (stride 8 ints) >= target
template<int SLP>
DEV void pollT(const int* f, int lane, int target){
  const int* p0 = f + lane * 8;
  const int* p1 = f + (64 + lane) * 8;
  for (;;) {
    int a = __hip_atomic_load(p0, __ATOMIC_RELAXED, __HIP_MEMORY_SCOPE_AGENT);
    int b = __hip_atomic_load(p1, __ATOMIC_RELAXED, __HIP_MEMORY_SCOPE_AGENT);
    if (__all((a >= target) && (b >= target))) break;
    __builtin_amdgcn_s_sleep(SLP);
  }
  CFENCE();
}
// h0 slot address: 0 -> s0 buf; 1..128 -> aliased over WA0; 129..256 -> hi buf
DEV char* h0slot(char* wa0, char* s0, char* hi, int s){
  return (s == 0) ? s0 : ((s <= 128) ? wa0 + ((size_t)(s - 1) << 17)
                                     : hi  + ((size_t)(s - 129) << 17));
}

// 8-iteration half-GEMM: A hi from LDS (smemMat), A lo streamed from ALb, B from Bb
DEV void halfgemm8(const char* smemMat, const char* ALb, const char* Bb,
                   int wgl, int ksb, int lane, f32x4 (&C)[2][2]) {
  s16x8 P[3][4], AL[3][2];
  #pragma unroll
  for (int d = 0; d < 2; ++d) {
    #pragma unroll
    for (int q = 0; q < 4; ++q) LDP(P[d][q], Bb + ((q * 32 + ksb + d) << 10) + lane * 16);
    LDP(AL[d][0], ALb + ((((wgl * 2 + 0) * 2 + 1) * 32 + ksb + d) << 10) + lane * 16);
    LDP(AL[d][1], ALb + ((((wgl * 2 + 1) * 2 + 1) * 32 + ksb + d) << 10) + lane * 16);
  }
  #pragma unroll
  for (int i = 0; i < 8; ++i) {
    const int ks = ksb + i;
    if (i < 6) {
      #pragma unroll
      for (int q = 0; q < 4; ++q) LDP(P[(i + 2) % 3][q], Bb + ((q * 32 + ks + 2) << 10) + lane * 16);
      LDP(AL[(i + 2) % 3][0], ALb + ((((wgl * 2 + 0) * 2 + 1) * 32 + ks + 2) << 10) + lane * 16);
      LDP(AL[(i + 2) % 3][1], ALb + ((((wgl * 2 + 1) * 2 + 1) * 32 + ks + 2) << 10) + lane * 16);
    }
    s16x8 Ah0 = ld16(smemMat + ((0 * 32 + ks) << 10) + lane * 16);
    s16x8 Ah1 = ld16(smemMat + ((1 * 32 + ks) << 10) + lane * 16);
    if (i < 6) { WAITVM(12); } else if (i == 6) { WAITVM(6); } else { WAITVM(0); }
    TRIPLE(C[0][0], Ah0, AL[i % 3][0], P[i % 3][0], P[i % 3][2]);
    TRIPLE(C[0][1], Ah0, AL[i % 3][0], P[i % 3][1], P[i % 3][3]);
    TRIPLE(C[1][0], Ah1, AL[i % 3][1], P[i % 3][0], P[i % 3][2]);
    TRIPLE(C[1][1], Ah1, AL[i % 3][1], P[i % 3][1], P[i % 3][3]);
  }
}

// ---------------- prep: W[k][g*H+u] -> A-frag hi/lo bf16 [jb256][part2][ks32][64*16B] ----
__global__ void prep_wfrag(const float* __restrict__ W0, const float* __restrict__ W1,
                           const float* __restrict__ W2, const float* __restrict__ W3,
                           char* D0, char* D1, char* D2, char* D3) {
  int gid = blockIdx.x * 256 + threadIdx.x;       // 4*256*32*64 = 2M
  int lane = gid & 63, ks = (gid >> 6) & 31, jb = (gid >> 11) & 255, mat = gid >> 19;
  const float* S = (mat == 0) ? W0 : (mat == 1) ? W1 : (mat == 2) ? W2 : W3;
  char* D = (mat == 0) ? D0 : (mat == 1) ? D1 : (mat == 2) ? D2 : D3;
  int jp = jb * 16 + (lane & 15), u = jp >> 2, g = jp & 3;
  int kb = ks * 32 + (lane >> 4) * 8;
  s16x8 vh, vl;
  #pragma unroll
  for (int i = 0; i < 8; ++i) {
    float x = S[(kb + i) * 4096 + g * 1024 + u];
    unsigned short h = f2bf(x);
    vh[i] = (short)h;
    vl[i] = (short)f2bf(x - bf2f(h));
  }
  *(s16x8*)(D + (((jb * 2 + 0) * 32 + ks) << 10) + lane * 16) = vh;
  *(s16x8*)(D + (((jb * 2 + 1) * 32 + ks) << 10) + lane * 16) = vl;
}

// ---------------- prep: emb [v][k] and W_out [k][v] -> B-frag hi/lo [vb16][part2][ks32] ----
__global__ void prep_bfrag(const float* __restrict__ emb, const float* __restrict__ Wout,
                           char* Demb, char* Dwout) {
  int gid = blockIdx.x * 256 + threadIdx.x;       // 2*16*32*64 = 64K
  int lane = gid & 63, ks = (gid >> 6) & 31, vb = (gid >> 11) & 15, which = gid >> 15;
  int v = vb * 16 + (lane & 15), kb = ks * 32 + (lane >> 4) * 8;
  s16x8 vh, vl;
  #pragma unroll
  for (int i = 0; i < 8; ++i) {
    float x = which ? Wout[(kb + i) * 256 + v] : emb[v * 1024 + kb + i];
    unsigned short h = f2bf(x);
    vh[i] = (short)h;
    vl[i] = (short)f2bf(x - bf2f(h));
  }
  char* D = which ? Dwout : Demb;
  *(s16x8*)(D + (((vb * 2 + 0) * 32 + ks) << 10) + lane * 16) = vh;
  *(s16x8*)(D + (((vb * 2 + 1) * 32 + ks) << 10) + lane * 16) = vl;
}

// ---------------- prep: h0_in/h1_in [b][k] f32 -> h-frag slot0 [part2][nt2][ks32] ----
__global__ void prep_hinit(const float* __restrict__ h0, const float* __restrict__ h1,
                           char* h0s0, char* h1f) {
  int gid = blockIdx.x * 256 + threadIdx.x;       // 2*2*32*64 = 8192
  int lane = gid & 63, ks = (gid >> 6) & 31, nt = (gid >> 11) & 1, which = gid >> 12;
  const float* S = which ? h1 : h0;
  char* D = which ? h1f : h0s0;                   // slot 0 of each
  int b = nt * 16 + (lane & 15), kb = ks * 32 + (lane >> 4) * 8;
  s16x8 vh, vl;
  #pragma unroll
  for (int i = 0; i < 8; ++i) {
    float x = S[b * 1024 + kb + i];
    unsigned short h = f2bf(x);
    vh[i] = (short)h;
    vl[i] = (short)f2bf(x - bf2f(h));
  }
  *(s16x8*)(D + (((0 * 2 + nt) * 32 + ks) << 10) + lane * 16) = vh;
  *(s16x8*)(D + (((1 * 2 + nt) * 32 + ks) << 10) + lane * 16) = vl;
}

// ---------------- prep: flags = -1 (staging gate), gate-interleave b1 ----
__global__ void prep_misc(const float* __restrict__ b1, float* b1i, int* f0a, int* f1a) {
  int i = blockIdx.x * 256 + threadIdx.x;         // 4608
  if (i < 4096) b1i[i] = b1[(i & 3) * 1024 + (i >> 2)];
  if (i < 1024) { f0a[i] = -1; f1a[i] = -1; }
}

// ---------------- the persistent LSTM kernel ----------------
__global__ __launch_bounds__(256, 1) void lstm_persist(
    const int* __restrict__ tgt,
    const float* __restrict__ c0_in, const float* __restrict__ c1_in,
    const float* __restrict__ b0, const float* __restrict__ b_out,
    char* __restrict__ WA0, const char* __restrict__ WA1, const char* __restrict__ WA2,
    const char* __restrict__ WAi0, const char* __restrict__ WoutB, const char* __restrict__ embB,
    float* __restrict__ E0, const float* __restrict__ b1i,
    char* __restrict__ h0s0, char* __restrict__ h0hi, char* __restrict__ h1frag,
    int* __restrict__ f0, int* __restrict__ f1,
    float* __restrict__ out)
{
  extern __shared__ char smem[];
  // L0: [0,128K) Whh0 hi+lo A-frags; PART 131072 (16 slots); RP0 147456 (1K)
  // L1: [0,128K) Wih1-hi + Whh1-hi;  PART1 131072 (12 slots); ZTMP 143360 (12 slots);
  //     RP1 155648 (1K). Total 156672 <= 160K.
  constexpr int PART  = 131072;
  constexpr int RP0   = 147456;
  constexpr int PART1 = 131072;
  constexpr int ZTMP  = 143360;
  constexpr int RP1   = 155648;
  const int tid = threadIdx.x, lane = tid & 63, wv = tid >> 6;
  const int wg = blockIdx.x;
  const bool isL0 = (wg < 128);
  const int wgl = isL0 ? wg : (wg - 128);
  const int l15 = lane & 15, l4 = lane >> 4;
  const int mi_e = wv >> 1, nt_e = wv & 1;        // epilogue role (mi, nt); quadrant q == wv

  // one-time cross-replay safety: invalidate stale L1/L2 lines
  __builtin_amdgcn_fence(__ATOMIC_ACQUIRE, "agent");

  // ---- stage A-frags into LDS: L0 = Whh0 hi+lo (sc-loads: WA0 becomes h0 slots!) ----
  if (isL0) {
    u32x4 tmp[8];
    for (int blk = 0; blk < 4; ++blk) {
      #pragma unroll
      for (int q = 0; q < 8; ++q) {
        int idx = tid + (blk * 8 + q) * 256;
        int l16 = idx & 63, ks = (idx >> 6) & 31, mi = (idx >> 11) & 1, part = idx >> 12;
        LDC(tmp[q], WA0 + ((((wgl * 2 + mi) * 2 + part) * 32 + ks) << 10) + l16 * 16);
      }
      WAITVM(0);
      #pragma unroll
      for (int q = 0; q < 8; ++q) {
        int idx = tid + (blk * 8 + q) * 256;
        int l16 = idx & 63, ks = (idx >> 6) & 31, mi = (idx >> 11) & 1, part = idx >> 12;
        *(u32x4*)(smem + (((part * 2 + mi) * 32 + ks) << 10) + l16 * 16) = tmp[q];
      }
    }
  } else {
    for (int idx = tid; idx < 8192; idx += 256) {
      int l16 = idx & 63, ks = (idx >> 6) & 31, mi = (idx >> 11) & 1, mat = idx >> 12;
      const char* W = mat ? WA2 : WA1;
      u32x4 v = *(const u32x4*)(W + ((((wgl * 2 + mi) * 2 + 0) * 32 + ks) << 10) + l16 * 16);
      *(u32x4*)(smem + (((mat * 2 + mi) * 32 + ks) << 10) + l16 * 16) = v;
    }
  }

  // ---- E0 = emb @ Wih0 + b0, own 32 gate-cols only (L0 wgs). WAi0 via sc-loads. ----
  if (isL0) {
    f32x4 C[2][4];
    #pragma unroll
    for (int a = 0; a < 2; ++a)
      #pragma unroll
      for (int b = 0; b < 4; ++b) C[a][b] = 0.0f;
    for (int ks = 0; ks < 32; ++ks) {
      s16x8 Ah0, Ah1, Al0, Al1;
      LDC(Ah0, WAi0 + ((((wgl * 2 + 0) * 2 + 0) * 32 + ks) << 10) + lane * 16);
      LDC(Ah1, WAi0 + ((((wgl * 2 + 1) * 2 + 0) * 32 + ks) << 10) + lane * 16);
      LDC(Al0, WAi0 + ((((wgl * 2 + 0) * 2 + 1) * 32 + ks) << 10) + lane * 16);
      LDC(Al1, WAi0 + ((((wgl * 2 + 1) * 2 + 1) * 32 + ks) << 10) + lane * 16);
      WAITVM(0);
      #pragma unroll
      for (int v4 = 0; v4 < 4; ++v4) {
        int vb = wv * 4 + v4;
        s16x8 Bh = ld16(embB + (((vb * 2 + 0) * 32 + ks) << 10) + lane * 16);
        s16x8 Bl = ld16(embB + (((vb * 2 + 1) * 32 + ks) << 10) + lane * 16);
        TRIPLE(C[0][v4], Ah0, Al0, Bh, Bl);
        TRIPLE(C[1][v4], Ah1, Al1, Bh, Bl);
      }
    }
    #pragma unroll
    for (int mi = 0; mi < 2; ++mi) {
      int jb4 = wgl * 32 + mi * 16 + l4 * 4;
      int u = jb4 >> 2;
      f32x4 bb;
      #pragma unroll
      for (int r = 0; r < 4; ++r) bb[r] = b0[r * 1024 + u];
      #pragma unroll
      for (int v4 = 0; v4 < 4; ++v4) {
        int v = (wv * 4 + v4) * 16 + l15;
        *(f32x4*)(E0 + v * 4096 + jb4) = C[mi][v4] + bb;
      }
    }
  }

  // ---- c state + L1 bias: one quadrant per wave ----
  float cst;
  {
    const float* cs = isL0 ? c0_in : c1_in;
    cst = cs[(nt_e * 16 + l15) * 1024 + wgl * 8 + mi_e * 4 + l4];
  }
  f32x4 b1z = {0.f, 0.f, 0.f, 0.f};
  if (!isL0) b1z = *(const f32x4*)(b1i + wgl * 32 + mi_e * 16 + (l4 << 2));

  __syncthreads();                                 // staging + E0 complete for this wg
  if (tid == 0) set_flag((isL0 ? f0 : f1) + wgl * 8, 0);   // "staged" release

  // ---- sequential recurrence ----
  if (isL0) {
    for (int t = 0; t < 256; ++t) {
      const int s = t + 1;
      f32x4 C[2][2];
      #pragma unroll
      for (int a = 0; a < 2; ++a)
        #pragma unroll
        for (int b = 0; b < 2; ++b) C[a][b] = 0.0f;

      // prefetch epilogue operands (E0 static during loop; issued before poll)
      int tv = tgt[(nt_e * 16 + l15) * 256 + t];
      f32x4 e0v = *(const f32x4*)(E0 + (size_t)tv * 4096 + wgl * 32 + mi_e * 16 + (l4 << 2));
      pollT<1>(f0, lane, t);
      const char* Bb = h0slot(WA0, h0s0, h0hi, t);
      const int ksb = wv * 8;
      s16x8 P[3][4];
      #pragma unroll
      for (int d = 0; d < 2; ++d)
        #pragma unroll
        for (int q = 0; q < 4; ++q) LDP(P[d][q], Bb + ((q * 32 + ksb + d) << 10) + lane * 16);
      #pragma unroll
      for (int i = 0; i < 8; ++i) {
        const int ks = ksb + i;
        if (i < 6) {
          #pragma unroll
          for (int q = 0; q < 4; ++q) LDP(P[(i + 2) % 3][q], Bb + ((q * 32 + ks + 2) << 10) + lane * 16);
        }
        s16x8 Ah0 = ld16(smem + ((0 * 32 + ks) << 10) + lane * 16);
        s16x8 Ah1 = ld16(smem + ((1 * 32 + ks) << 10) + lane * 16);
        s16x8 Al0 = ld16(smem + ((2 * 32 + ks) << 10) + lane * 16);
        s16x8 Al1 = ld16(smem + ((3 * 32 + ks) << 10) + lane * 16);
        if (i < 6) { WAITVM(8); } else if (i == 6) { WAITVM(4); } else { WAITVM(0); }
        TRIPLE(C[0][0], Ah0, Al0, P[i % 3][0], P[i % 3][2]);
        TRIPLE(C[0][1], Ah0, Al0, P[i % 3][1], P[i % 3][3]);
        TRIPLE(C[1][0], Ah1, Al1, P[i % 3][0], P[i % 3][2]);
        TRIPLE(C[1][1], Ah1, Al1, P[i % 3][1], P[i % 3][3]);
      }

      #pragma unroll
      for (int mi = 0; mi < 2; ++mi)
        #pragma unroll
        for (int nt = 0; nt < 2; ++nt)
          *(f32x4*)(smem + PART + ((wv * 4 + mi * 2 + nt) << 10) + lane * 16) = C[mi][nt];
      __syncthreads();                             // syncA

      {
        f32x4 z = *(const f32x4*)(smem + PART + ((0 * 4 + wv) << 10) + lane * 16);
        #pragma unroll
        for (int w = 1; w < 4; ++w)
          z += *(const f32x4*)(smem + PART + ((w * 4 + wv) << 10) + lane * 16);
        z += e0v;
        float ig = 1.f / (1.f + __expf(-z[0]));
        float fg = 1.f / (1.f + __expf(-z[1]));
        float og = 1.f / (1.f + __expf(-z[3]));
        float cn = fg * cst + ig * tanhf(z[2]);
        float hn = og * tanhf(cn);
        cst = cn;
        unsigned short hb = f2bf(hn);
        unsigned short lb = f2bf(hn - bf2f(hb));
        *(short*)(smem + RP0 + ((0 + nt_e) * 16 + l15) * 16 + (mi_e * 4 + l4) * 2) = (short)hb;
        *(short*)(smem + RP0 + ((2 + nt_e) * 16 + l15) * 16 + (mi_e * 4 + l4) * 2) = (short)lb;
        if (t == 255) {
          int u = wgl * 8 + mi_e * 4 + l4, b = nt_e * 16 + l15;
          out[2097152 + b * 1024 + u] = hn;
          out[2097152 + 32768 + b * 1024 + u] = cn;
        }
      }
      __syncthreads();                             // syncB

      if (wv == 0) {
        char* hd = h0slot(WA0, h0s0, h0hi, s);
        u32x4 v = *(const u32x4*)(smem + RP0 + lane * 16);
        char* dst = hd + (((lane >> 4) * 32 + (wgl >> 2)) << 10) + ((wgl & 3) * 16 + l15) * 16;
        st16c(dst, v);
        asm volatile("s_waitcnt vmcnt(0)" ::: "memory");
        if (lane == 0) set_flag(f0 + wgl * 8, s);
      }
    }
  } else {
    // ---- L1 prologue: zpre for t=0 (h0 slot 1 @ Wih1) on all 4 waves ----
    f32x4 zC2own;                                   // own quadrant of zpre, carried in regs
    {
      pollT<2>(f0, lane, 1);
      f32x4 C2[2][2];
      #pragma unroll
      for (int a = 0; a < 2; ++a)
        #pragma unroll
        for (int b = 0; b < 2; ++b) C2[a][b] = 0.0f;
      halfgemm8(smem, WA1, h0slot(WA0, h0s0, h0hi, 1), wgl, wv * 8, lane, C2);
      zC2own = C2[mi_e][nt_e];
      #pragma unroll
      for (int mi = 0; mi < 2; ++mi)
        #pragma unroll
        for (int nt = 0; nt < 2; ++nt) {
          int q = mi * 2 + nt;
          if (q != wv)
            *(f32x4*)(smem + ZTMP + ((wv * 3 + (q > wv ? q - 1 : q)) << 10) + lane * 16) = C2[mi][nt];
        }
      // no barrier: dumps are pre-syncA(t=0) in each wave's program order
    }

    for (int t = 0; t < 256; ++t) {
      const int s = t + 1;
      f32x4 C[2][2];
      #pragma unroll
      for (int a = 0; a < 2; ++a)
        #pragma unroll
        for (int b = 0; b < 2; ++b) C[a][b] = 0.0f;

      // ---- CRITICAL: h1_{t-1} @ Whh1 on all 4 waves ----
      pollT<1>(f1, lane, t);
      halfgemm8(smem + 65536, WA2, h1frag + (size_t)t * 131072, wgl, wv * 8, lane, C);

      #pragma unroll
      for (int mi = 0; mi < 2; ++mi)
        #pragma unroll
        for (int nt = 0; nt < 2; ++nt) {
          int q = mi * 2 + nt;
          if (q != wv)
            *(f32x4*)(smem + PART1 + ((wv * 3 + (q > wv ? q - 1 : q)) << 10) + lane * 16) = C[mi][nt];
        }
      __syncthreads();                             // syncA

      {
        f32x4 z = C[mi_e][nt_e];                   // own crit quadrant (register)
        #pragma unroll
        for (int w = 0; w < 4; ++w)
          if (w != wv)
            z += *(const f32x4*)(smem + PART1 + ((w * 3 + (wv > w ? wv - 1 : wv)) << 10) + lane * 16);
        z += zC2own;                               // own zpre quadrant (register)
        #pragma unroll
        for (int w = 0; w < 4; ++w)
          if (w != wv)
            z += *(const f32x4*)(smem + ZTMP + ((w * 3 + (wv > w ? wv - 1 : wv)) << 10) + lane * 16);
        z += b1z;
        float ig = 1.f / (1.f + __expf(-z[0]));
        float fg = 1.f / (1.f + __expf(-z[1]));
        float og = 1.f / (1.f + __expf(-z[3]));
        float cn = fg * cst + ig * tanhf(z[2]);
        float hn = og * tanhf(cn);
        cst = cn;
        unsigned short hb = f2bf(hn);
        unsigned short lb = f2bf(hn - bf2f(hb));
        *(short*)(smem + RP1 + ((0 + nt_e) * 16 + l15) * 16 + (mi_e * 4 + l4) * 2) = (short)hb;
        *(short*)(smem + RP1 + ((2 + nt_e) * 16 + l15) * 16 + (mi_e * 4 + l4) * 2) = (short)lb;
        if (t == 255) {
          int u = wgl * 8 + mi_e * 4 + l4, b = nt_e * 16 + l15;
          out[2097152 + 65536 + b * 1024 + u] = hn;
          out[2097152 + 65536 + 32768 + b * 1024 + u] = cn;
        }
      }
      __syncthreads();                             // syncB

      if (wv == 0) {
        char* hd = h1frag + (size_t)s * 131072;
        u32x4 v = *(const u32x4*)(smem + RP1 + lane * 16);
        char* dst = hd + (((lane >> 4) * 32 + (wgl >> 2)) << 10) + ((wgl & 3) * 16 + l15) * 16;
        st16c(dst, v);
        asm volatile("s_waitcnt vmcnt(0)" ::: "memory");
        if (lane == 0) set_flag(f1 + wgl * 8, s);
      }

      // ---- off-critical: zpre_{t+1} = h0_{t+1} @ Wih1 (slot t+2), after flag ----
      // ZTMP writes here are ordered vs epi reads by syncB (reads done) and next syncA.
      if (t < 255) {
        pollT<2>(f0, lane, t + 2);
        f32x4 C2[2][2];
        #pragma unroll
        for (int a = 0; a < 2; ++a)
          #pragma unroll
          for (int b = 0; b < 2; ++b) C2[a][b] = 0.0f;
        halfgemm8(smem, WA1, h0slot(WA0, h0s0, h0hi, t + 2), wgl, wv * 8, lane, C2);
        zC2own = C2[mi_e][nt_e];
        #pragma unroll
        for (int mi = 0; mi < 2; ++mi)
          #pragma unroll
          for (int nt = 0; nt < 2; ++nt) {
            int q = mi * 2 + nt;
            if (q != wv)
              *(f32x4*)(smem + ZTMP + ((wv * 3 + (q > wv ? q - 1 : q)) << 10) + lane * 16) = C2[mi][nt];
          }
      }
    }
  }

  // ---- projection: logits[b][t][v] = h1_t @ W_out + b_out ; one t per CU ----
  // L0 wgs (finish first) take EARLY t (flags long set); L1 wgs take late t.
  {
    const int tp = isL0 ? wgl : (128 + wgl);
    pollT<32>(f1, lane, tp + 1);
    const char* A = h1frag + (size_t)(tp + 1) * 131072;
    f32x4 C[2][4];
    #pragma unroll
    for (int a = 0; a < 2; ++a)
      #pragma unroll
      for (int b = 0; b < 4; ++b) C[a][b] = 0.0f;
    s16x8 QA[4], QB[4];
    #pragma unroll
    for (int q = 0; q < 4; ++q) LDP(QA[q], A + ((q * 32 + 0) << 10) + lane * 16);
    for (int kk = 0; kk < 16; ++kk) {
      const int ks = kk * 2;
      #pragma unroll
      for (int q = 0; q < 4; ++q) LDP(QB[q], A + ((q * 32 + ks + 1) << 10) + lane * 16);
      asm volatile("s_waitcnt vmcnt(4)" ::: "memory");
      __builtin_amdgcn_sched_barrier(0);
      #pragma unroll
      for (int v4 = 0; v4 < 4; ++v4) {
        int vb = wv * 4 + v4;
        s16x8 Bh = ld16(WoutB + (((vb * 2 + 0) * 32 + ks) << 10) + lane * 16);
        s16x8 Bl = ld16(WoutB + (((vb * 2 + 1) * 32 + ks) << 10) + lane * 16);
        C[0][v4] = MF(QA[0], Bh, C[0][v4]); C[0][v4] = MF(QA[0], Bl, C[0][v4]); C[0][v4] = MF(QA[2], Bh, C[0][v4]);
        C[1][v4] = MF(QA[1], Bh, C[1][v4]); C[1][v4] = MF(QA[1], Bl, C[1][v4]); C[1][v4] = MF(QA[3], Bh, C[1][v4]);
      }
      if (kk < 15) {
        #pragma unroll
        for (int q = 0; q < 4; ++q) LDP(QA[q], A + ((q * 32 + ks + 2) << 10) + lane * 16);
        asm volatile("s_waitcnt vmcnt(4)" ::: "memory");
      } else {
        asm volatile("s_waitcnt vmcnt(0)" ::: "memory");
      }
      __builtin_amdgcn_sched_barrier(0);
      #pragma unroll
      for (int v4 = 0; v4 < 4; ++v4) {
        int vb = wv * 4 + v4;
        s16x8 Bh = ld16(WoutB + (((vb * 2 + 0) * 32 + ks + 1) << 10) + lane * 16);
        s16x8 Bl = ld16(WoutB + (((vb * 2 + 1) * 32 + ks + 1) << 10) + lane * 16);
        C[0][v4] = MF(QB[0], Bh, C[0][v4]); C[0][v4] = MF(QB[0], Bl, C[0][v4]); C[0][v4] = MF(QB[2], Bh, C[0][v4]);
        C[1][v4] = MF(QB[1], Bh, C[1][v4]); C[1][v4] = MF(QB[1], Bl, C[1][v4]); C[1][v4] = MF(QB[3], Bh, C[1][v4]);
      }
    }
    #pragma unroll
    for (int nt = 0; nt < 2; ++nt)
      #pragma unroll
      for (int v4 = 0; v4 < 4; ++v4) {
        int v = (wv * 4 + v4) * 16 + l15;
        float bo = b_out[v];
        #pragma unroll
        for (int r = 0; r < 4; ++r) {
          int b = nt * 16 + l4 * 4 + r;
          out[((size_t)b * 256 + tp) * 256 + v] = C[nt][v4][r] + bo;
        }
      }
  }
}

extern "C" void kernel_launch(void* const* d_in, const int* in_sizes, int n_in,
                              void* d_out, int out_size, void* d_ws, size_t ws_size,
                              hipStream_t stream) {
  const int*   targets = (const int*)d_in[1];
  const float* h0_in   = (const float*)d_in[2];
  const float* c0_in   = (const float*)d_in[3];
  const float* h1_in   = (const float*)d_in[4];
  const float* c1_in   = (const float*)d_in[5];
  const float* emb     = (const float*)d_in[6];
  const float* W_ih0   = (const float*)d_in[7];
  const float* W_hh0   = (const float*)d_in[8];
  const float* b0      = (const float*)d_in[9];
  const float* W_ih1   = (const float*)d_in[10];
  const float* W_hh1   = (const float*)d_in[11];
  const float* b1      = (const float*)d_in[12];
  const float* W_out   = (const float*)d_in[13];
  const float* b_out   = (const float*)d_in[14];
  float* out = (float*)d_out;

  char* ws = (char*)d_ws;
  char*  WA0    = ws;                         // Whh0 A-frags hi/lo 16MB; becomes h0 slots 1..128
  char*  WA1    = ws + 16777216;              // Wih1 (hi staged, lo streamed)
  char*  WA2    = ws + 33554432;              // Whh1 (hi staged, lo streamed)
  char*  WoutB  = ws + 50331648;              // W_out B-frags, 1MB
  char*  embB   = ws + 51380224;              // emb B-frags, 1MB
  float* E0     = (float*)(ws + 52428800);    // 4MB f32
  float* b1i    = (float*)(ws + 56623104);    // 16KB
  int*   f0     = (int*)(ws + 56639488);      // flag array, 4KB (128 x stride 32B)
  int*   f1     = (int*)(ws + 56643584);      // flag array, 4KB
  char*  h0s0   = ws + 56647680;              // h0 slot 0, 128KB
  char*  h0hi   = ws + 56778752;              // h0 slots 129..256, 16MB
  char*  h1frag = ws + 73555968;              // 257 slots x 128KB (~33.7MB) -> end ~102.3MB
  char*  WAi0   = h1frag + 16777216;          // Wih0 A-frags alias h1 slots 128..255
                                              // (read via sc-loads at E0; slot 128 written step 127)

  prep_misc <<<18,   256, 0, stream>>>(b1, b1i, f0, f1);
  prep_wfrag<<<8192, 256, 0, stream>>>(W_hh0, W_ih1, W_hh1, W_ih0, WA0, WA1, WA2, WAi0);
  prep_bfrag<<<256,  256, 0, stream>>>(emb, W_out, embB, WoutB);
  prep_hinit<<<32,   256, 0, stream>>>(h0_in, h1_in, h0s0, h1frag);

  hipFuncSetAttribute(reinterpret_cast<const void*>(lstm_persist),
                      hipFuncAttributeMaxDynamicSharedMemorySize, 156672);
  lstm_persist<<<256, 256, 156672, stream>>>(
      targets, c0_in, c1_in, b0, b_out,
      WA0, WA1, WA2, WAi0, WoutB, embB,
      E0, b1i, h0s0, h0hi, h1frag, f0, f1, out);
}

// Round 15
// 1735.115 us; speedup vs baseline: 1.9555x; 1.1521x over previous
//
#include <hip/hip_runtime.h>
#include <cstdint>

// CharRNN 2-layer LSTM, B=32,T=256,H=1024,V=256. Persistent kernel (= round 7, best):
//   wgs 0..127  = layer-0 chain (8 units each), Whh0 hi+lo frags in LDS
//   wgs 128..255= layer-1 chain (8 units each): CRITICAL loop = h1@Whh1 on ALL 4 waves
//                 (8 iters each); h0@Wih1 prefetched ONE STEP AHEAD off-critical into zpre.
//   Projection: L0 wgs take EARLY t (instant flags), L1 wgs late t; slow-sleep tail polls.
//   h slots write-once (257/layer); h0 slots 1..128 alias WA0; flags relaxed agent atomics.
//   math: mfma_f32_16x16x32_bf16 split-bf16 (hi*hi + hi*lo + lo*hi) ~ f32 accuracy.

typedef float    f32x4 __attribute__((ext_vector_type(4)));
typedef short    s16x8 __attribute__((ext_vector_type(8)));
typedef unsigned u32x4 __attribute__((ext_vector_type(4)));

#define DEV __device__ __forceinline__

DEV unsigned short f2bf(float x){
  unsigned u = __builtin_bit_cast(unsigned, x);
  unsigned r = (u + 0x7fffu + ((u >> 16) & 1u)) >> 16;   // round-nearest-even
  return (unsigned short)r;
}
DEV float bf2f(unsigned short b){ return __builtin_bit_cast(float, ((unsigned)b) << 16); }

DEV s16x8 ld16(const void* p){ return *(const s16x8*)p; }

DEV f32x4 MF(s16x8 a, s16x8 b, f32x4 c){
  return __builtin_amdgcn_mfma_f32_16x16x32_bf16(a, b, c, 0, 0, 0);
}

// coherent (bypass L1/L2) 16B load — only for WA0/WAi0 (aliased regions)
#define LDC(dst, ptr)  asm volatile("global_load_dwordx4 %0, %1, off sc0 sc1" : "=v"(dst) : "v"(ptr))
// plain cached 16B load (participates in our vmcnt accounting)
#define LDP(dst, ptr)  asm volatile("global_load_dwordx4 %0, %1, off"         : "=v"(dst) : "v"(ptr))
#define WAITVM(n) do { asm volatile("s_waitcnt vmcnt(" #n ")" ::: "memory"); \
                       __builtin_amdgcn_sched_barrier(0); } while (0)
#define CFENCE()  asm volatile("" ::: "memory")
#define TRIPLE(Cmn, Ahm, Alm, Bhn, Bln) do { \
    Cmn = MF(Ahm, Bhn, Cmn); Cmn = MF(Ahm, Bln, Cmn); Cmn = MF(Alm, Bhn, Cmn); } while (0)

DEV void st16c(void* p, u32x4 v){   // coherent 16B store (write-through)
  asm volatile("global_store_dwordx4 %0, %1, off sc0 sc1" :: "v"(p), "v"(v) : "memory");
}
DEV void set_flag(int* p, int v){
  __hip_atomic_store(p, v, __ATOMIC_RELAXED, __HIP_MEMORY_SCOPE_AGENT);
}
// collective poll: all 128 flags (stride 8 ints) >= target. SLP = sleep amount.
template<int SLP>
DEV void pollT(const int* f, int lane, int target){
  const int* p0 = f + lane * 8;
  const int* p1 = f + (64 + lane) * 8;
  for (;;) {
    int a = __hip_atomic_load(p0, __ATOMIC_RELAXED, __HIP_MEMORY_SCOPE_AGENT);
    int b = __hip_atomic_load(p1, __ATOMIC_RELAXED, __HIP_MEMORY_SCOPE_AGENT);
    if (__all((a >= target) && (b >= target))) break;
    __builtin_amdgcn_s_sleep(SLP);
  }
  CFENCE();
}
// h0 slot address: 0 -> s0 buf; 1..128 -> aliased over WA0; 129..256 -> hi buf
DEV char* h0slot(char* wa0, char* s0, char* hi, int s){
  return (s == 0) ? s0 : ((s <= 128) ? wa0 + ((size_t)(s - 1) << 17)
                                     : hi  + ((size_t)(s - 129) << 17));
}

// 8-iteration half-GEMM: A hi from LDS (smemMat), A lo streamed from ALb, B 4 quarters from Bb
DEV void halfgemm8(const char* smemMat, const char* ALb, const char* Bb,
                   int wgl, int ksb, int lane, f32x4 (&C)[2][2]) {
  s16x8 P[3][4], AL[3][2];
  #pragma unroll
  for (int d = 0; d < 2; ++d) {
    #pragma unroll
    for (int q = 0; q < 4; ++q) LDP(P[d][q], Bb + ((q * 32 + ksb + d) << 10) + lane * 16);
    LDP(AL[d][0], ALb + ((((wgl * 2 + 0) * 2 + 1) * 32 + ksb + d) << 10) + lane * 16);
    LDP(AL[d][1], ALb + ((((wgl * 2 + 1) * 2 + 1) * 32 + ksb + d) << 10) + lane * 16);
  }
  #pragma unroll
  for (int i = 0; i < 8; ++i) {
    const int ks = ksb + i;
    if (i < 6) {
      #pragma unroll
      for (int q = 0; q < 4; ++q) LDP(P[(i + 2) % 3][q], Bb + ((q * 32 + ks + 2) << 10) + lane * 16);
      LDP(AL[(i + 2) % 3][0], ALb + ((((wgl * 2 + 0) * 2 + 1) * 32 + ks + 2) << 10) + lane * 16);
      LDP(AL[(i + 2) % 3][1], ALb + ((((wgl * 2 + 1) * 2 + 1) * 32 + ks + 2) << 10) + lane * 16);
    }
    s16x8 Ah0 = ld16(smemMat + ((0 * 32 + ks) << 10) + lane * 16);
    s16x8 Ah1 = ld16(smemMat + ((1 * 32 + ks) << 10) + lane * 16);
    if (i < 6) { WAITVM(12); } else if (i == 6) { WAITVM(6); } else { WAITVM(0); }
    TRIPLE(C[0][0], Ah0, AL[i % 3][0], P[i % 3][0], P[i % 3][2]);
    TRIPLE(C[0][1], Ah0, AL[i % 3][0], P[i % 3][1], P[i % 3][3]);
    TRIPLE(C[1][0], Ah1, AL[i % 3][1], P[i % 3][0], P[i % 3][2]);
    TRIPLE(C[1][1], Ah1, AL[i % 3][1], P[i % 3][1], P[i % 3][3]);
  }
}

// ---------------- prep: W[k][g*H+u] -> A-frag hi/lo bf16 [jb256][part2][ks32][64*16B] ----
__global__ void prep_wfrag(const float* __restrict__ W0, const float* __restrict__ W1,
                           const float* __restrict__ W2, const float* __restrict__ W3,
                           char* D0, char* D1, char* D2, char* D3) {
  int gid = blockIdx.x * 256 + threadIdx.x;       // 4*256*32*64 = 2M
  int lane = gid & 63, ks = (gid >> 6) & 31, jb = (gid >> 11) & 255, mat = gid >> 19;
  const float* S = (mat == 0) ? W0 : (mat == 1) ? W1 : (mat == 2) ? W2 : W3;
  char* D = (mat == 0) ? D0 : (mat == 1) ? D1 : (mat == 2) ? D2 : D3;
  int jp = jb * 16 + (lane & 15), u = jp >> 2, g = jp & 3;
  int kb = ks * 32 + (lane >> 4) * 8;
  s16x8 vh, vl;
  #pragma unroll
  for (int i = 0; i < 8; ++i) {
    float x = S[(kb + i) * 4096 + g * 1024 + u];
    unsigned short h = f2bf(x);
    vh[i] = (short)h;
    vl[i] = (short)f2bf(x - bf2f(h));
  }
  *(s16x8*)(D + (((jb * 2 + 0) * 32 + ks) << 10) + lane * 16) = vh;
  *(s16x8*)(D + (((jb * 2 + 1) * 32 + ks) << 10) + lane * 16) = vl;
}

// ---------------- prep: emb [v][k] and W_out [k][v] -> B-frag hi/lo [vb16][part2][ks32] ----
__global__ void prep_bfrag(const float* __restrict__ emb, const float* __restrict__ Wout,
                           char* Demb, char* Dwout) {
  int gid = blockIdx.x * 256 + threadIdx.x;       // 2*16*32*64 = 64K
  int lane = gid & 63, ks = (gid >> 6) & 31, vb = (gid >> 11) & 15, which = gid >> 15;
  int v = vb * 16 + (lane & 15), kb = ks * 32 + (lane >> 4) * 8;
  s16x8 vh, vl;
  #pragma unroll
  for (int i = 0; i < 8; ++i) {
    float x = which ? Wout[(kb + i) * 256 + v] : emb[v * 1024 + kb + i];
    unsigned short h = f2bf(x);
    vh[i] = (short)h;
    vl[i] = (short)f2bf(x - bf2f(h));
  }
  char* D = which ? Dwout : Demb;
  *(s16x8*)(D + (((vb * 2 + 0) * 32 + ks) << 10) + lane * 16) = vh;
  *(s16x8*)(D + (((vb * 2 + 1) * 32 + ks) << 10) + lane * 16) = vl;
}

// ---------------- prep: h0_in/h1_in [b][k] f32 -> h-frag slot0 [part2][nt2][ks32] ----
__global__ void prep_hinit(const float* __restrict__ h0, const float* __restrict__ h1,
                           char* h0s0, char* h1f) {
  int gid = blockIdx.x * 256 + threadIdx.x;       // 2*2*32*64 = 8192
  int lane = gid & 63, ks = (gid >> 6) & 31, nt = (gid >> 11) & 1, which = gid >> 12;
  const float* S = which ? h1 : h0;
  char* D = which ? h1f : h0s0;                   // slot 0 of each
  int b = nt * 16 + (lane & 15), kb = ks * 32 + (lane >> 4) * 8;
  s16x8 vh, vl;
  #pragma unroll
  for (int i = 0; i < 8; ++i) {
    float x = S[b * 1024 + kb + i];
    unsigned short h = f2bf(x);
    vh[i] = (short)h;
    vl[i] = (short)f2bf(x - bf2f(h));
  }
  *(s16x8*)(D + (((0 * 2 + nt) * 32 + ks) << 10) + lane * 16) = vh;
  *(s16x8*)(D + (((1 * 2 + nt) * 32 + ks) << 10) + lane * 16) = vl;
}

// ---------------- prep: flags = -1 (staging gate), gate-interleave b1 ----
__global__ void prep_misc(const float* __restrict__ b1, float* b1i, int* f0a, int* f1a) {
  int i = blockIdx.x * 256 + threadIdx.x;         // 4608
  if (i < 4096) b1i[i] = b1[(i & 3) * 1024 + (i >> 2)];
  if (i < 1024) { f0a[i] = -1; f1a[i] = -1; }
}

// ---------------- the persistent LSTM kernel ----------------
__global__ __launch_bounds__(256, 1) void lstm_persist(
    const int* __restrict__ tgt,
    const float* __restrict__ c0_in, const float* __restrict__ c1_in,
    const float* __restrict__ b0, const float* __restrict__ b_out,
    char* __restrict__ WA0, const char* __restrict__ WA1, const char* __restrict__ WA2,
    const char* __restrict__ WAi0, const char* __restrict__ WoutB, const char* __restrict__ embB,
    float* __restrict__ E0, const float* __restrict__ b1i,
    char* __restrict__ h0s0, char* __restrict__ h0hi, char* __restrict__ h1frag,
    int* __restrict__ f0, int* __restrict__ f1,
    float* __restrict__ out)
{
  extern __shared__ char smem[];     // 128KB A-frags + 16KB partials + 1KB repack
  constexpr int PART = 131072;
  constexpr int RP   = 131072 + 16384;
  const int tid = threadIdx.x, lane = tid & 63, wv = tid >> 6;
  const int wg = blockIdx.x;
  const bool isL0 = (wg < 128);
  const int wgl = isL0 ? wg : (wg - 128);
  const int l15 = lane & 15, l4 = lane >> 4;
  const int mi_e = wv >> 1, nt_e = wv & 1;        // epilogue role (mi, nt)

  // one-time cross-replay safety: invalidate stale L1/L2 lines
  __builtin_amdgcn_fence(__ATOMIC_ACQUIRE, "agent");

  // ---- stage A-frags into LDS: L0 = Whh0 hi+lo (sc-loads: WA0 becomes h0 slots!) ----
  if (isL0) {
    u32x4 tmp[8];
    for (int blk = 0; blk < 4; ++blk) {
      #pragma unroll
      for (int q = 0; q < 8; ++q) {
        int idx = tid + (blk * 8 + q) * 256;
        int l16 = idx & 63, ks = (idx >> 6) & 31, mi = (idx >> 11) & 1, part = idx >> 12;
        LDC(tmp[q], WA0 + ((((wgl * 2 + mi) * 2 + part) * 32 + ks) << 10) + l16 * 16);
      }
      WAITVM(0);
      #pragma unroll
      for (int q = 0; q < 8; ++q) {
        int idx = tid + (blk * 8 + q) * 256;
        int l16 = idx & 63, ks = (idx >> 6) & 31, mi = (idx >> 11) & 1, part = idx >> 12;
        *(u32x4*)(smem + (((part * 2 + mi) * 32 + ks) << 10) + l16 * 16) = tmp[q];
      }
    }
  } else {
    for (int idx = tid; idx < 8192; idx += 256) {
      int l16 = idx & 63, ks = (idx >> 6) & 31, mi = (idx >> 11) & 1, mat = idx >> 12;
      const char* W = mat ? WA2 : WA1;
      u32x4 v = *(const u32x4*)(W + ((((wgl * 2 + mi) * 2 + 0) * 32 + ks) << 10) + l16 * 16);
      *(u32x4*)(smem + (((mat * 2 + mi) * 32 + ks) << 10) + l16 * 16) = v;
    }
  }

  // ---- E0 = emb @ Wih0 + b0, own 32 gate-cols only (L0 wgs). WAi0 via sc-loads. ----
  if (isL0) {
    f32x4 C[2][4];
    #pragma unroll
    for (int a = 0; a < 2; ++a)
      #pragma unroll
      for (int b = 0; b < 4; ++b) C[a][b] = 0.0f;
    for (int ks = 0; ks < 32; ++ks) {
      s16x8 Ah0, Ah1, Al0, Al1;
      LDC(Ah0, WAi0 + ((((wgl * 2 + 0) * 2 + 0) * 32 + ks) << 10) + lane * 16);
      LDC(Ah1, WAi0 + ((((wgl * 2 + 1) * 2 + 0) * 32 + ks) << 10) + lane * 16);
      LDC(Al0, WAi0 + ((((wgl * 2 + 0) * 2 + 1) * 32 + ks) << 10) + lane * 16);
      LDC(Al1, WAi0 + ((((wgl * 2 + 1) * 2 + 1) * 32 + ks) << 10) + lane * 16);
      WAITVM(0);
      #pragma unroll
      for (int v4 = 0; v4 < 4; ++v4) {
        int vb = wv * 4 + v4;
        s16x8 Bh = ld16(embB + (((vb * 2 + 0) * 32 + ks) << 10) + lane * 16);
        s16x8 Bl = ld16(embB + (((vb * 2 + 1) * 32 + ks) << 10) + lane * 16);
        TRIPLE(C[0][v4], Ah0, Al0, Bh, Bl);
        TRIPLE(C[1][v4], Ah1, Al1, Bh, Bl);
      }
    }
    #pragma unroll
    for (int mi = 0; mi < 2; ++mi) {
      int jb4 = wgl * 32 + mi * 16 + l4 * 4;
      int u = jb4 >> 2;
      f32x4 bb;
      #pragma unroll
      for (int r = 0; r < 4; ++r) bb[r] = b0[r * 1024 + u];
      #pragma unroll
      for (int v4 = 0; v4 < 4; ++v4) {
        int v = (wv * 4 + v4) * 16 + l15;
        *(f32x4*)(E0 + v * 4096 + jb4) = C[mi][v4] + bb;
      }
    }
  }

  // ---- c state + L1 bias: one quadrant per wave ----
  float cst;
  {
    const float* cs = isL0 ? c0_in : c1_in;
    cst = cs[(nt_e * 16 + l15) * 1024 + wgl * 8 + mi_e * 4 + l4];
  }
  f32x4 b1z = {0.f, 0.f, 0.f, 0.f};
  if (!isL0) b1z = *(const f32x4*)(b1i + wgl * 32 + mi_e * 16 + (l4 << 2));

  __syncthreads();                                 // staging + E0 complete for this wg
  if (tid == 0) set_flag((isL0 ? f0 : f1) + wgl * 8, 0);   // "staged" release

  // ---- sequential recurrence ----
  if (isL0) {
    for (int t = 0; t < 256; ++t) {
      const int s = t + 1;
      f32x4 C[2][2];
      #pragma unroll
      for (int a = 0; a < 2; ++a)
        #pragma unroll
        for (int b = 0; b < 2; ++b) C[a][b] = 0.0f;

      // prefetch epilogue operands (E0 static during loop; issued before poll)
      int tv = tgt[(nt_e * 16 + l15) * 256 + t];
      f32x4 e0v = *(const f32x4*)(E0 + (size_t)tv * 4096 + wgl * 32 + mi_e * 16 + (l4 << 2));
      pollT<1>(f0, lane, t);
      const char* Bb = h0slot(WA0, h0s0, h0hi, t);
      const int ksb = wv * 8;
      s16x8 P[3][4];
      #pragma unroll
      for (int d = 0; d < 2; ++d)
        #pragma unroll
        for (int q = 0; q < 4; ++q) LDP(P[d][q], Bb + ((q * 32 + ksb + d) << 10) + lane * 16);
      #pragma unroll
      for (int i = 0; i < 8; ++i) {
        const int ks = ksb + i;
        if (i < 6) {
          #pragma unroll
          for (int q = 0; q < 4; ++q) LDP(P[(i + 2) % 3][q], Bb + ((q * 32 + ks + 2) << 10) + lane * 16);
        }
        s16x8 Ah0 = ld16(smem + ((0 * 32 + ks) << 10) + lane * 16);
        s16x8 Ah1 = ld16(smem + ((1 * 32 + ks) << 10) + lane * 16);
        s16x8 Al0 = ld16(smem + ((2 * 32 + ks) << 10) + lane * 16);
        s16x8 Al1 = ld16(smem + ((3 * 32 + ks) << 10) + lane * 16);
        if (i < 6) { WAITVM(8); } else if (i == 6) { WAITVM(4); } else { WAITVM(0); }
        TRIPLE(C[0][0], Ah0, Al0, P[i % 3][0], P[i % 3][2]);
        TRIPLE(C[0][1], Ah0, Al0, P[i % 3][1], P[i % 3][3]);
        TRIPLE(C[1][0], Ah1, Al1, P[i % 3][0], P[i % 3][2]);
        TRIPLE(C[1][1], Ah1, Al1, P[i % 3][1], P[i % 3][3]);
      }

      #pragma unroll
      for (int mi = 0; mi < 2; ++mi)
        #pragma unroll
        for (int nt = 0; nt < 2; ++nt)
          *(f32x4*)(smem + PART + ((wv * 4 + mi * 2 + nt) << 10) + lane * 16) = C[mi][nt];
      __syncthreads();                             // syncA

      {
        f32x4 z = *(const f32x4*)(smem + PART + ((0 * 4 + wv) << 10) + lane * 16);
        #pragma unroll
        for (int w = 1; w < 4; ++w)
          z += *(const f32x4*)(smem + PART + ((w * 4 + wv) << 10) + lane * 16);
        z += e0v;
        float ig = 1.f / (1.f + __expf(-z[0]));
        float fg = 1.f / (1.f + __expf(-z[1]));
        float og = 1.f / (1.f + __expf(-z[3]));
        float cn = fg * cst + ig * tanhf(z[2]);
        float hn = og * tanhf(cn);
        cst = cn;
        unsigned short hb = f2bf(hn);
        unsigned short lb = f2bf(hn - bf2f(hb));
        *(short*)(smem + RP + ((0 + nt_e) * 16 + l15) * 16 + (mi_e * 4 + l4) * 2) = (short)hb;
        *(short*)(smem + RP + ((2 + nt_e) * 16 + l15) * 16 + (mi_e * 4 + l4) * 2) = (short)lb;
        if (t == 255) {
          int u = wgl * 8 + mi_e * 4 + l4, b = nt_e * 16 + l15;
          out[2097152 + b * 1024 + u] = hn;
          out[2097152 + 32768 + b * 1024 + u] = cn;
        }
      }
      __syncthreads();                             // syncB

      if (wv == 0) {
        char* hd = h0slot(WA0, h0s0, h0hi, s);
        u32x4 v = *(const u32x4*)(smem + RP + lane * 16);
        char* dst = hd + (((lane >> 4) * 32 + (wgl >> 2)) << 10) + ((wgl & 3) * 16 + l15) * 16;
        st16c(dst, v);
        asm volatile("s_waitcnt vmcnt(0)" ::: "memory");
        if (lane == 0) set_flag(f0 + wgl * 8, s);
      }
    }
  } else {
    // ---- L1: prologue — prefetch Z1a[0] = h0_0 @ Wih1 (slot 1) ----
    f32x4 zpre;
    {
      pollT<2>(f0, lane, 1);
      f32x4 C2[2][2];
      #pragma unroll
      for (int a = 0; a < 2; ++a)
        #pragma unroll
        for (int b = 0; b < 2; ++b) C2[a][b] = 0.0f;
      halfgemm8(smem, WA1, h0slot(WA0, h0s0, h0hi, 1), wgl, wv * 8, lane, C2);
      #pragma unroll
      for (int mi = 0; mi < 2; ++mi)
        #pragma unroll
        for (int nt = 0; nt < 2; ++nt)
          *(f32x4*)(smem + PART + ((wv * 4 + mi * 2 + nt) << 10) + lane * 16) = C2[mi][nt];
      __syncthreads();                             // syncC
      zpre = *(const f32x4*)(smem + PART + ((0 * 4 + wv) << 10) + lane * 16);
      #pragma unroll
      for (int w = 1; w < 4; ++w)
        zpre += *(const f32x4*)(smem + PART + ((w * 4 + wv) << 10) + lane * 16);
      __syncthreads();                             // syncD
    }

    for (int t = 0; t < 256; ++t) {
      const int s = t + 1;
      f32x4 C[2][2];
      #pragma unroll
      for (int a = 0; a < 2; ++a)
        #pragma unroll
        for (int b = 0; b < 2; ++b) C[a][b] = 0.0f;

      // ---- CRITICAL: h1_{t-1} @ Whh1 on all 4 waves ----
      pollT<1>(f1, lane, t);
      halfgemm8(smem + 65536, WA2, h1frag + (size_t)t * 131072, wgl, wv * 8, lane, C);

      #pragma unroll
      for (int mi = 0; mi < 2; ++mi)
        #pragma unroll
        for (int nt = 0; nt < 2; ++nt)
          *(f32x4*)(smem + PART + ((wv * 4 + mi * 2 + nt) << 10) + lane * 16) = C[mi][nt];
      __syncthreads();                             // syncA

      {
        f32x4 z = *(const f32x4*)(smem + PART + ((0 * 4 + wv) << 10) + lane * 16);
        #pragma unroll
        for (int w = 1; w < 4; ++w)
          z += *(const f32x4*)(smem + PART + ((w * 4 + wv) << 10) + lane * 16);
        z += zpre + b1z;
        float ig = 1.f / (1.f + __expf(-z[0]));
        float fg = 1.f / (1.f + __expf(-z[1]));
        float og = 1.f / (1.f + __expf(-z[3]));
        float cn = fg * cst + ig * tanhf(z[2]);
        float hn = og * tanhf(cn);
        cst = cn;
        unsigned short hb = f2bf(hn);
        unsigned short lb = f2bf(hn - bf2f(hb));
        *(short*)(smem + RP + ((0 + nt_e) * 16 + l15) * 16 + (mi_e * 4 + l4) * 2) = (short)hb;
        *(short*)(smem + RP + ((2 + nt_e) * 16 + l15) * 16 + (mi_e * 4 + l4) * 2) = (short)lb;
        if (t == 255) {
          int u = wgl * 8 + mi_e * 4 + l4, b = nt_e * 16 + l15;
          out[2097152 + 65536 + b * 1024 + u] = hn;
          out[2097152 + 65536 + 32768 + b * 1024 + u] = cn;
        }
      }
      __syncthreads();                             // syncB

      if (wv == 0) {
        char* hd = h1frag + (size_t)s * 131072;
        u32x4 v = *(const u32x4*)(smem + RP + lane * 16);
        char* dst = hd + (((lane >> 4) * 32 + (wgl >> 2)) << 10) + ((wgl & 3) * 16 + l15) * 16;
        st16c(dst, v);
        asm volatile("s_waitcnt vmcnt(0)" ::: "memory");
        if (lane == 0) set_flag(f1 + wgl * 8, s);
      }

      // ---- off-critical: prefetch Z1a[t+1] = h0_{t+1} @ Wih1 (slot t+2) ----
      if (t < 255) {
        pollT<2>(f0, lane, t + 2);
        f32x4 C2[2][2];
        #pragma unroll
        for (int a = 0; a < 2; ++a)
          #pragma unroll
          for (int b = 0; b < 2; ++b) C2[a][b] = 0.0f;
        halfgemm8(smem, WA1, h0slot(WA0, h0s0, h0hi, t + 2), wgl, wv * 8, lane, C2);
        #pragma unroll
        for (int mi = 0; mi < 2; ++mi)
          #pragma unroll
          for (int nt = 0; nt < 2; ++nt)
            *(f32x4*)(smem + PART + ((wv * 4 + mi * 2 + nt) << 10) + lane * 16) = C2[mi][nt];
        __syncthreads();                           // syncC
        zpre = *(const f32x4*)(smem + PART + ((0 * 4 + wv) << 10) + lane * 16);
        #pragma unroll
        for (int w = 1; w < 4; ++w)
          zpre += *(const f32x4*)(smem + PART + ((w * 4 + wv) << 10) + lane * 16);
        __syncthreads();                           // syncD
      }
    }
  }

  // ---- projection: logits[b][t][v] = h1_t @ W_out + b_out ; one t per CU ----
  // L0 wgs (finish first) take EARLY t (flags long set); L1 wgs take late t.
  {
    const int tp = isL0 ? wgl : (128 + wgl);
    pollT<32>(f1, lane, tp + 1);
    const char* A = h1frag + (size_t)(tp + 1) * 131072;
    f32x4 C[2][4];
    #pragma unroll
    for (int a = 0; a < 2; ++a)
      #pragma unroll
      for (int b = 0; b < 4; ++b) C[a][b] = 0.0f;
    s16x8 QA[4], QB[4];
    #pragma unroll
    for (int q = 0; q < 4; ++q) LDP(QA[q], A + ((q * 32 + 0) << 10) + lane * 16);
    for (int kk = 0; kk < 16; ++kk) {
      const int ks = kk * 2;
      #pragma unroll
      for (int q = 0; q < 4; ++q) LDP(QB[q], A + ((q * 32 + ks + 1) << 10) + lane * 16);
      asm volatile("s_waitcnt vmcnt(4)" ::: "memory");
      __builtin_amdgcn_sched_barrier(0);
      #pragma unroll
      for (int v4 = 0; v4 < 4; ++v4) {
        int vb = wv * 4 + v4;
        s16x8 Bh = ld16(WoutB + (((vb * 2 + 0) * 32 + ks) << 10) + lane * 16);
        s16x8 Bl = ld16(WoutB + (((vb * 2 + 1) * 32 + ks) << 10) + lane * 16);
        C[0][v4] = MF(QA[0], Bh, C[0][v4]); C[0][v4] = MF(QA[0], Bl, C[0][v4]); C[0][v4] = MF(QA[2], Bh, C[0][v4]);
        C[1][v4] = MF(QA[1], Bh, C[1][v4]); C[1][v4] = MF(QA[1], Bl, C[1][v4]); C[1][v4] = MF(QA[3], Bh, C[1][v4]);
      }
      if (kk < 15) {
        #pragma unroll
        for (int q = 0; q < 4; ++q) LDP(QA[q], A + ((q * 32 + ks + 2) << 10) + lane * 16);
        asm volatile("s_waitcnt vmcnt(4)" ::: "memory");
      } else {
        asm volatile("s_waitcnt vmcnt(0)" ::: "memory");
      }
      __builtin_amdgcn_sched_barrier(0);
      #pragma unroll
      for (int v4 = 0; v4 < 4; ++v4) {
        int vb = wv * 4 + v4;
        s16x8 Bh = ld16(WoutB + (((vb * 2 + 0) * 32 + ks + 1) << 10) + lane * 16);
        s16x8 Bl = ld16(WoutB + (((vb * 2 + 1) * 32 + ks + 1) << 10) + lane * 16);
        C[0][v4] = MF(QB[0], Bh, C[0][v4]); C[0][v4] = MF(QB[0], Bl, C[0][v4]); C[0][v4] = MF(QB[2], Bh, C[0][v4]);
        C[1][v4] = MF(QB[1], Bh, C[1][v4]); C[1][v4] = MF(QB[1], Bl, C[1][v4]); C[1][v4] = MF(QB[3], Bh, C[1][v4]);
      }
    }
    #pragma unroll
    for (int nt = 0; nt < 2; ++nt)
      #pragma unroll
      for (int v4 = 0; v4 < 4; ++v4) {
        int v = (wv * 4 + v4) * 16 + l15;
        float bo = b_out[v];
        #pragma unroll
        for (int r = 0; r < 4; ++r) {
          int b = nt * 16 + l4 * 4 + r;
          out[((size_t)b * 256 + tp) * 256 + v] = C[nt][v4][r] + bo;
        }
      }
  }
}

extern "C" void kernel_launch(void* const* d_in, const int* in_sizes, int n_in,
                              void* d_out, int out_size, void* d_ws, size_t ws_size,
                              hipStream_t stream) {
  const int*   targets = (const int*)d_in[1];
  const float* h0_in   = (const float*)d_in[2];
  const float* c0_in   = (const float*)d_in[3];
  const float* h1_in   = (const float*)d_in[4];
  const float* c1_in   = (const float*)d_in[5];
  const float* emb     = (const float*)d_in[6];
  const float* W_ih0   = (const float*)d_in[7];
  const float* W_hh0   = (const float*)d_in[8];
  const float* b0      = (const float*)d_in[9];
  const float* W_ih1   = (const float*)d_in[10];
  const float* W_hh1   = (const float*)d_in[11];
  const float* b1      = (const float*)d_in[12];
  const float* W_out   = (const float*)d_in[13];
  const float* b_out   = (const float*)d_in[14];
  float* out = (float*)d_out;

  char* ws = (char*)d_ws;
  char*  WA0    = ws;                         // Whh0 A-frags hi/lo 16MB; becomes h0 slots 1..128
  char*  WA1    = ws + 16777216;              // Wih1 (hi staged, lo streamed)
  char*  WA2    = ws + 33554432;              // Whh1
  char*  WoutB  = ws + 50331648;              // W_out B-frags, 1MB
  char*  embB   = ws + 51380224;              // emb B-frags, 1MB
  float* E0     = (float*)(ws + 52428800);    // 4MB f32
  float* b1i    = (float*)(ws + 56623104);    // 16KB
  int*   f0     = (int*)(ws + 56639488);      // flag array, 4KB (128 x stride 32B)
  int*   f1     = (int*)(ws + 56643584);      // flag array, 4KB
  char*  h0s0   = ws + 56647680;              // h0 slot 0, 128KB
  char*  h0hi   = ws + 56778752;              // h0 slots 129..256, 16MB
  char*  h1frag = ws + 73555968;              // 257 slots x 128KB (~33.7MB) -> end ~102.3MB
  char*  WAi0   = h1frag + 16777216;          // Wih0 A-frags alias h1 slots 128..255
                                              // (read via sc-loads at E0; slot 128 written step 127)

  prep_misc <<<18,   256, 0, stream>>>(b1, b1i, f0, f1);
  prep_wfrag<<<8192, 256, 0, stream>>>(W_hh0, W_ih1, W_hh1, W_ih0, WA0, WA1, WA2, WAi0);
  prep_bfrag<<<256,  256, 0, stream>>>(emb, W_out, embB, WoutB);
  prep_hinit<<<32,   256, 0, stream>>>(h0_in, h1_in, h0s0, h1frag);

  hipFuncSetAttribute(reinterpret_cast<const void*>(lstm_persist),
                      hipFuncAttributeMaxDynamicSharedMemorySize, 148480);
  lstm_persist<<<256, 256, 148480, stream>>>(
      targets, c0_in, c1_in, b0, b_out,
      WA0, WA1, WA2, WAi0, WoutB, embB,
      E0, b1i, h0s0, h0hi, h1frag, f0, f1, out);
}